// Round 1
// baseline (725.750 us; speedup 1.0000x reference)
//
#include <hip/hip_runtime.h>

// ---------------------------------------------------------------------------
// AsymAttention on MI355X (gfx950).
// B=16, N=256, M=16, D=768, H=12, Dh=64.  scale = 1/8.
//
// Key algebraic refactor (avoids 155 GF of sim k/v projections):
//   logits_sim[b,h,n,m] = (se[b,n,m,:].T_row + q_h.bk_h) * scale,
//       T[b,n,h,D] = sum_dh q[b,h,n,dh] * Wk[D, h*64+dh]       (K=64 GEMM)
//   out_sim[b,h,n,dh]  = sum_D s_v[b,h,n,D] * Wv[D,h*64+dh] + asum*bv
//       s_v[b,h,n,D]   = sum_m a_sim[m] * se[b,n,m,D]
// ---------------------------------------------------------------------------

typedef __attribute__((ext_vector_type(8))) short short8;   // 8 x bf16 (MFMA frag)
typedef __attribute__((ext_vector_type(4))) float f32x4;    // MFMA acc
typedef __attribute__((ext_vector_type(4))) unsigned short u16x4;

__device__ __forceinline__ float bf2f(unsigned short u) {
  union { unsigned int i; float f; } c; c.i = ((unsigned int)u) << 16; return c.f;
}
__device__ __forceinline__ unsigned short f2bf(float f) {
  union { float f; unsigned int i; } c; c.f = f;
  unsigned int r = c.i + 0x7fffu + ((c.i >> 16) & 1u);   // RNE
  return (unsigned short)(r >> 16);
}

// --------------------------- small cast kernels ----------------------------

__global__ void cast_bf16(const float* __restrict__ in, unsigned short* __restrict__ out, int n) {
  int i = (blockIdx.x * 256 + threadIdx.x) * 4;
  if (i < n) {
    float4 v = *(const float4*)&in[i];
    out[i+0] = f2bf(v.x); out[i+1] = f2bf(v.y); out[i+2] = f2bf(v.z); out[i+3] = f2bf(v.w);
  }
}

// Wt[n][k] = W[k][n], bf16 out.  768x768, 32x32 tiles, 576 blocks.
__global__ void transpose_cast(const float* __restrict__ W, unsigned short* __restrict__ Wt) {
  __shared__ float tile[32][33];
  int bx = blockIdx.x % 24, by = blockIdx.x / 24;
  int n0 = bx * 32, k0 = by * 32;
  int tid = threadIdx.x;
  for (int l = tid; l < 1024; l += 256) {
    int i = l >> 5, j = l & 31;
    tile[i][j] = W[(size_t)(k0 + i) * 768 + n0 + j];
  }
  __syncthreads();
  for (int l = tid; l < 1024; l += 256) {
    int i = l >> 5, j = l & 31;
    Wt[(size_t)(n0 + i) * 768 + k0 + j] = f2bf(tile[j][i]);
  }
}

__global__ void concat_bias(const float* __restrict__ bq, const float* __restrict__ bk,
                            const float* __restrict__ bv, float* __restrict__ o) {
  int i = blockIdx.x * 256 + threadIdx.x;
  if (i < 2304) o[i] = (i < 768) ? bq[i] : ((i < 1536) ? bk[i - 768] : bv[i - 1536]);
}

// ------------------------------- GEMM (m97 pattern) ------------------------
// C[M x Nvalid] = A[M x K](bf16,row-major) * Bt[N x K]^T (+bias) ; 128x128 tile,
// BK=32, 4 waves (2x2), 4x4 frags/wave, global_load_lds width 16.

template<bool OUT_BF16, bool ADD, bool BIAS2>
__global__ __launch_bounds__(256)
void gemm_bt(const unsigned short* __restrict__ A, int lda, int zsA,
             const unsigned short* __restrict__ Bt, int ldb, int zsB,
             void* __restrict__ Cv, int ldc, int zsC,
             int M, int Nvalid, int K,
             const float* __restrict__ bias,
             const float* __restrict__ bias2, int zsBias2,
             const float* __restrict__ asum, int asumStride)
{
  const int z = blockIdx.z;
  A  += (size_t)zsA * z;
  Bt += (size_t)zsB * z;
  if (BIAS2) { bias2 += (size_t)zsBias2 * z; asum += z; }
  const int row0 = blockIdx.x * 128;
  const int col0 = blockIdx.y * 128;
  __shared__ __align__(16) unsigned short lgA[128 * 32];
  __shared__ __align__(16) unsigned short lgB[128 * 32];
  const int tid = threadIdx.x;
  const int lane = tid & 63;
  const int w = tid >> 6;
  const int wr = w >> 1, wc = w & 1;
  const int lr = lane & 15, kg = lane >> 4;

  f32x4 acc[4][4];
  #pragma unroll
  for (int m = 0; m < 4; m++)
    #pragma unroll
    for (int n = 0; n < 4; n++)
      #pragma unroll
      for (int q = 0; q < 4; q++) acc[m][n][q] = 0.f;

  for (int k0 = 0; k0 < K; k0 += 32) {
    __syncthreads();
    #pragma unroll
    for (int it = 0; it < 2; ++it) {
      const int off  = it * 4096 + tid * 16;
      const int row  = off >> 6;
      const int colb = off & 63;
      const char* ga = (const char*)A + (size_t)(row0 + row) * (lda * 2) + k0 * 2 + colb;
      char* la = (char*)lgA + it * 4096 + w * 1024;
      __builtin_amdgcn_global_load_lds((const __attribute__((address_space(1))) unsigned int*)ga,
                                       (__attribute__((address_space(3))) unsigned int*)la, 16, 0, 0);
      const char* gb = (const char*)Bt + (size_t)(col0 + row) * (ldb * 2) + k0 * 2 + colb;
      char* lb = (char*)lgB + it * 4096 + w * 1024;
      __builtin_amdgcn_global_load_lds((const __attribute__((address_space(1))) unsigned int*)gb,
                                       (__attribute__((address_space(3))) unsigned int*)lb, 16, 0, 0);
    }
    __syncthreads();
    short8 af[4], bfr[4];
    #pragma unroll
    for (int m = 0; m < 4; m++) af[m]  = *(const short8*)&lgA[(wr * 64 + m * 16 + lr) * 32 + kg * 8];
    #pragma unroll
    for (int n = 0; n < 4; n++) bfr[n] = *(const short8*)&lgB[(wc * 64 + n * 16 + lr) * 32 + kg * 8];
    #pragma unroll
    for (int m = 0; m < 4; m++)
      #pragma unroll
      for (int n = 0; n < 4; n++)
        acc[m][n] = __builtin_amdgcn_mfma_f32_16x16x32_bf16(af[m], bfr[n], acc[m][n], 0, 0, 0);
  }

  // epilogue: C layout col=lane&15, row=(lane>>4)*4+reg
  #pragma unroll
  for (int m = 0; m < 4; m++) {
    #pragma unroll
    for (int n = 0; n < 4; n++) {
      const int gc = col0 + wc * 64 + n * 16 + lr;
      if (gc >= Nvalid) continue;
      #pragma unroll
      for (int j = 0; j < 4; j++) {
        const int gr = row0 + wr * 64 + m * 16 + kg * 4 + j;
        if (gr >= M) continue;
        float v = acc[m][n][j];
        if (bias) v += bias[gc];
        if (BIAS2) v += asum[(size_t)gr * asumStride] * bias2[gc];
        const size_t idx = (size_t)gr * ldc + gc;
        if (OUT_BF16) {
          unsigned short* C = (unsigned short*)Cv + (size_t)zsC * z;
          if (ADD) v += bf2f(C[idx]);
          C[idx] = f2bf(v);
        } else {
          float* C = (float*)Cv + (size_t)zsC * z;
          if (ADD) v += C[idx];
          C[idx] = v;
        }
      }
    }
  }
}

// --------------------------- sim logits (se pass 1) ------------------------
// One block per (b,n):  ls[r,h,m] = (se[r,m,:].T[r,h,:] + q_h.bk_h) * 0.125

__global__ __launch_bounds__(256)
void sim_logits_kernel(const float* __restrict__ se, const unsigned short* __restrict__ T,
                       const unsigned short* __restrict__ qkv, const float* __restrict__ bk,
                       float* __restrict__ ls)
{
  const int r = blockIdx.x;                    // b*256+n
  __shared__ float Tl[12 * 768];
  __shared__ float sel[16 * 768];
  __shared__ float ql[768];
  __shared__ float qb[12];
  const int tid = threadIdx.x;

  for (int i = tid * 4; i < 9216; i += 1024) { // T row (bf16 -> f32)
    u16x4 t4 = *(const u16x4*)&T[(size_t)r * 9216 + i];
    Tl[i] = bf2f(t4.x); Tl[i+1] = bf2f(t4.y); Tl[i+2] = bf2f(t4.z); Tl[i+3] = bf2f(t4.w);
  }
  if (tid < 192) {                             // q row (cols 0..767 of qkv)
    u16x4 q4 = *(const u16x4*)&qkv[(size_t)r * 2304 + tid * 4];
    ql[tid*4] = bf2f(q4.x); ql[tid*4+1] = bf2f(q4.y); ql[tid*4+2] = bf2f(q4.z); ql[tid*4+3] = bf2f(q4.w);
  }
  for (int i = tid * 4; i < 12288; i += 1024) { // se rows (f32)
    float4 s4 = *(const float4*)&se[(size_t)r * 12288 + i];
    sel[i] = s4.x; sel[i+1] = s4.y; sel[i+2] = s4.z; sel[i+3] = s4.w;
  }
  __syncthreads();
  if (tid < 12) {
    float s = 0.f;
    for (int d = 0; d < 64; ++d) s += ql[tid * 64 + d] * bk[tid * 64 + d];
    qb[tid] = s;
  }
  __syncthreads();
  const int w = tid >> 6, lane = tid & 63;
  for (int p = w; p < 192; p += 4) {           // 192 (h,m) dot products of 768
    const int hh = p >> 4, m = p & 15;
    float s = 0.f;
    #pragma unroll
    for (int j = 0; j < 12; j++) s += sel[m * 768 + lane + j * 64] * Tl[hh * 768 + lane + j * 64];
    #pragma unroll
    for (int sft = 32; sft; sft >>= 1) s += __shfl_xor(s, sft);
    if (lane == 0) ls[(size_t)r * 192 + hh * 16 + m] = (s + qb[hh]) * 0.125f;
  }
}

// ------------------------------ attention core -----------------------------
// One block per (b,h); 4 waves, 64 query rows each.  QK^T and PV via MFMA.
// Softmax over 256 self + 16 sim logits, fully in registers + 16-lane shfl.

__global__ __launch_bounds__(256, 1)
void attn_kernel(const unsigned short* __restrict__ qkv,
                 const float* __restrict__ ls,
                 unsigned short* __restrict__ att,
                 float* __restrict__ a_sim,
                 float* __restrict__ asum)
{
  const int b = blockIdx.x / 12;
  const int h = blockIdx.x % 12;
  const int tid = threadIdx.x;
  const int lane = tid & 63;
  const int w = tid >> 6;
  const int lr = lane & 15, kg = lane >> 4;
  const size_t rowbase = (size_t)b * 256;

  __shared__ __align__(16) char smem[107520];
  unsigned short* Qs = (unsigned short*)smem;             // [256][72]
  unsigned short* Ks = (unsigned short*)(smem + 36864);   // [256][72]
  unsigned short* VT = (unsigned short*)(smem + 73728);   // [64][264]  VT[d][k]=V[k][d]
  unsigned short* aL = (unsigned short*)(smem + (size_t)w * 17408); // [64][136]/wave, aliases Qs/Ks

  for (int j = tid * 4; j < 256 * 64; j += 1024) {
    const int row = j >> 6, d = j & 63;
    const unsigned short* qp = qkv + (rowbase + row) * 2304 + h * 64 + d;
    u16x4 qv = *(const u16x4*)qp;
    u16x4 kv = *(const u16x4*)(qp + 768);
    *(u16x4*)&Qs[row * 72 + d] = qv;
    *(u16x4*)&Ks[row * 72 + d] = kv;
  }
  for (int i = 0; i < 64; ++i) {       // V transpose: lane=d, rows kk
    const int kk = w * 64 + i;
    VT[lane * 264 + kk] = qkv[(rowbase + kk) * 2304 + 1536 + h * 64 + lane];
  }
  __syncthreads();

  const int n0 = w * 64;
  f32x4 acc[4][16];
  #pragma unroll
  for (int m = 0; m < 4; m++)
    #pragma unroll
    for (int n = 0; n < 16; n++)
      #pragma unroll
      for (int q = 0; q < 4; q++) acc[m][n][q] = 0.f;

  #pragma unroll
  for (int ks = 0; ks < 64; ks += 32) {           // QK^T, K=64
    short8 af[4];
    #pragma unroll
    for (int m = 0; m < 4; m++) af[m] = *(const short8*)&Qs[(n0 + m * 16 + lr) * 72 + ks + kg * 8];
    #pragma unroll
    for (int n = 0; n < 16; n++) {
      short8 bfr = *(const short8*)&Ks[(n * 16 + lr) * 72 + ks + kg * 8];
      #pragma unroll
      for (int m = 0; m < 4; m++)
        acc[m][n] = __builtin_amdgcn_mfma_f32_16x16x32_bf16(af[m], bfr, acc[m][n], 0, 0, 0);
    }
  }

  float inv_[4][4];
  #pragma unroll
  for (int m = 0; m < 4; m++) {
    #pragma unroll
    for (int j = 0; j < 4; j++) {
      float vmx = -1e30f;
      #pragma unroll
      for (int n = 0; n < 16; n++) { float s = acc[m][n][j] * 0.125f; acc[m][n][j] = s; vmx = fmaxf(vmx, s); }
      const int row = n0 + m * 16 + kg * 4 + j;
      const float lsim = ls[(rowbase + row) * 192 + h * 16 + lr];   // lr = sim index (M=16)
      vmx = fmaxf(vmx, lsim);
      #pragma unroll
      for (int s = 1; s < 16; s <<= 1) vmx = fmaxf(vmx, __shfl_xor(vmx, s));
      float sum = 0.f;
      #pragma unroll
      for (int n = 0; n < 16; n++) { float e = __expf(acc[m][n][j] - vmx); acc[m][n][j] = e; sum += e; }
      const float es = __expf(lsim - vmx);
      float ssum = es;
      sum += es;
      #pragma unroll
      for (int s = 1; s < 16; s <<= 1) { sum += __shfl_xor(sum, s); ssum += __shfl_xor(ssum, s); }
      const float inv = 1.0f / sum;
      inv_[m][j] = inv;
      a_sim[(((size_t)b * 12 + h) * 256 + row) * 16 + lr] = es * inv;
      if (lr == 0) asum[(rowbase + row) * 12 + h] = ssum * inv;
    }
  }

  __syncthreads();   // all waves done reading Qs/Ks before aL overwrites them

  f32x4 acc2[4][4];
  #pragma unroll
  for (int m = 0; m < 4; m++)
    #pragma unroll
    for (int n = 0; n < 4; n++)
      #pragma unroll
      for (int q = 0; q < 4; q++) acc2[m][n][q] = 0.f;

  #pragma unroll
  for (int hl = 0; hl < 2; ++hl) {   // PV in two 128-col halves (LDS budget)
    #pragma unroll
    for (int m = 0; m < 4; m++)
      #pragma unroll
      for (int j = 0; j < 4; j++) {
        const int rw = m * 16 + kg * 4 + j;
        #pragma unroll
        for (int n2 = 0; n2 < 8; n2++)
          aL[rw * 136 + n2 * 16 + lr] = f2bf(acc[m][hl * 8 + n2][j] * inv_[m][j]);
      }
    #pragma unroll
    for (int ks2 = 0; ks2 < 4; ++ks2) {   // out^T = VT * a^T
      short8 vf[4], pf[4];
      #pragma unroll
      for (int mm = 0; mm < 4; mm++)
        vf[mm] = *(const short8*)&VT[(mm * 16 + lr) * 264 + hl * 128 + ks2 * 32 + kg * 8];
      #pragma unroll
      for (int nn = 0; nn < 4; nn++)
        pf[nn] = *(const short8*)&aL[(nn * 16 + lr) * 136 + ks2 * 32 + kg * 8];
      #pragma unroll
      for (int mm = 0; mm < 4; mm++)
        #pragma unroll
        for (int nn = 0; nn < 4; nn++)
          acc2[mm][nn] = __builtin_amdgcn_mfma_f32_16x16x32_bf16(vf[mm], pf[nn], acc2[mm][nn], 0, 0, 0);
    }
  }

  #pragma unroll
  for (int mm = 0; mm < 4; mm++)      // D rows = dh, D cols = query row
    #pragma unroll
    for (int nn = 0; nn < 4; nn++)
      #pragma unroll
      for (int j = 0; j < 4; j++) {
        const int dh = mm * 16 + kg * 4 + j;
        const int rn = n0 + nn * 16 + lr;
        att[(rowbase + rn) * 768 + h * 64 + dh] = f2bf(acc2[mm][nn][j]);
      }
}

// ------------------------------ s_v (se pass 2) ----------------------------
// One block per (b,n): s_v[h,D] = sum_m a_sim[h,m] * se[m,D]  (bf16 out)

__global__ __launch_bounds__(256)
void sv_kernel(const float* __restrict__ se, const float* __restrict__ a_sim,
               unsigned short* __restrict__ s_v)
{
  const int r = blockIdx.x;
  const int b = r >> 8, n = r & 255;
  __shared__ float al[192];
  const int tid = threadIdx.x;
  if (tid < 192) {
    const int hh = tid >> 4, m = tid & 15;
    al[tid] = a_sim[(((size_t)b * 12 + hh) * 256 + n) * 16 + m];
  }
  __syncthreads();
  #pragma unroll
  for (int j = 0; j < 3; j++) {
    const int d = tid + j * 256;
    float accv[12];
    #pragma unroll
    for (int hh = 0; hh < 12; hh++) accv[hh] = 0.f;
    for (int m = 0; m < 16; m++) {
      const float xv = se[(size_t)r * 12288 + m * 768 + d];
      #pragma unroll
      for (int hh = 0; hh < 12; hh++) accv[hh] += al[hh * 16 + m] * xv;
    }
    #pragma unroll
    for (int hh = 0; hh < 12; hh++) s_v[((size_t)r * 12 + hh) * 768 + d] = f2bf(accv[hh]);
  }
}

// ------------------------------- launcher ----------------------------------

extern "C" void kernel_launch(void* const* d_in, const int* in_sizes, int n_in,
                              void* d_out, int out_size, void* d_ws, size_t ws_size,
                              hipStream_t stream) {
  const float* x  = (const float*)d_in[0];
  const float* se = (const float*)d_in[1];
  const float* Wq = (const float*)d_in[2];
  const float* bq = (const float*)d_in[3];
  const float* Wk = (const float*)d_in[4];
  const float* bk = (const float*)d_in[5];
  const float* Wv = (const float*)d_in[6];
  const float* bv = (const float*)d_in[7];
  const float* Wp = (const float*)d_in[8];
  const float* bp = (const float*)d_in[9];
  float* out = (float*)d_out;
  char* ws = (char*)d_ws;

  // workspace layout (all offsets 256B-aligned), total ~119.5 MB
  unsigned short* x_bf   = (unsigned short*)(ws);                 // 4096x768        bf16
  unsigned short* Wqkv_t = (unsigned short*)(ws + 6291456);       // 2368x768 (pad)  bf16, rows: Wq^T|Wk^T|Wv^T
  unsigned short* Wp_t   = (unsigned short*)(ws + 9928704);       // 768x768         bf16
  unsigned short* Wk_bf  = (unsigned short*)(ws + 11108352);      // 768x768         bf16 (untransposed)
  float*          bqkv   = (float*)(ws + 12288000);               // 2304            f32
  unsigned short* qkv    = (unsigned short*)(ws + 12297216);      // 4096x2304       bf16  q|k|v
  unsigned short* Tbuf   = (unsigned short*)(ws + 31171584);      // 4096x12x768     bf16  T, then s_v
  float*          lsb    = (float*)(ws + 106669056);              // 4096x12x16      f32
  float*          a_simb = (float*)(ws + 109814784);              // 16x12x256x16    f32
  float*          asumb  = (float*)(ws + 112960512);              // 4096x12         f32
  unsigned short* att    = (unsigned short*)(ws + 113157120);     // 4096x768        bf16

  cast_bf16<<<3072, 256, 0, stream>>>(x, x_bf, 3145728);
  transpose_cast<<<576, 256, 0, stream>>>(Wq, Wqkv_t);
  transpose_cast<<<576, 256, 0, stream>>>(Wk, Wqkv_t + 768 * 768);
  transpose_cast<<<576, 256, 0, stream>>>(Wv, Wqkv_t + 1536 * 768);
  transpose_cast<<<576, 256, 0, stream>>>(Wp, Wp_t);
  cast_bf16<<<576, 256, 0, stream>>>(Wk, Wk_bf, 589824);
  concat_bias<<<9, 256, 0, stream>>>(bq, bk, bv, bqkv);

  // qkv = x @ [Wq|Wk|Wv] + bias  (M=4096, N=2304, K=768)
  gemm_bt<true, false, false><<<dim3(32, 18, 1), 256, 0, stream>>>(
      x_bf, 768, 0, Wqkv_t, 768, 0, qkv, 2304, 0, 4096, 2304, 768, bqkv, nullptr, 0, nullptr, 0);
  // T[r,h,:] = q_h @ Wk_h^T  (per-head z=12, K=64)
  gemm_bt<true, false, false><<<dim3(32, 6, 12), 256, 0, stream>>>(
      qkv, 2304, 64, Wk_bf, 768, 64, Tbuf, 9216, 768, 4096, 768, 64, nullptr, nullptr, 0, nullptr, 0);

  sim_logits_kernel<<<4096, 256, 0, stream>>>(se, Tbuf, qkv, bk, lsb);
  attn_kernel<<<192, 256, 0, stream>>>(qkv, lsb, att, a_simb, asumb);
  sv_kernel<<<4096, 256, 0, stream>>>(se, a_simb, Tbuf /* reused as s_v */);

  // att += s_v_h @ Wv_h  (+ asum*bv_h)   (per-head z=12, N=64, K=768)
  gemm_bt<true, true, true><<<dim3(32, 1, 12), 256, 0, stream>>>(
      Tbuf, 9216, 768, Wqkv_t + 1536 * 768, 768, 64 * 768, att, 768, 64,
      4096, 64, 768, nullptr, bv, 64, asumb, 12);
  // out = att @ Wp + bp  (f32 out)
  gemm_bt<false, false, false><<<dim3(32, 6, 1), 256, 0, stream>>>(
      att, 768, 0, Wp_t, 768, 0, out, 768, 0, 4096, 768, 768, bp, nullptr, 0, nullptr, 0);
}

// Round 2
// 394.347 us; speedup vs baseline: 1.8404x; 1.8404x over previous
//
#include <hip/hip_runtime.h>

// ---------------------------------------------------------------------------
// AsymAttention on MI355X (gfx950).
// B=16, N=256, M=16, D=768, H=12, Dh=64.  scale = 1/8.
//
// Key algebraic refactor (avoids 155 GF of sim k/v projections):
//   logits_sim[b,h,n,m] = (se[b,n,m,:].T_row + q_h.bk_h) * scale,
//       T[b,n,h,D] = sum_dh q[b,h,n,dh] * Wk[D, h*64+dh]       (K=64 GEMM)
//   out_sim[b,h,n,dh]  = sum_D s_v[b,h,n,D] * Wv[D,h*64+dh] + asum*bv
//       s_v[b,h,n,D]   = sum_m a_sim[m] * se[b,n,m,D]
// ---------------------------------------------------------------------------

typedef __attribute__((ext_vector_type(8))) short short8;   // 8 x bf16 (MFMA frag)
typedef __attribute__((ext_vector_type(4))) float f32x4;    // MFMA acc
typedef __attribute__((ext_vector_type(4))) unsigned short u16x4;

__device__ __forceinline__ float bf2f(unsigned short u) {
  union { unsigned int i; float f; } c; c.i = ((unsigned int)u) << 16; return c.f;
}
__device__ __forceinline__ unsigned short f2bf(float f) {
  union { float f; unsigned int i; } c; c.f = f;
  unsigned int r = c.i + 0x7fffu + ((c.i >> 16) & 1u);   // RNE
  return (unsigned short)(r >> 16);
}

// --------------------------- small cast kernels ----------------------------

__global__ void cast_bf16(const float* __restrict__ in, unsigned short* __restrict__ out, int n) {
  int i = (blockIdx.x * 256 + threadIdx.x) * 4;
  if (i < n) {
    float4 v = *(const float4*)&in[i];
    out[i+0] = f2bf(v.x); out[i+1] = f2bf(v.y); out[i+2] = f2bf(v.z); out[i+3] = f2bf(v.w);
  }
}

// Wt[n][k] = W[k][n], bf16 out.  768x768, 32x32 tiles, 576 blocks.
__global__ void transpose_cast(const float* __restrict__ W, unsigned short* __restrict__ Wt) {
  __shared__ float tile[32][33];
  int bx = blockIdx.x % 24, by = blockIdx.x / 24;
  int n0 = bx * 32, k0 = by * 32;
  int tid = threadIdx.x;
  for (int l = tid; l < 1024; l += 256) {
    int i = l >> 5, j = l & 31;
    tile[i][j] = W[(size_t)(k0 + i) * 768 + n0 + j];
  }
  __syncthreads();
  for (int l = tid; l < 1024; l += 256) {
    int i = l >> 5, j = l & 31;
    Wt[(size_t)(n0 + i) * 768 + k0 + j] = f2bf(tile[j][i]);
  }
}

__global__ void concat_bias(const float* __restrict__ bq, const float* __restrict__ bk,
                            const float* __restrict__ bv, float* __restrict__ o) {
  int i = blockIdx.x * 256 + threadIdx.x;
  if (i < 2304) o[i] = (i < 768) ? bq[i] : ((i < 1536) ? bk[i - 768] : bv[i - 1536]);
}

// ------------------------------- GEMM (m97 pattern) ------------------------
// C[M x Nvalid] = A[M x K](bf16,row-major) * Bt[N x K]^T (+bias) ; 128x128 tile,
// BK=32, 4 waves (2x2), 4x4 frags/wave, global_load_lds width 16.

template<bool OUT_BF16, bool ADD, bool BIAS2>
__global__ __launch_bounds__(256)
void gemm_bt(const unsigned short* __restrict__ A, int lda, int zsA,
             const unsigned short* __restrict__ Bt, int ldb, int zsB,
             void* __restrict__ Cv, int ldc, int zsC,
             int M, int Nvalid, int K,
             const float* __restrict__ bias,
             const float* __restrict__ bias2, int zsBias2,
             const float* __restrict__ asum, int asumStride)
{
  const int z = blockIdx.z;
  A  += (size_t)zsA * z;
  Bt += (size_t)zsB * z;
  if (BIAS2) { bias2 += (size_t)zsBias2 * z; asum += z; }
  const int row0 = blockIdx.x * 128;
  const int col0 = blockIdx.y * 128;
  __shared__ __align__(16) unsigned short lgA[128 * 32];
  __shared__ __align__(16) unsigned short lgB[128 * 32];
  const int tid = threadIdx.x;
  const int lane = tid & 63;
  const int w = tid >> 6;
  const int wr = w >> 1, wc = w & 1;
  const int lr = lane & 15, kg = lane >> 4;

  f32x4 acc[4][4];
  #pragma unroll
  for (int m = 0; m < 4; m++)
    #pragma unroll
    for (int n = 0; n < 4; n++)
      #pragma unroll
      for (int q = 0; q < 4; q++) acc[m][n][q] = 0.f;

  for (int k0 = 0; k0 < K; k0 += 32) {
    __syncthreads();
    #pragma unroll
    for (int it = 0; it < 2; ++it) {
      const int off  = it * 4096 + tid * 16;
      const int row  = off >> 6;
      const int colb = off & 63;
      const char* ga = (const char*)A + (size_t)(row0 + row) * (lda * 2) + k0 * 2 + colb;
      char* la = (char*)lgA + it * 4096 + w * 1024;
      __builtin_amdgcn_global_load_lds((const __attribute__((address_space(1))) unsigned int*)ga,
                                       (__attribute__((address_space(3))) unsigned int*)la, 16, 0, 0);
      const char* gb = (const char*)Bt + (size_t)(col0 + row) * (ldb * 2) + k0 * 2 + colb;
      char* lb = (char*)lgB + it * 4096 + w * 1024;
      __builtin_amdgcn_global_load_lds((const __attribute__((address_space(1))) unsigned int*)gb,
                                       (__attribute__((address_space(3))) unsigned int*)lb, 16, 0, 0);
    }
    __syncthreads();
    short8 af[4], bfr[4];
    #pragma unroll
    for (int m = 0; m < 4; m++) af[m]  = *(const short8*)&lgA[(wr * 64 + m * 16 + lr) * 32 + kg * 8];
    #pragma unroll
    for (int n = 0; n < 4; n++) bfr[n] = *(const short8*)&lgB[(wc * 64 + n * 16 + lr) * 32 + kg * 8];
    #pragma unroll
    for (int m = 0; m < 4; m++)
      #pragma unroll
      for (int n = 0; n < 4; n++)
        acc[m][n] = __builtin_amdgcn_mfma_f32_16x16x32_bf16(af[m], bfr[n], acc[m][n], 0, 0, 0);
  }

  // epilogue: C layout col=lane&15, row=(lane>>4)*4+reg
  #pragma unroll
  for (int m = 0; m < 4; m++) {
    #pragma unroll
    for (int n = 0; n < 4; n++) {
      const int gc = col0 + wc * 64 + n * 16 + lr;
      if (gc >= Nvalid) continue;
      #pragma unroll
      for (int j = 0; j < 4; j++) {
        const int gr = row0 + wr * 64 + m * 16 + kg * 4 + j;
        if (gr >= M) continue;
        float v = acc[m][n][j];
        if (bias) v += bias[gc];
        if (BIAS2) v += asum[(size_t)gr * asumStride] * bias2[gc];
        const size_t idx = (size_t)gr * ldc + gc;
        if (OUT_BF16) {
          unsigned short* C = (unsigned short*)Cv + (size_t)zsC * z;
          if (ADD) v += bf2f(C[idx]);
          C[idx] = f2bf(v);
        } else {
          float* C = (float*)Cv + (size_t)zsC * z;
          if (ADD) v += C[idx];
          C[idx] = v;
        }
      }
    }
  }
}

// --------------------------- sim logits (se pass 1) ------------------------
// One block per (b,n), 16 waves: wave m owns sim index m and streams
// se[r,m,:] into registers (3x float4/lane).  T row (12x768) staged once in
// LDS as f32 and reused by all 16 waves.  ls[r,h,m] = (se_m.T_h + q.bk_h)/8.

__global__ __launch_bounds__(1024)
void sim_logits_kernel(const float* __restrict__ se, const unsigned short* __restrict__ T,
                       const unsigned short* __restrict__ qkv, const float* __restrict__ bk,
                       float* __restrict__ ls)
{
  const int r = blockIdx.x;                    // b*256+n
  __shared__ float TlF[12 * 768];
  __shared__ float qb[12];
  const int tid = threadIdx.x;
  const int w = tid >> 6, lane = tid & 63;

  // stage T row (bf16 -> f32): 9216 elems, 1024 threads, 4 at a time
  for (int i = tid * 4; i < 9216; i += 4096) {
    u16x4 t4 = *(const u16x4*)&T[(size_t)r * 9216 + i];
    TlF[i] = bf2f(t4.x); TlF[i+1] = bf2f(t4.y); TlF[i+2] = bf2f(t4.z); TlF[i+3] = bf2f(t4.w);
  }
  // qb[h] = q_h . bk_h  (waves 0..11, wave-parallel reduce)
  if (w < 12) {
    float p = bf2f(qkv[(size_t)r * 2304 + w * 64 + lane]) * bk[w * 64 + lane];
    #pragma unroll
    for (int s = 32; s; s >>= 1) p += __shfl_xor(p, s);
    if (lane == 0) qb[w] = p;
  }
  __syncthreads();

  // wave w = sim index m: se row in registers, dot vs 12 T rows from LDS
  float4 sv4[3];
  #pragma unroll
  for (int c = 0; c < 3; c++)
    sv4[c] = *(const float4*)&se[(size_t)r * 12288 + w * 768 + lane * 4 + 256 * c];
  #pragma unroll
  for (int h = 0; h < 12; h++) {
    float s = 0.f;
    #pragma unroll
    for (int c = 0; c < 3; c++) {
      float4 t4 = *(const float4*)&TlF[h * 768 + lane * 4 + 256 * c];
      s += sv4[c].x * t4.x + sv4[c].y * t4.y + sv4[c].z * t4.z + sv4[c].w * t4.w;
    }
    #pragma unroll
    for (int sft = 32; sft; sft >>= 1) s += __shfl_xor(s, sft);
    if (lane == 0) ls[(size_t)r * 192 + h * 16 + w] = (s + qb[h]) * 0.125f;
  }
}

// ------------------------------ attention core -----------------------------
// One block per (b,h); 4 waves, 64 query rows each.  QK^T and PV via MFMA.
// Softmax over 256 self + 16 sim logits, fully in registers + 16-lane shfl.

__global__ __launch_bounds__(256, 1)
void attn_kernel(const unsigned short* __restrict__ qkv,
                 const float* __restrict__ ls,
                 unsigned short* __restrict__ att,
                 float* __restrict__ a_sim,
                 float* __restrict__ asum)
{
  const int b = blockIdx.x / 12;
  const int h = blockIdx.x % 12;
  const int tid = threadIdx.x;
  const int lane = tid & 63;
  const int w = tid >> 6;
  const int lr = lane & 15, kg = lane >> 4;
  const size_t rowbase = (size_t)b * 256;

  __shared__ __align__(16) char smem[107520];
  unsigned short* Qs = (unsigned short*)smem;             // [256][72]
  unsigned short* Ks = (unsigned short*)(smem + 36864);   // [256][72]
  unsigned short* VT = (unsigned short*)(smem + 73728);   // [64][264]  VT[d][k]=V[k][d]
  unsigned short* aL = (unsigned short*)(smem + (size_t)w * 17408); // [64][136]/wave, aliases Qs/Ks

  for (int j = tid * 4; j < 256 * 64; j += 1024) {
    const int row = j >> 6, d = j & 63;
    const unsigned short* qp = qkv + (rowbase + row) * 2304 + h * 64 + d;
    u16x4 qv = *(const u16x4*)qp;
    u16x4 kv = *(const u16x4*)(qp + 768);
    *(u16x4*)&Qs[row * 72 + d] = qv;
    *(u16x4*)&Ks[row * 72 + d] = kv;
  }
  for (int i = 0; i < 64; ++i) {       // V transpose: lane=d, rows kk
    const int kk = w * 64 + i;
    VT[lane * 264 + kk] = qkv[(rowbase + kk) * 2304 + 1536 + h * 64 + lane];
  }
  __syncthreads();

  const int n0 = w * 64;
  f32x4 acc[4][16];
  #pragma unroll
  for (int m = 0; m < 4; m++)
    #pragma unroll
    for (int n = 0; n < 16; n++)
      #pragma unroll
      for (int q = 0; q < 4; q++) acc[m][n][q] = 0.f;

  #pragma unroll
  for (int ks = 0; ks < 64; ks += 32) {           // QK^T, K=64
    short8 af[4];
    #pragma unroll
    for (int m = 0; m < 4; m++) af[m] = *(const short8*)&Qs[(n0 + m * 16 + lr) * 72 + ks + kg * 8];
    #pragma unroll
    for (int n = 0; n < 16; n++) {
      short8 bfr = *(const short8*)&Ks[(n * 16 + lr) * 72 + ks + kg * 8];
      #pragma unroll
      for (int m = 0; m < 4; m++)
        acc[m][n] = __builtin_amdgcn_mfma_f32_16x16x32_bf16(af[m], bfr, acc[m][n], 0, 0, 0);
    }
  }

  float inv_[4][4];
  #pragma unroll
  for (int m = 0; m < 4; m++) {
    #pragma unroll
    for (int j = 0; j < 4; j++) {
      float vmx = -1e30f;
      #pragma unroll
      for (int n = 0; n < 16; n++) { float s = acc[m][n][j] * 0.125f; acc[m][n][j] = s; vmx = fmaxf(vmx, s); }
      const int row = n0 + m * 16 + kg * 4 + j;
      const float lsim = ls[(rowbase + row) * 192 + h * 16 + lr];   // lr = sim index (M=16)
      vmx = fmaxf(vmx, lsim);
      #pragma unroll
      for (int s = 1; s < 16; s <<= 1) vmx = fmaxf(vmx, __shfl_xor(vmx, s));
      float sum = 0.f;
      #pragma unroll
      for (int n = 0; n < 16; n++) { float e = __expf(acc[m][n][j] - vmx); acc[m][n][j] = e; sum += e; }
      const float es = __expf(lsim - vmx);
      float ssum = es;
      sum += es;
      #pragma unroll
      for (int s = 1; s < 16; s <<= 1) { sum += __shfl_xor(sum, s); ssum += __shfl_xor(ssum, s); }
      const float inv = 1.0f / sum;
      inv_[m][j] = inv;
      a_sim[(((size_t)b * 12 + h) * 256 + row) * 16 + lr] = es * inv;
      if (lr == 0) asum[(rowbase + row) * 12 + h] = ssum * inv;
    }
  }

  __syncthreads();   // all waves done reading Qs/Ks before aL overwrites them

  f32x4 acc2[4][4];
  #pragma unroll
  for (int m = 0; m < 4; m++)
    #pragma unroll
    for (int n = 0; n < 4; n++)
      #pragma unroll
      for (int q = 0; q < 4; q++) acc2[m][n][q] = 0.f;

  #pragma unroll
  for (int hl = 0; hl < 2; ++hl) {   // PV in two 128-col halves (LDS budget)
    #pragma unroll
    for (int m = 0; m < 4; m++)
      #pragma unroll
      for (int j = 0; j < 4; j++) {
        const int rw = m * 16 + kg * 4 + j;
        #pragma unroll
        for (int n2 = 0; n2 < 8; n2++)
          aL[rw * 136 + n2 * 16 + lr] = f2bf(acc[m][hl * 8 + n2][j] * inv_[m][j]);
      }
    #pragma unroll
    for (int ks2 = 0; ks2 < 4; ++ks2) {   // out^T = VT * a^T
      short8 vf[4], pf[4];
      #pragma unroll
      for (int mm = 0; mm < 4; mm++)
        vf[mm] = *(const short8*)&VT[(mm * 16 + lr) * 264 + hl * 128 + ks2 * 32 + kg * 8];
      #pragma unroll
      for (int nn = 0; nn < 4; nn++)
        pf[nn] = *(const short8*)&aL[(nn * 16 + lr) * 136 + ks2 * 32 + kg * 8];
      #pragma unroll
      for (int mm = 0; mm < 4; mm++)
        #pragma unroll
        for (int nn = 0; nn < 4; nn++)
          acc2[mm][nn] = __builtin_amdgcn_mfma_f32_16x16x32_bf16(vf[mm], pf[nn], acc2[mm][nn], 0, 0, 0);
    }
  }

  #pragma unroll
  for (int mm = 0; mm < 4; mm++)      // D rows = dh, D cols = query row
    #pragma unroll
    for (int nn = 0; nn < 4; nn++)
      #pragma unroll
      for (int j = 0; j < 4; j++) {
        const int dh = mm * 16 + kg * 4 + j;
        const int rn = n0 + nn * 16 + lr;
        att[(rowbase + rn) * 768 + h * 64 + dh] = f2bf(acc2[mm][nn][j]);
      }
}

// ------------------------------ s_v (se pass 2) ----------------------------
// One block per (b,n): s_v[h,D] = sum_m a_sim[h,m] * se[m,D]  (bf16 out)

__global__ __launch_bounds__(256)
void sv_kernel(const float* __restrict__ se, const float* __restrict__ a_sim,
               unsigned short* __restrict__ s_v)
{
  const int r = blockIdx.x;
  const int b = r >> 8, n = r & 255;
  __shared__ float al[192];
  const int tid = threadIdx.x;
  if (tid < 192) {
    const int hh = tid >> 4, m = tid & 15;
    al[tid] = a_sim[(((size_t)b * 12 + hh) * 256 + n) * 16 + m];
  }
  __syncthreads();
  #pragma unroll
  for (int j = 0; j < 3; j++) {
    const int d = tid + j * 256;
    float accv[12];
    #pragma unroll
    for (int hh = 0; hh < 12; hh++) accv[hh] = 0.f;
    for (int m = 0; m < 16; m++) {
      const float xv = se[(size_t)r * 12288 + m * 768 + d];
      #pragma unroll
      for (int hh = 0; hh < 12; hh++) accv[hh] += al[hh * 16 + m] * xv;
    }
    #pragma unroll
    for (int hh = 0; hh < 12; hh++) s_v[((size_t)r * 12 + hh) * 768 + d] = f2bf(accv[hh]);
  }
}

// ------------------------------- launcher ----------------------------------

extern "C" void kernel_launch(void* const* d_in, const int* in_sizes, int n_in,
                              void* d_out, int out_size, void* d_ws, size_t ws_size,
                              hipStream_t stream) {
  const float* x  = (const float*)d_in[0];
  const float* se = (const float*)d_in[1];
  const float* Wq = (const float*)d_in[2];
  const float* bq = (const float*)d_in[3];
  const float* Wk = (const float*)d_in[4];
  const float* bk = (const float*)d_in[5];
  const float* Wv = (const float*)d_in[6];
  const float* bv = (const float*)d_in[7];
  const float* Wp = (const float*)d_in[8];
  const float* bp = (const float*)d_in[9];
  float* out = (float*)d_out;
  char* ws = (char*)d_ws;

  // workspace layout (all offsets 256B-aligned), total ~119.5 MB
  unsigned short* x_bf   = (unsigned short*)(ws);                 // 4096x768        bf16
  unsigned short* Wqkv_t = (unsigned short*)(ws + 6291456);       // 2368x768 (pad)  bf16, rows: Wq^T|Wk^T|Wv^T
  unsigned short* Wp_t   = (unsigned short*)(ws + 9928704);       // 768x768         bf16
  unsigned short* Wk_bf  = (unsigned short*)(ws + 11108352);      // 768x768         bf16 (untransposed)
  float*          bqkv   = (float*)(ws + 12288000);               // 2304            f32
  unsigned short* qkv    = (unsigned short*)(ws + 12297216);      // 4096x2304       bf16  q|k|v
  unsigned short* Tbuf   = (unsigned short*)(ws + 31171584);      // 4096x12x768     bf16  T, then s_v
  float*          lsb    = (float*)(ws + 106669056);              // 4096x12x16      f32
  float*          a_simb = (float*)(ws + 109814784);              // 16x12x256x16    f32
  float*          asumb  = (float*)(ws + 112960512);              // 4096x12         f32
  unsigned short* att    = (unsigned short*)(ws + 113157120);     // 4096x768        bf16

  cast_bf16<<<3072, 256, 0, stream>>>(x, x_bf, 3145728);
  transpose_cast<<<576, 256, 0, stream>>>(Wq, Wqkv_t);
  transpose_cast<<<576, 256, 0, stream>>>(Wk, Wqkv_t + 768 * 768);
  transpose_cast<<<576, 256, 0, stream>>>(Wv, Wqkv_t + 1536 * 768);
  transpose_cast<<<576, 256, 0, stream>>>(Wp, Wp_t);
  cast_bf16<<<576, 256, 0, stream>>>(Wk, Wk_bf, 589824);
  concat_bias<<<9, 256, 0, stream>>>(bq, bk, bv, bqkv);

  // qkv = x @ [Wq|Wk|Wv] + bias  (M=4096, N=2304, K=768)
  gemm_bt<true, false, false><<<dim3(32, 18, 1), 256, 0, stream>>>(
      x_bf, 768, 0, Wqkv_t, 768, 0, qkv, 2304, 0, 4096, 2304, 768, bqkv, nullptr, 0, nullptr, 0);
  // T[r,h,:] = q_h @ Wk_h^T  (per-head z=12, K=64)
  gemm_bt<true, false, false><<<dim3(32, 6, 12), 256, 0, stream>>>(
      qkv, 2304, 64, Wk_bf, 768, 64, Tbuf, 9216, 768, 4096, 768, 64, nullptr, nullptr, 0, nullptr, 0);

  sim_logits_kernel<<<4096, 1024, 0, stream>>>(se, Tbuf, qkv, bk, lsb);
  attn_kernel<<<192, 256, 0, stream>>>(qkv, lsb, att, a_simb, asumb);
  sv_kernel<<<4096, 256, 0, stream>>>(se, a_simb, Tbuf /* reused as s_v */);

  // att += s_v_h @ Wv_h  (+ asum*bv_h)   (per-head z=12, N=64, K=768)
  gemm_bt<true, true, true><<<dim3(32, 1, 12), 256, 0, stream>>>(
      Tbuf, 9216, 768, Wqkv_t + 1536 * 768, 768, 64 * 768, att, 768, 64,
      4096, 64, 768, nullptr, bv, 64, asumb, 12);
  // out = att @ Wp + bp  (f32 out)
  gemm_bt<false, false, false><<<dim3(32, 6, 1), 256, 0, stream>>>(
      att, 768, 0, Wp_t, 768, 0, out, 768, 0, 4096, 768, 768, bp, nullptr, 0, nullptr, 0);
}

// Round 3
// 377.142 us; speedup vs baseline: 1.9243x; 1.0456x over previous
//
#include <hip/hip_runtime.h>

// ---------------------------------------------------------------------------
// AsymAttention on MI355X (gfx950).
// B=16, N=256, M=16, D=768, H=12, Dh=64.  scale = 1/8.
//
// Algebraic refactors:
//  (1) avoid sim k/v projections (155 GF):
//      logits_sim[b,h,n,m] = (se[b,n,m,:].T_row + q_h.bk_h) * scale,
//          T[b,n,h,D] = sum_dh q[b,h,n,dh] * Wk[D, h*64+dh]       (K=64 GEMM)
//      out_sim = Wv_h^T s_v + (sum a_sim) bv,  s_v = sum_m a_sim[m] se[b,n,m,:]
//  (2) single se pass: attn_self emits UNNORMALIZED out_self + (m_self,sum_self);
//      fused_sim computes sim logits, joint-softmax renorm factors, and s_v in
//      one kernel (se row read once from HBM, phase-B re-read hits L2).
//      Final combine folded into the out_sim GEMM epilogue.
// ---------------------------------------------------------------------------

typedef __attribute__((ext_vector_type(8))) short short8;   // 8 x bf16 (MFMA frag)
typedef __attribute__((ext_vector_type(4))) float f32x4;    // MFMA acc
typedef __attribute__((ext_vector_type(4))) unsigned short u16x4;

__device__ __forceinline__ float bf2f(unsigned short u) {
  union { unsigned int i; float f; } c; c.i = ((unsigned int)u) << 16; return c.f;
}
__device__ __forceinline__ unsigned short f2bf(float f) {
  union { float f; unsigned int i; } c; c.f = f;
  unsigned int r = c.i + 0x7fffu + ((c.i >> 16) & 1u);   // RNE
  return (unsigned short)(r >> 16);
}

// --------------------------- small cast kernels ----------------------------

__global__ void cast_bf16(const float* __restrict__ in, unsigned short* __restrict__ out, int n) {
  int i = (blockIdx.x * 256 + threadIdx.x) * 4;
  if (i < n) {
    float4 v = *(const float4*)&in[i];
    out[i+0] = f2bf(v.x); out[i+1] = f2bf(v.y); out[i+2] = f2bf(v.z); out[i+3] = f2bf(v.w);
  }
}

// Wt[n][k] = W[k][n], bf16 out.  768x768, 32x32 tiles, 576 blocks.
__global__ void transpose_cast(const float* __restrict__ W, unsigned short* __restrict__ Wt) {
  __shared__ float tile[32][33];
  int bx = blockIdx.x % 24, by = blockIdx.x / 24;
  int n0 = bx * 32, k0 = by * 32;
  int tid = threadIdx.x;
  for (int l = tid; l < 1024; l += 256) {
    int i = l >> 5, j = l & 31;
    tile[i][j] = W[(size_t)(k0 + i) * 768 + n0 + j];
  }
  __syncthreads();
  for (int l = tid; l < 1024; l += 256) {
    int i = l >> 5, j = l & 31;
    Wt[(size_t)(n0 + i) * 768 + k0 + j] = f2bf(tile[j][i]);
  }
}

__global__ void concat_bias(const float* __restrict__ bq, const float* __restrict__ bk,
                            const float* __restrict__ bv, float* __restrict__ o) {
  int i = blockIdx.x * 256 + threadIdx.x;
  if (i < 2304) o[i] = (i < 768) ? bq[i] : ((i < 1536) ? bk[i - 768] : bv[i - 1536]);
}

// ------------------------------- GEMM (m97 pattern) ------------------------
// C[M x Nvalid] = A[M x K](bf16,row-major) * Bt[N x K]^T (+bias) ; 128x128 tile,
// BK=32, 4 waves (2x2), 4x4 frags/wave, global_load_lds width 16.
// SELFC epilogue: C = selfacc*scl + acc + simw*bv2  (joint-softmax combine).

template<bool OUT_BF16, bool SELFC>
__global__ __launch_bounds__(256)
void gemm_bt(const unsigned short* __restrict__ A, int lda, int zsA,
             const unsigned short* __restrict__ Bt, int ldb, int zsB,
             void* __restrict__ Cv, int ldc, int zsC,
             int M, int Nvalid, int K,
             const float* __restrict__ bias,
             const float* __restrict__ selfacc,
             const float* __restrict__ scl,
             const float* __restrict__ simw,
             const float* __restrict__ bv2)
{
  const int z = blockIdx.z;
  A  += (size_t)zsA * z;
  Bt += (size_t)zsB * z;
  const int row0 = blockIdx.x * 128;
  const int col0 = blockIdx.y * 128;
  __shared__ __align__(16) unsigned short lgA[128 * 32];
  __shared__ __align__(16) unsigned short lgB[128 * 32];
  const int tid = threadIdx.x;
  const int lane = tid & 63;
  const int w = tid >> 6;
  const int wr = w >> 1, wc = w & 1;
  const int lr = lane & 15, kg = lane >> 4;

  f32x4 acc[4][4];
  #pragma unroll
  for (int m = 0; m < 4; m++)
    #pragma unroll
    for (int n = 0; n < 4; n++)
      #pragma unroll
      for (int q = 0; q < 4; q++) acc[m][n][q] = 0.f;

  for (int k0 = 0; k0 < K; k0 += 32) {
    __syncthreads();
    #pragma unroll
    for (int it = 0; it < 2; ++it) {
      const int off  = it * 4096 + tid * 16;
      const int row  = off >> 6;
      const int colb = off & 63;
      const char* ga = (const char*)A + (size_t)(row0 + row) * (lda * 2) + k0 * 2 + colb;
      char* la = (char*)lgA + it * 4096 + w * 1024;
      __builtin_amdgcn_global_load_lds((const __attribute__((address_space(1))) unsigned int*)ga,
                                       (__attribute__((address_space(3))) unsigned int*)la, 16, 0, 0);
      const char* gb = (const char*)Bt + (size_t)(col0 + row) * (ldb * 2) + k0 * 2 + colb;
      char* lb = (char*)lgB + it * 4096 + w * 1024;
      __builtin_amdgcn_global_load_lds((const __attribute__((address_space(1))) unsigned int*)gb,
                                       (__attribute__((address_space(3))) unsigned int*)lb, 16, 0, 0);
    }
    __syncthreads();
    short8 af[4], bfr[4];
    #pragma unroll
    for (int m = 0; m < 4; m++) af[m]  = *(const short8*)&lgA[(wr * 64 + m * 16 + lr) * 32 + kg * 8];
    #pragma unroll
    for (int n = 0; n < 4; n++) bfr[n] = *(const short8*)&lgB[(wc * 64 + n * 16 + lr) * 32 + kg * 8];
    #pragma unroll
    for (int m = 0; m < 4; m++)
      #pragma unroll
      for (int n = 0; n < 4; n++)
        acc[m][n] = __builtin_amdgcn_mfma_f32_16x16x32_bf16(af[m], bfr[n], acc[m][n], 0, 0, 0);
  }

  // epilogue: C layout col=lane&15, row=(lane>>4)*4+reg
  #pragma unroll
  for (int m = 0; m < 4; m++) {
    #pragma unroll
    for (int n = 0; n < 4; n++) {
      const int gc = col0 + wc * 64 + n * 16 + lr;
      if (gc >= Nvalid) continue;
      #pragma unroll
      for (int j = 0; j < 4; j++) {
        const int gr = row0 + wr * 64 + m * 16 + kg * 4 + j;
        if (gr >= M) continue;
        float v = acc[m][n][j];
        if (bias) v += bias[gc];
        if (SELFC) {
          v += selfacc[(size_t)gr * 768 + z * 64 + gc] * scl[(size_t)gr * 12 + z]
             + simw[(size_t)gr * 12 + z] * bv2[z * 64 + gc];
        }
        const size_t idx = (size_t)gr * ldc + gc;
        if (OUT_BF16) {
          unsigned short* C = (unsigned short*)Cv + (size_t)zsC * z;
          C[idx] = f2bf(v);
        } else {
          float* C = (float*)Cv + (size_t)zsC * z;
          C[idx] = v;
        }
      }
    }
  }
}

// --------------------------- self attention ---------------------------------
// One block per (b,h); 4 waves, 64 query rows each.  QK^T and PV via MFMA.
// Softmax over the 256 SELF logits only; emits UNNORMALIZED out_self (f32)
// plus per-row stats (m_self, sum_self) for the joint renorm in fused_sim.

__global__ __launch_bounds__(256, 1)
void attn_self_kernel(const unsigned short* __restrict__ qkv,
                      float* __restrict__ selfacc,
                      float* __restrict__ mstat,
                      float* __restrict__ sstat)
{
  const int b = blockIdx.x / 12;
  const int h = blockIdx.x % 12;
  const int tid = threadIdx.x;
  const int lane = tid & 63;
  const int w = tid >> 6;
  const int lr = lane & 15, kg = lane >> 4;
  const size_t rowbase = (size_t)b * 256;

  __shared__ __align__(16) char smem[107520];
  unsigned short* Qs = (unsigned short*)smem;             // [256][72]
  unsigned short* Ks = (unsigned short*)(smem + 36864);   // [256][72]
  unsigned short* VT = (unsigned short*)(smem + 73728);   // [64][264]  VT[d][k]=V[k][d]
  unsigned short* aL = (unsigned short*)(smem + (size_t)w * 17408); // [64][136]/wave, aliases Qs/Ks

  for (int j = tid * 4; j < 256 * 64; j += 1024) {
    const int row = j >> 6, d = j & 63;
    const unsigned short* qp = qkv + (rowbase + row) * 2304 + h * 64 + d;
    u16x4 qv = *(const u16x4*)qp;
    u16x4 kv = *(const u16x4*)(qp + 768);
    *(u16x4*)&Qs[row * 72 + d] = qv;
    *(u16x4*)&Ks[row * 72 + d] = kv;
  }
  for (int i = 0; i < 64; ++i) {       // V transpose: lane=d, rows kk
    const int kk = w * 64 + i;
    VT[lane * 264 + kk] = qkv[(rowbase + kk) * 2304 + 1536 + h * 64 + lane];
  }
  __syncthreads();

  const int n0 = w * 64;
  f32x4 acc[4][16];
  #pragma unroll
  for (int m = 0; m < 4; m++)
    #pragma unroll
    for (int n = 0; n < 16; n++)
      #pragma unroll
      for (int q = 0; q < 4; q++) acc[m][n][q] = 0.f;

  #pragma unroll
  for (int ks = 0; ks < 64; ks += 32) {           // QK^T, K=64
    short8 af[4];
    #pragma unroll
    for (int m = 0; m < 4; m++) af[m] = *(const short8*)&Qs[(n0 + m * 16 + lr) * 72 + ks + kg * 8];
    #pragma unroll
    for (int n = 0; n < 16; n++) {
      short8 bfr = *(const short8*)&Ks[(n * 16 + lr) * 72 + ks + kg * 8];
      #pragma unroll
      for (int m = 0; m < 4; m++)
        acc[m][n] = __builtin_amdgcn_mfma_f32_16x16x32_bf16(af[m], bfr, acc[m][n], 0, 0, 0);
    }
  }

  #pragma unroll
  for (int m = 0; m < 4; m++) {
    #pragma unroll
    for (int j = 0; j < 4; j++) {
      float vmx = -1e30f;
      #pragma unroll
      for (int n = 0; n < 16; n++) { float s = acc[m][n][j] * 0.125f; acc[m][n][j] = s; vmx = fmaxf(vmx, s); }
      #pragma unroll
      for (int s = 1; s < 16; s <<= 1) vmx = fmaxf(vmx, __shfl_xor(vmx, s));
      float sum = 0.f;
      #pragma unroll
      for (int n = 0; n < 16; n++) { float e = __expf(acc[m][n][j] - vmx); acc[m][n][j] = e; sum += e; }
      #pragma unroll
      for (int s = 1; s < 16; s <<= 1) sum += __shfl_xor(sum, s);
      if (lr == 0) {
        const int row = n0 + m * 16 + kg * 4 + j;
        mstat[(rowbase + row) * 12 + h] = vmx;
        sstat[(rowbase + row) * 12 + h] = sum;
      }
    }
  }

  __syncthreads();   // all waves done reading Qs/Ks before aL overwrites them

  f32x4 acc2[4][4];
  #pragma unroll
  for (int m = 0; m < 4; m++)
    #pragma unroll
    for (int n = 0; n < 4; n++)
      #pragma unroll
      for (int q = 0; q < 4; q++) acc2[m][n][q] = 0.f;

  #pragma unroll
  for (int hl = 0; hl < 2; ++hl) {   // PV in two 128-col halves (LDS budget)
    #pragma unroll
    for (int m = 0; m < 4; m++)
      #pragma unroll
      for (int j = 0; j < 4; j++) {
        const int rw = m * 16 + kg * 4 + j;
        #pragma unroll
        for (int n2 = 0; n2 < 8; n2++)
          aL[rw * 136 + n2 * 16 + lr] = f2bf(acc[m][hl * 8 + n2][j]);   // unnormalized
      }
    #pragma unroll
    for (int ks2 = 0; ks2 < 4; ++ks2) {   // out^T = VT * a^T
      short8 vf[4], pf[4];
      #pragma unroll
      for (int mm = 0; mm < 4; mm++)
        vf[mm] = *(const short8*)&VT[(mm * 16 + lr) * 264 + hl * 128 + ks2 * 32 + kg * 8];
      #pragma unroll
      for (int nn = 0; nn < 4; nn++)
        pf[nn] = *(const short8*)&aL[(nn * 16 + lr) * 136 + ks2 * 32 + kg * 8];
      #pragma unroll
      for (int mm = 0; mm < 4; mm++)
        #pragma unroll
        for (int nn = 0; nn < 4; nn++)
          acc2[mm][nn] = __builtin_amdgcn_mfma_f32_16x16x32_bf16(vf[mm], pf[nn], acc2[mm][nn], 0, 0, 0);
    }
  }

  #pragma unroll
  for (int mm = 0; mm < 4; mm++)      // D rows = dh, D cols = query row
    #pragma unroll
    for (int nn = 0; nn < 4; nn++)
      #pragma unroll
      for (int j = 0; j < 4; j++) {
        const int dh = mm * 16 + kg * 4 + j;
        const int rn = n0 + nn * 16 + lr;
        selfacc[(rowbase + rn) * 768 + h * 64 + dh] = acc2[mm][nn][j];   // f32 unnorm
      }
}

// --------------------- fused sim logits + renorm + s_v ---------------------
// One block per (b,n), 16 waves.
// A : wave m streams se[r,m,:] into regs, dots vs T row (LDS) -> ls[h][m]
// A2: wave h (lanes 0..15) joins with (m_self,sum_self): global max, Z,
//     normalized sim weights -> LDS; writes scale & simw.
// B : threads 0..767 (d) compute s_v[h,d] = sum_m a_norm[h,m]*se[m,d]
//     (se re-read hits L2) and store bf16.

__global__ __launch_bounds__(1024)
void fused_sim_kernel(const float* __restrict__ se, const unsigned short* __restrict__ T,
                      const unsigned short* __restrict__ qkv, const float* __restrict__ bk,
                      const float* __restrict__ mstat, const float* __restrict__ sstat,
                      unsigned short* __restrict__ s_v,
                      float* __restrict__ sclA, float* __restrict__ simwA)
{
  const int r = blockIdx.x;                    // b*256+n
  __shared__ float TlF[12 * 768];
  __shared__ float qb[12];
  __shared__ float lsL[192];
  __shared__ float anL[192];
  const int tid = threadIdx.x;
  const int w = tid >> 6, lane = tid & 63;

  // stage T row (bf16 -> f32)
  for (int i = tid * 4; i < 9216; i += 4096) {
    u16x4 t4 = *(const u16x4*)&T[(size_t)r * 9216 + i];
    TlF[i] = bf2f(t4.x); TlF[i+1] = bf2f(t4.y); TlF[i+2] = bf2f(t4.z); TlF[i+3] = bf2f(t4.w);
  }
  // qb[h] = q_h . bk_h
  if (w < 12) {
    float p = bf2f(qkv[(size_t)r * 2304 + w * 64 + lane]) * bk[w * 64 + lane];
    #pragma unroll
    for (int s = 32; s; s >>= 1) p += __shfl_xor(p, s);
    if (lane == 0) qb[w] = p;
  }
  __syncthreads();

  // phase A: wave w = sim index m
  {
    float4 sv4[3];
    #pragma unroll
    for (int c = 0; c < 3; c++)
      sv4[c] = *(const float4*)&se[(size_t)r * 12288 + w * 768 + lane * 4 + 256 * c];
    #pragma unroll
    for (int h = 0; h < 12; h++) {
      float s = 0.f;
      #pragma unroll
      for (int c = 0; c < 3; c++) {
        float4 t4 = *(const float4*)&TlF[h * 768 + lane * 4 + 256 * c];
        s += sv4[c].x * t4.x + sv4[c].y * t4.y + sv4[c].z * t4.z + sv4[c].w * t4.w;
      }
      #pragma unroll
      for (int sft = 32; sft; sft >>= 1) s += __shfl_xor(s, sft);
      if (lane == 0) lsL[h * 16 + w] = (s + qb[h]) * 0.125f;
    }
  }
  __syncthreads();

  // phase A2: joint softmax renorm per head
  if (w < 12 && lane < 16) {
    const int h = w;
    const float l = lsL[h * 16 + lane];
    float mx = l;
    #pragma unroll
    for (int s = 1; s < 16; s <<= 1) mx = fmaxf(mx, __shfl_xor(mx, s));
    const float msf = mstat[(size_t)r * 12 + h];
    const float ssf = sstat[(size_t)r * 12 + h];
    const float mj = fmaxf(mx, msf);
    const float aun = __expf(l - mj);
    float ssum = aun;
    #pragma unroll
    for (int s = 1; s < 16; s <<= 1) ssum += __shfl_xor(ssum, s);
    const float alpha = __expf(msf - mj);
    const float invZ = 1.0f / (ssf * alpha + ssum);
    anL[h * 16 + lane] = aun * invZ;
    if (lane == 0) {
      sclA[(size_t)r * 12 + h]  = alpha * invZ;
      simwA[(size_t)r * 12 + h] = ssum * invZ;
    }
  }
  __syncthreads();

  // phase B: s_v (se re-read is L2-resident)
  if (tid < 768) {
    const int d = tid;
    float accv[12];
    #pragma unroll
    for (int h = 0; h < 12; h++) accv[h] = 0.f;
    #pragma unroll
    for (int m = 0; m < 16; m++) {
      const float sval = se[(size_t)r * 12288 + m * 768 + d];
      #pragma unroll
      for (int h = 0; h < 12; h++) accv[h] += anL[h * 16 + m] * sval;
    }
    #pragma unroll
    for (int h = 0; h < 12; h++) s_v[(size_t)r * 9216 + h * 768 + d] = f2bf(accv[h]);
  }
}

// ------------------------------- launcher ----------------------------------

extern "C" void kernel_launch(void* const* d_in, const int* in_sizes, int n_in,
                              void* d_out, int out_size, void* d_ws, size_t ws_size,
                              hipStream_t stream) {
  const float* x  = (const float*)d_in[0];
  const float* se = (const float*)d_in[1];
  const float* Wq = (const float*)d_in[2];
  const float* bq = (const float*)d_in[3];
  const float* Wk = (const float*)d_in[4];
  const float* bk = (const float*)d_in[5];
  const float* Wv = (const float*)d_in[6];
  const float* bv = (const float*)d_in[7];
  const float* Wp = (const float*)d_in[8];
  const float* bp = (const float*)d_in[9];
  float* out = (float*)d_out;
  char* ws = (char*)d_ws;

  // workspace layout (256B-aligned), total ~120.4 MB
  unsigned short* x_bf    = (unsigned short*)(ws);                 // 4096x768   bf16
  unsigned short* Wqkv_t  = (unsigned short*)(ws + 6291456);       // 2304x768   bf16  Wq^T|Wk^T|Wv^T rows
  unsigned short* Wp_t    = (unsigned short*)(ws + 9830400);       // 768x768    bf16
  unsigned short* Wk_bf   = (unsigned short*)(ws + 11010048);      // 768x768    bf16 (untransposed)
  float*          bqkv    = (float*)(ws + 12189696);               // 2304       f32
  unsigned short* qkv     = (unsigned short*)(ws + 12198912);      // 4096x2304  bf16  q|k|v
  unsigned short* Tbuf    = (unsigned short*)(ws + 31073280);      // 4096x12x768 bf16  T, then s_v
  float*          selfacc = (float*)(ws + 106570752);              // 4096x768   f32  unnorm out_self
  float*          mstat   = (float*)(ws + 119153664);              // 4096x12    f32
  float*          sstat   = (float*)(ws + 119350272);              // 4096x12    f32
  float*          sclA    = (float*)(ws + 119546880);              // 4096x12    f32
  float*          simwA   = (float*)(ws + 119743488);              // 4096x12    f32
  unsigned short* att     = (unsigned short*)(ws + 119940096);     // 4096x768   bf16

  cast_bf16<<<3072, 256, 0, stream>>>(x, x_bf, 3145728);
  transpose_cast<<<576, 256, 0, stream>>>(Wq, Wqkv_t);
  transpose_cast<<<576, 256, 0, stream>>>(Wk, Wqkv_t + 768 * 768);
  transpose_cast<<<576, 256, 0, stream>>>(Wv, Wqkv_t + 1536 * 768);
  transpose_cast<<<576, 256, 0, stream>>>(Wp, Wp_t);
  cast_bf16<<<576, 256, 0, stream>>>(Wk, Wk_bf, 589824);
  concat_bias<<<9, 256, 0, stream>>>(bq, bk, bv, bqkv);

  // qkv = x @ [Wq|Wk|Wv] + bias  (M=4096, N=2304, K=768)
  gemm_bt<true, false><<<dim3(32, 18, 1), 256, 0, stream>>>(
      x_bf, 768, 0, Wqkv_t, 768, 0, qkv, 2304, 0, 4096, 2304, 768,
      bqkv, nullptr, nullptr, nullptr, nullptr);
  // T[r,h,:] = q_h @ Wk_h^T  (per-head z=12, K=64)
  gemm_bt<true, false><<<dim3(32, 6, 12), 256, 0, stream>>>(
      qkv, 2304, 64, Wk_bf, 768, 64, Tbuf, 9216, 768, 4096, 768, 64,
      nullptr, nullptr, nullptr, nullptr, nullptr);

  attn_self_kernel<<<192, 256, 0, stream>>>(qkv, selfacc, mstat, sstat);
  fused_sim_kernel<<<4096, 1024, 0, stream>>>(se, Tbuf, qkv, bk, mstat, sstat,
                                              Tbuf /* s_v overwrites T in-place per r */,
                                              sclA, simwA);

  // att = selfacc*scl + s_v_h @ Wv_h + simw*bv_h   (per-head z=12, N=64, K=768)
  gemm_bt<true, true><<<dim3(32, 1, 12), 256, 0, stream>>>(
      Tbuf, 9216, 768, Wqkv_t + 1536 * 768, 768, 64 * 768, att, 768, 64,
      4096, 64, 768, nullptr, selfacc, sclA, simwA, bv);
  // out = att @ Wp + bp  (f32 out)
  gemm_bt<false, false><<<dim3(32, 6, 1), 256, 0, stream>>>(
      att, 768, 0, Wp_t, 768, 0, out, 768, 0, 4096, 768, 768,
      bp, nullptr, nullptr, nullptr, nullptr);
}

// Round 4
// 329.543 us; speedup vs baseline: 2.2023x; 1.1444x over previous
//
#include <hip/hip_runtime.h>

// ---------------------------------------------------------------------------
// AsymAttention on MI355X (gfx950).
// B=16, N=256, M=16, D=768, H=12, Dh=64.  scale = 1/8.
//
// Algebraic refactors:
//  (1) avoid sim k/v projections (155 GF):
//      logits_sim[b,h,n,m] = (se[b,n,m,:].T_row + q_h.bk_h) * scale,
//          T[b,n,h,D] = sum_dh q[b,h,n,dh] * Wk[D, h*64+dh]       (K=64 GEMM)
//      out_sim = Wv_h^T s_v + (sum a_sim) bv,  s_v = sum_m a_sim[m] se[b,n,m,:]
//  (2) single se pass: attn_self emits UNNORMALIZED out_self + (m_self,sum_self);
//      fused_sim computes sim logits (MFMA), joint-softmax renorm factors, and
//      s_v (MFMA) in one kernel.  Combine folded into the out_sim GEMM epilogue.
// ---------------------------------------------------------------------------

typedef __attribute__((ext_vector_type(8))) short short8;   // 8 x bf16 (MFMA frag)
typedef __attribute__((ext_vector_type(4))) float f32x4;    // MFMA acc
typedef __attribute__((ext_vector_type(4))) unsigned short u16x4;

__device__ __forceinline__ float bf2f(unsigned short u) {
  union { unsigned int i; float f; } c; c.i = ((unsigned int)u) << 16; return c.f;
}
__device__ __forceinline__ unsigned short f2bf(float f) {
  union { float f; unsigned int i; } c; c.f = f;
  unsigned int r = c.i + 0x7fffu + ((c.i >> 16) & 1u);   // RNE
  return (unsigned short)(r >> 16);
}

// --------------------------- small cast kernels ----------------------------

__global__ void cast_bf16(const float* __restrict__ in, unsigned short* __restrict__ out, int n) {
  int i = (blockIdx.x * 256 + threadIdx.x) * 4;
  if (i < n) {
    float4 v = *(const float4*)&in[i];
    out[i+0] = f2bf(v.x); out[i+1] = f2bf(v.y); out[i+2] = f2bf(v.z); out[i+3] = f2bf(v.w);
  }
}

// Wt[n][k] = W[k][n], bf16 out.  768x768, 32x32 tiles, 576 blocks.
__global__ void transpose_cast(const float* __restrict__ W, unsigned short* __restrict__ Wt) {
  __shared__ float tile[32][33];
  int bx = blockIdx.x % 24, by = blockIdx.x / 24;
  int n0 = bx * 32, k0 = by * 32;
  int tid = threadIdx.x;
  for (int l = tid; l < 1024; l += 256) {
    int i = l >> 5, j = l & 31;
    tile[i][j] = W[(size_t)(k0 + i) * 768 + n0 + j];
  }
  __syncthreads();
  for (int l = tid; l < 1024; l += 256) {
    int i = l >> 5, j = l & 31;
    Wt[(size_t)(n0 + i) * 768 + k0 + j] = f2bf(tile[j][i]);
  }
}

__global__ void concat_bias(const float* __restrict__ bq, const float* __restrict__ bk,
                            const float* __restrict__ bv, float* __restrict__ o) {
  int i = blockIdx.x * 256 + threadIdx.x;
  if (i < 2304) o[i] = (i < 768) ? bq[i] : ((i < 1536) ? bk[i - 768] : bv[i - 1536]);
}

// ------------------------------- GEMM (m97 pattern) ------------------------
// C[M x Nvalid] = A[M x K](bf16,row-major) * Bt[N x K]^T (+bias) ; 128x128 tile,
// BK=32, 4 waves (2x2), 4x4 frags/wave, global_load_lds width 16.
// SELFC epilogue: C = selfacc*scl + acc + simw*bv2  (joint-softmax combine).

template<bool OUT_BF16, bool SELFC>
__global__ __launch_bounds__(256)
void gemm_bt(const unsigned short* __restrict__ A, int lda, int zsA,
             const unsigned short* __restrict__ Bt, int ldb, int zsB,
             void* __restrict__ Cv, int ldc, int zsC,
             int M, int Nvalid, int K,
             const float* __restrict__ bias,
             const float* __restrict__ selfacc,
             const float* __restrict__ scl,
             const float* __restrict__ simw,
             const float* __restrict__ bv2)
{
  const int z = blockIdx.z;
  A  += (size_t)zsA * z;
  Bt += (size_t)zsB * z;
  const int row0 = blockIdx.x * 128;
  const int col0 = blockIdx.y * 128;
  __shared__ __align__(16) unsigned short lgA[128 * 32];
  __shared__ __align__(16) unsigned short lgB[128 * 32];
  const int tid = threadIdx.x;
  const int lane = tid & 63;
  const int w = tid >> 6;
  const int wr = w >> 1, wc = w & 1;
  const int lr = lane & 15, kg = lane >> 4;

  f32x4 acc[4][4];
  #pragma unroll
  for (int m = 0; m < 4; m++)
    #pragma unroll
    for (int n = 0; n < 4; n++)
      #pragma unroll
      for (int q = 0; q < 4; q++) acc[m][n][q] = 0.f;

  for (int k0 = 0; k0 < K; k0 += 32) {
    __syncthreads();
    #pragma unroll
    for (int it = 0; it < 2; ++it) {
      const int off  = it * 4096 + tid * 16;
      const int row  = off >> 6;
      const int colb = off & 63;
      const char* ga = (const char*)A + (size_t)(row0 + row) * (lda * 2) + k0 * 2 + colb;
      char* la = (char*)lgA + it * 4096 + w * 1024;
      __builtin_amdgcn_global_load_lds((const __attribute__((address_space(1))) unsigned int*)ga,
                                       (__attribute__((address_space(3))) unsigned int*)la, 16, 0, 0);
      const char* gb = (const char*)Bt + (size_t)(col0 + row) * (ldb * 2) + k0 * 2 + colb;
      char* lb = (char*)lgB + it * 4096 + w * 1024;
      __builtin_amdgcn_global_load_lds((const __attribute__((address_space(1))) unsigned int*)gb,
                                       (__attribute__((address_space(3))) unsigned int*)lb, 16, 0, 0);
    }
    __syncthreads();
    short8 af[4], bfr[4];
    #pragma unroll
    for (int m = 0; m < 4; m++) af[m]  = *(const short8*)&lgA[(wr * 64 + m * 16 + lr) * 32 + kg * 8];
    #pragma unroll
    for (int n = 0; n < 4; n++) bfr[n] = *(const short8*)&lgB[(wc * 64 + n * 16 + lr) * 32 + kg * 8];
    #pragma unroll
    for (int m = 0; m < 4; m++)
      #pragma unroll
      for (int n = 0; n < 4; n++)
        acc[m][n] = __builtin_amdgcn_mfma_f32_16x16x32_bf16(af[m], bfr[n], acc[m][n], 0, 0, 0);
  }

  // epilogue: C layout col=lane&15, row=(lane>>4)*4+reg
  #pragma unroll
  for (int m = 0; m < 4; m++) {
    #pragma unroll
    for (int n = 0; n < 4; n++) {
      const int gc = col0 + wc * 64 + n * 16 + lr;
      if (gc >= Nvalid) continue;
      #pragma unroll
      for (int j = 0; j < 4; j++) {
        const int gr = row0 + wr * 64 + m * 16 + kg * 4 + j;
        if (gr >= M) continue;
        float v = acc[m][n][j];
        if (bias) v += bias[gc];
        if (SELFC) {
          v += selfacc[(size_t)gr * 768 + z * 64 + gc] * scl[(size_t)gr * 12 + z]
             + simw[(size_t)gr * 12 + z] * bv2[z * 64 + gc];
        }
        const size_t idx = (size_t)gr * ldc + gc;
        if (OUT_BF16) {
          unsigned short* C = (unsigned short*)Cv + (size_t)zsC * z;
          C[idx] = f2bf(v);
        } else {
          float* C = (float*)Cv + (size_t)zsC * z;
          C[idx] = v;
        }
      }
    }
  }
}

// --------------------------- self attention ---------------------------------
// One block per (b,h); 4 waves, 64 query rows each.  QK^T and PV via MFMA.
// Softmax over the 256 SELF logits only; emits UNNORMALIZED out_self (f32)
// plus per-row stats (m_self, sum_self) for the joint renorm in fused_sim.

__global__ __launch_bounds__(256, 1)
void attn_self_kernel(const unsigned short* __restrict__ qkv,
                      float* __restrict__ selfacc,
                      float* __restrict__ mstat,
                      float* __restrict__ sstat)
{
  const int b = blockIdx.x / 12;
  const int h = blockIdx.x % 12;
  const int tid = threadIdx.x;
  const int lane = tid & 63;
  const int w = tid >> 6;
  const int lr = lane & 15, kg = lane >> 4;
  const size_t rowbase = (size_t)b * 256;

  __shared__ __align__(16) char smem[107520];
  unsigned short* Qs = (unsigned short*)smem;             // [256][72]
  unsigned short* Ks = (unsigned short*)(smem + 36864);   // [256][72]
  unsigned short* VT = (unsigned short*)(smem + 73728);   // [64][264]  VT[d][k]=V[k][d]
  unsigned short* aL = (unsigned short*)(smem + (size_t)w * 17408); // [64][136]/wave, aliases Qs/Ks

  for (int j = tid * 4; j < 256 * 64; j += 1024) {
    const int row = j >> 6, d = j & 63;
    const unsigned short* qp = qkv + (rowbase + row) * 2304 + h * 64 + d;
    u16x4 qv = *(const u16x4*)qp;
    u16x4 kv = *(const u16x4*)(qp + 768);
    *(u16x4*)&Qs[row * 72 + d] = qv;
    *(u16x4*)&Ks[row * 72 + d] = kv;
  }
  for (int i = 0; i < 64; ++i) {       // V transpose: lane=d, rows kk
    const int kk = w * 64 + i;
    VT[lane * 264 + kk] = qkv[(rowbase + kk) * 2304 + 1536 + h * 64 + lane];
  }
  __syncthreads();

  const int n0 = w * 64;
  f32x4 acc[4][16];
  #pragma unroll
  for (int m = 0; m < 4; m++)
    #pragma unroll
    for (int n = 0; n < 16; n++)
      #pragma unroll
      for (int q = 0; q < 4; q++) acc[m][n][q] = 0.f;

  #pragma unroll
  for (int ks = 0; ks < 64; ks += 32) {           // QK^T, K=64
    short8 af[4];
    #pragma unroll
    for (int m = 0; m < 4; m++) af[m] = *(const short8*)&Qs[(n0 + m * 16 + lr) * 72 + ks + kg * 8];
    #pragma unroll
    for (int n = 0; n < 16; n++) {
      short8 bfr = *(const short8*)&Ks[(n * 16 + lr) * 72 + ks + kg * 8];
      #pragma unroll
      for (int m = 0; m < 4; m++)
        acc[m][n] = __builtin_amdgcn_mfma_f32_16x16x32_bf16(af[m], bfr, acc[m][n], 0, 0, 0);
    }
  }

  #pragma unroll
  for (int m = 0; m < 4; m++) {
    #pragma unroll
    for (int j = 0; j < 4; j++) {
      float vmx = -1e30f;
      #pragma unroll
      for (int n = 0; n < 16; n++) { float s = acc[m][n][j] * 0.125f; acc[m][n][j] = s; vmx = fmaxf(vmx, s); }
      #pragma unroll
      for (int s = 1; s < 16; s <<= 1) vmx = fmaxf(vmx, __shfl_xor(vmx, s));
      float sum = 0.f;
      #pragma unroll
      for (int n = 0; n < 16; n++) { float e = __expf(acc[m][n][j] - vmx); acc[m][n][j] = e; sum += e; }
      #pragma unroll
      for (int s = 1; s < 16; s <<= 1) sum += __shfl_xor(sum, s);
      if (lr == 0) {
        const int row = n0 + m * 16 + kg * 4 + j;
        mstat[(rowbase + row) * 12 + h] = vmx;
        sstat[(rowbase + row) * 12 + h] = sum;
      }
    }
  }

  __syncthreads();   // all waves done reading Qs/Ks before aL overwrites them

  f32x4 acc2[4][4];
  #pragma unroll
  for (int m = 0; m < 4; m++)
    #pragma unroll
    for (int n = 0; n < 4; n++)
      #pragma unroll
      for (int q = 0; q < 4; q++) acc2[m][n][q] = 0.f;

  #pragma unroll
  for (int hl = 0; hl < 2; ++hl) {   // PV in two 128-col halves (LDS budget)
    #pragma unroll
    for (int m = 0; m < 4; m++)
      #pragma unroll
      for (int j = 0; j < 4; j++) {
        const int rw = m * 16 + kg * 4 + j;
        #pragma unroll
        for (int n2 = 0; n2 < 8; n2++)
          aL[rw * 136 + n2 * 16 + lr] = f2bf(acc[m][hl * 8 + n2][j]);   // unnormalized
      }
    #pragma unroll
    for (int ks2 = 0; ks2 < 4; ++ks2) {   // out^T = VT * a^T
      short8 vf[4], pf[4];
      #pragma unroll
      for (int mm = 0; mm < 4; mm++)
        vf[mm] = *(const short8*)&VT[(mm * 16 + lr) * 264 + hl * 128 + ks2 * 32 + kg * 8];
      #pragma unroll
      for (int nn = 0; nn < 4; nn++)
        pf[nn] = *(const short8*)&aL[(nn * 16 + lr) * 136 + ks2 * 32 + kg * 8];
      #pragma unroll
      for (int mm = 0; mm < 4; mm++)
        #pragma unroll
        for (int nn = 0; nn < 4; nn++)
          acc2[mm][nn] = __builtin_amdgcn_mfma_f32_16x16x32_bf16(vf[mm], pf[nn], acc2[mm][nn], 0, 0, 0);
    }
  }

  #pragma unroll
  for (int mm = 0; mm < 4; mm++)      // D rows = dh, D cols = query row
    #pragma unroll
    for (int nn = 0; nn < 4; nn++)
      #pragma unroll
      for (int j = 0; j < 4; j++) {
        const int dh = mm * 16 + kg * 4 + j;
        const int rn = n0 + nn * 16 + lr;
        selfacc[(rowbase + rn) * 768 + h * 64 + dh] = acc2[mm][nn][j];   // f32 unnorm
      }
}

// --------------------- fused sim logits + renorm + s_v (MFMA) --------------
// One block per (b,n) = r, 4 waves, 256 threads.
//  stage : SE_T[768 d][16 m] bf16 in LDS (transpose, for s_v B-frags);
//          qb[h] = q_h.bk_h via wave reduce.
//  L-GEMM: L[16m][16h] = SE·T^T, mfma_16x16x32, K split 192/wave, A-frags
//          straight from global se (f32->bf16), B-frags straight from global T.
//          Partials summed via 4KB LDS.
//  softmax (per wave, redundant): column h = lane&15 lives in 4 lanes ->
//          3 local ops + 2 shfl_xor; joint renorm with (mstat,sstat).
//  s_v   : s_v[12h][768d] = a^T·SE.  a^T A-frag built from softmax regs with
//          8 shuffles (K=32, m 16..31 zero-padded: zero-A x dont-care-B = 0).
//          B-frag = one ds_read_b128 from SE_T.  12 tiles/wave.

__global__ __launch_bounds__(256, 4)
void fused_sim_kernel(const float* __restrict__ se, const unsigned short* __restrict__ T,
                      const unsigned short* __restrict__ qkv, const float* __restrict__ bk,
                      const float* __restrict__ mstat, const float* __restrict__ sstat,
                      unsigned short* __restrict__ s_v,
                      float* __restrict__ sclA, float* __restrict__ simwA)
{
  const int r = blockIdx.x;                    // b*256+n
  __shared__ __align__(16) unsigned short SE_T[768 * 16];  // [d][m] bf16, 24KB
  __shared__ float Lp[4 * 256];                            // [wave][m][h] f32, 4KB
  __shared__ float qb[16];
  const int tid = threadIdx.x;
  const int w = tid >> 6, lane = tid & 63;
  const int lr = lane & 15, kg = lane >> 4;

  // ---- stage SE_T (f32 -> bf16 transpose): unit u = (dblk, m) ----
  #pragma unroll
  for (int c = 0; c < 3; ++c) {
    const int u = tid + c * 256;
    const int dblk = u >> 4, m = u & 15;
    const float* src = &se[(size_t)r * 12288 + m * 768 + dblk * 16];
    float4 f0 = *(const float4*)(src);
    float4 f1 = *(const float4*)(src + 4);
    float4 f2 = *(const float4*)(src + 8);
    float4 f3 = *(const float4*)(src + 12);
    const int d0 = dblk * 16;
    SE_T[(d0+ 0)*16+m] = f2bf(f0.x); SE_T[(d0+ 1)*16+m] = f2bf(f0.y);
    SE_T[(d0+ 2)*16+m] = f2bf(f0.z); SE_T[(d0+ 3)*16+m] = f2bf(f0.w);
    SE_T[(d0+ 4)*16+m] = f2bf(f1.x); SE_T[(d0+ 5)*16+m] = f2bf(f1.y);
    SE_T[(d0+ 6)*16+m] = f2bf(f1.z); SE_T[(d0+ 7)*16+m] = f2bf(f1.w);
    SE_T[(d0+ 8)*16+m] = f2bf(f2.x); SE_T[(d0+ 9)*16+m] = f2bf(f2.y);
    SE_T[(d0+10)*16+m] = f2bf(f2.z); SE_T[(d0+11)*16+m] = f2bf(f2.w);
    SE_T[(d0+12)*16+m] = f2bf(f3.x); SE_T[(d0+13)*16+m] = f2bf(f3.y);
    SE_T[(d0+14)*16+m] = f2bf(f3.z); SE_T[(d0+15)*16+m] = f2bf(f3.w);
  }
  // qb[h] = q_h . bk_h  (3 heads per wave)
  #pragma unroll
  for (int i = 0; i < 3; ++i) {
    const int hh = w * 3 + i;
    float p = bf2f(qkv[(size_t)r * 2304 + hh * 64 + lane]) * bk[hh * 64 + lane];
    #pragma unroll
    for (int sft = 32; sft; sft >>= 1) p += __shfl_xor(p, sft);
    if (lane == 0) qb[hh] = p;
  }
  if (tid < 4) qb[12 + tid] = 0.f;
  __syncthreads();

  // ---- L-GEMM partial: wave w covers K in [w*192, (w+1)*192) ----
  f32x4 accL = {0.f, 0.f, 0.f, 0.f};
  #pragma unroll
  for (int s = 0; s < 6; ++s) {
    const int k0 = w * 192 + s * 32;
    const float* ap = &se[(size_t)r * 12288 + lr * 768 + k0 + kg * 8];
    float4 a0 = *(const float4*)ap;
    float4 a1 = *(const float4*)(ap + 4);
    short8 af;
    af[0] = f2bf(a0.x); af[1] = f2bf(a0.y); af[2] = f2bf(a0.z); af[3] = f2bf(a0.w);
    af[4] = f2bf(a1.x); af[5] = f2bf(a1.y); af[6] = f2bf(a1.z); af[7] = f2bf(a1.w);
    short8 bfr = *(const short8*)&T[(size_t)r * 9216 + lr * 768 + k0 + kg * 8];
    accL = __builtin_amdgcn_mfma_f32_16x16x32_bf16(af, bfr, accL, 0, 0, 0);
  }
  #pragma unroll
  for (int j = 0; j < 4; ++j) Lp[w * 256 + (kg * 4 + j) * 16 + lr] = accL[j];
  __syncthreads();

  // ---- softmax + joint renorm (each wave redundantly; col h = lr) ----
  float vals[4];
  #pragma unroll
  for (int j = 0; j < 4; ++j) {
    const int mi = (kg * 4 + j) * 16 + lr;
    vals[j] = (Lp[mi] + Lp[256 + mi] + Lp[512 + mi] + Lp[768 + mi]) * 0.125f + qb[lr];
  }
  float mx = fmaxf(fmaxf(vals[0], vals[1]), fmaxf(vals[2], vals[3]));
  mx = fmaxf(mx, __shfl_xor(mx, 16));
  mx = fmaxf(mx, __shfl_xor(mx, 32));
  const int hidx = r * 12 + (lr < 12 ? lr : 11);
  const float msf = mstat[hidx];
  const float ssf = sstat[hidx];
  const float mj = fmaxf(mx, msf);
  float ea[4];
  #pragma unroll
  for (int j = 0; j < 4; ++j) ea[j] = __expf(vals[j] - mj);
  float ssum = ea[0] + ea[1] + ea[2] + ea[3];
  ssum += __shfl_xor(ssum, 16);
  ssum += __shfl_xor(ssum, 32);
  const float alpha = __expf(msf - mj);
  const float invZ = 1.0f / (ssf * alpha + ssum);
  float a[4];
  #pragma unroll
  for (int j = 0; j < 4; ++j) a[j] = ea[j] * invZ;
  if (w == 0 && kg == 0 && lr < 12) {
    sclA[(size_t)r * 12 + lr]  = alpha * invZ;
    simwA[(size_t)r * 12 + lr] = ssum * invZ;
  }

  // ---- a^T A-frag: lane (h=lr, kg) needs a[m=kg*8+e][h], zeros for kg>=2 ----
  short8 af8;
  #pragma unroll
  for (int e = 0; e < 8; ++e) {
    const int src = lr + ((kg & 1) * 2 + (e >> 2)) * 16;
    const float v = __shfl(a[e & 3], src);
    af8[e] = (kg < 2) ? (short)f2bf(v) : (short)0;
  }

  // ---- s_v GEMM: 12 d-tiles per wave, one mfma each ----
  #pragma unroll
  for (int i = 0; i < 12; ++i) {
    const int ntile = w + i * 4;
    short8 bf8 = *(const short8*)&SE_T[(ntile * 16 + lr) * 16 + (kg & 1) * 8];
    f32x4 cacc = {0.f, 0.f, 0.f, 0.f};
    cacc = __builtin_amdgcn_mfma_f32_16x16x32_bf16(af8, bf8, cacc, 0, 0, 0);
    if (kg < 3) {
      #pragma unroll
      for (int j = 0; j < 4; ++j) {
        const int h = kg * 4 + j;
        s_v[(size_t)r * 9216 + h * 768 + ntile * 16 + lr] = f2bf(cacc[j]);
      }
    }
  }
}

// ------------------------------- launcher ----------------------------------

extern "C" void kernel_launch(void* const* d_in, const int* in_sizes, int n_in,
                              void* d_out, int out_size, void* d_ws, size_t ws_size,
                              hipStream_t stream) {
  const float* x  = (const float*)d_in[0];
  const float* se = (const float*)d_in[1];
  const float* Wq = (const float*)d_in[2];
  const float* bq = (const float*)d_in[3];
  const float* Wk = (const float*)d_in[4];
  const float* bk = (const float*)d_in[5];
  const float* Wv = (const float*)d_in[6];
  const float* bv = (const float*)d_in[7];
  const float* Wp = (const float*)d_in[8];
  const float* bp = (const float*)d_in[9];
  float* out = (float*)d_out;
  char* ws = (char*)d_ws;

  // workspace layout (256B-aligned), total ~120.4 MB
  unsigned short* x_bf    = (unsigned short*)(ws);                 // 4096x768   bf16
  unsigned short* Wqkv_t  = (unsigned short*)(ws + 6291456);       // 2304x768   bf16  Wq^T|Wk^T|Wv^T rows
  unsigned short* Wp_t    = (unsigned short*)(ws + 9830400);       // 768x768    bf16
  unsigned short* Wk_bf   = (unsigned short*)(ws + 11010048);      // 768x768    bf16 (untransposed)
  float*          bqkv    = (float*)(ws + 12189696);               // 2304       f32
  unsigned short* qkv     = (unsigned short*)(ws + 12198912);      // 4096x2304  bf16  q|k|v
  unsigned short* Tbuf    = (unsigned short*)(ws + 31073280);      // 4096x12x768 bf16  T, then s_v
  float*          selfacc = (float*)(ws + 106570752);              // 4096x768   f32  unnorm out_self
  float*          mstat   = (float*)(ws + 119153664);              // 4096x12    f32
  float*          sstat   = (float*)(ws + 119350272);              // 4096x12    f32
  float*          sclA    = (float*)(ws + 119546880);              // 4096x12    f32
  float*          simwA   = (float*)(ws + 119743488);              // 4096x12    f32
  unsigned short* att     = (unsigned short*)(ws + 119940096);     // 4096x768   bf16

  cast_bf16<<<3072, 256, 0, stream>>>(x, x_bf, 3145728);
  transpose_cast<<<576, 256, 0, stream>>>(Wq, Wqkv_t);
  transpose_cast<<<576, 256, 0, stream>>>(Wk, Wqkv_t + 768 * 768);
  transpose_cast<<<576, 256, 0, stream>>>(Wv, Wqkv_t + 1536 * 768);
  transpose_cast<<<576, 256, 0, stream>>>(Wp, Wp_t);
  cast_bf16<<<576, 256, 0, stream>>>(Wk, Wk_bf, 589824);
  concat_bias<<<9, 256, 0, stream>>>(bq, bk, bv, bqkv);

  // qkv = x @ [Wq|Wk|Wv] + bias  (M=4096, N=2304, K=768)
  gemm_bt<true, false><<<dim3(32, 18, 1), 256, 0, stream>>>(
      x_bf, 768, 0, Wqkv_t, 768, 0, qkv, 2304, 0, 4096, 2304, 768,
      bqkv, nullptr, nullptr, nullptr, nullptr);
  // T[r,h,:] = q_h @ Wk_h^T  (per-head z=12, K=64)
  gemm_bt<true, false><<<dim3(32, 6, 12), 256, 0, stream>>>(
      qkv, 2304, 64, Wk_bf, 768, 64, Tbuf, 9216, 768, 4096, 768, 64,
      nullptr, nullptr, nullptr, nullptr, nullptr);

  attn_self_kernel<<<192, 256, 0, stream>>>(qkv, selfacc, mstat, sstat);
  fused_sim_kernel<<<4096, 256, 0, stream>>>(se, Tbuf, qkv, bk, mstat, sstat,
                                             Tbuf /* s_v overwrites T in-place per r */,
                                             sclA, simwA);

  // att = selfacc*scl + s_v_h @ Wv_h + simw*bv_h   (per-head z=12, N=64, K=768)
  gemm_bt<true, true><<<dim3(32, 1, 12), 256, 0, stream>>>(
      Tbuf, 9216, 768, Wqkv_t + 1536 * 768, 768, 64 * 768, att, 768, 64,
      4096, 64, 768, nullptr, selfacc, sclA, simwA, bv);
  // out = att @ Wp + bp  (f32 out)
  gemm_bt<false, false><<<dim3(32, 6, 1), 256, 0, stream>>>(
      att, 768, 0, Wp_t, 768, 0, out, 768, 0, 4096, 768, 768,
      bp, nullptr, nullptr, nullptr, nullptr);
}

// Round 5
// 284.855 us; speedup vs baseline: 2.5478x; 1.1569x over previous
//
#include <hip/hip_runtime.h>

// ---------------------------------------------------------------------------
// AsymAttention on MI355X (gfx950).
// B=16, N=256, M=16, D=768, H=12, Dh=64.  scale = 1/8.
//
// Algebraic refactors:
//  (1) avoid sim k/v projections (155 GF):
//      logits_sim[b,h,n,m] = (se[b,n,m,:].T_row + q_h.bk_h) * scale,
//          T[b,n,h,D] = sum_dh q[b,h,n,dh] * Wk[D, h*64+dh]       (K=64 GEMM)
//      out_sim = Wv_h^T s_v + (sum a_sim) bv,  s_v = sum_m a_sim[m] se[b,n,m,:]
//  (2) single COALESCED se pass: fused_sim stages se^T once (bf16, swizzled
//      LDS), L-GEMM + joint-softmax renorm + s_v all consume LDS/L2 only.
//      Combine folded into the out_sim GEMM epilogue.
// ---------------------------------------------------------------------------

typedef __attribute__((ext_vector_type(8))) short short8;   // 8 x bf16 (MFMA frag)
typedef __attribute__((ext_vector_type(4))) float f32x4;    // MFMA acc
typedef __attribute__((ext_vector_type(4))) unsigned short u16x4;

__device__ __forceinline__ float bf2f(unsigned short u) {
  union { unsigned int i; float f; } c; c.i = ((unsigned int)u) << 16; return c.f;
}
__device__ __forceinline__ unsigned short f2bf(float f) {
  union { float f; unsigned int i; } c; c.f = f;
  unsigned int r = c.i + 0x7fffu + ((c.i >> 16) & 1u);   // RNE
  return (unsigned short)(r >> 16);
}

// --------------------------- small cast kernels ----------------------------

__global__ void cast_bf16(const float* __restrict__ in, unsigned short* __restrict__ out, int n) {
  int i = (blockIdx.x * 256 + threadIdx.x) * 4;
  if (i < n) {
    float4 v = *(const float4*)&in[i];
    out[i+0] = f2bf(v.x); out[i+1] = f2bf(v.y); out[i+2] = f2bf(v.z); out[i+3] = f2bf(v.w);
  }
}

// Wt[n][k] = W[k][n], bf16 out.  768x768, 32x32 tiles, 576 blocks.
__global__ void transpose_cast(const float* __restrict__ W, unsigned short* __restrict__ Wt) {
  __shared__ float tile[32][33];
  int bx = blockIdx.x % 24, by = blockIdx.x / 24;
  int n0 = bx * 32, k0 = by * 32;
  int tid = threadIdx.x;
  for (int l = tid; l < 1024; l += 256) {
    int i = l >> 5, j = l & 31;
    tile[i][j] = W[(size_t)(k0 + i) * 768 + n0 + j];
  }
  __syncthreads();
  for (int l = tid; l < 1024; l += 256) {
    int i = l >> 5, j = l & 31;
    Wt[(size_t)(n0 + i) * 768 + k0 + j] = f2bf(tile[j][i]);
  }
}

__global__ void concat_bias(const float* __restrict__ bq, const float* __restrict__ bk,
                            const float* __restrict__ bv, float* __restrict__ o) {
  int i = blockIdx.x * 256 + threadIdx.x;
  if (i < 2304) o[i] = (i < 768) ? bq[i] : ((i < 1536) ? bk[i - 768] : bv[i - 1536]);
}

// ------------------------------- GEMM (m97 pattern) ------------------------
// C[M x Nvalid] = A[M x K](bf16,row-major) * Bt[N x K]^T (+bias) ; 128x128 tile,
// BK=32, 4 waves (2x2), 4x4 frags/wave, global_load_lds width 16.
// SELFC epilogue: C = selfacc*scl + acc + simw*bv2  (joint-softmax combine).

template<bool OUT_BF16, bool SELFC>
__global__ __launch_bounds__(256)
void gemm_bt(const unsigned short* __restrict__ A, int lda, int zsA,
             const unsigned short* __restrict__ Bt, int ldb, int zsB,
             void* __restrict__ Cv, int ldc, int zsC,
             int M, int Nvalid, int K,
             const float* __restrict__ bias,
             const float* __restrict__ selfacc,
             const float* __restrict__ scl,
             const float* __restrict__ simw,
             const float* __restrict__ bv2)
{
  const int z = blockIdx.z;
  A  += (size_t)zsA * z;
  Bt += (size_t)zsB * z;
  const int row0 = blockIdx.x * 128;
  const int col0 = blockIdx.y * 128;
  __shared__ __align__(16) unsigned short lgA[128 * 32];
  __shared__ __align__(16) unsigned short lgB[128 * 32];
  const int tid = threadIdx.x;
  const int lane = tid & 63;
  const int w = tid >> 6;
  const int wr = w >> 1, wc = w & 1;
  const int lr = lane & 15, kg = lane >> 4;

  f32x4 acc[4][4];
  #pragma unroll
  for (int m = 0; m < 4; m++)
    #pragma unroll
    for (int n = 0; n < 4; n++)
      #pragma unroll
      for (int q = 0; q < 4; q++) acc[m][n][q] = 0.f;

  for (int k0 = 0; k0 < K; k0 += 32) {
    __syncthreads();
    #pragma unroll
    for (int it = 0; it < 2; ++it) {
      const int off  = it * 4096 + tid * 16;
      const int row  = off >> 6;
      const int colb = off & 63;
      const char* ga = (const char*)A + (size_t)(row0 + row) * (lda * 2) + k0 * 2 + colb;
      char* la = (char*)lgA + it * 4096 + w * 1024;
      __builtin_amdgcn_global_load_lds((const __attribute__((address_space(1))) unsigned int*)ga,
                                       (__attribute__((address_space(3))) unsigned int*)la, 16, 0, 0);
      const char* gb = (const char*)Bt + (size_t)(col0 + row) * (ldb * 2) + k0 * 2 + colb;
      char* lb = (char*)lgB + it * 4096 + w * 1024;
      __builtin_amdgcn_global_load_lds((const __attribute__((address_space(1))) unsigned int*)gb,
                                       (__attribute__((address_space(3))) unsigned int*)lb, 16, 0, 0);
    }
    __syncthreads();
    short8 af[4], bfr[4];
    #pragma unroll
    for (int m = 0; m < 4; m++) af[m]  = *(const short8*)&lgA[(wr * 64 + m * 16 + lr) * 32 + kg * 8];
    #pragma unroll
    for (int n = 0; n < 4; n++) bfr[n] = *(const short8*)&lgB[(wc * 64 + n * 16 + lr) * 32 + kg * 8];
    #pragma unroll
    for (int m = 0; m < 4; m++)
      #pragma unroll
      for (int n = 0; n < 4; n++)
        acc[m][n] = __builtin_amdgcn_mfma_f32_16x16x32_bf16(af[m], bfr[n], acc[m][n], 0, 0, 0);
  }

  // epilogue: C layout col=lane&15, row=(lane>>4)*4+reg
  #pragma unroll
  for (int m = 0; m < 4; m++) {
    #pragma unroll
    for (int n = 0; n < 4; n++) {
      const int gc = col0 + wc * 64 + n * 16 + lr;
      if (gc >= Nvalid) continue;
      #pragma unroll
      for (int j = 0; j < 4; j++) {
        const int gr = row0 + wr * 64 + m * 16 + kg * 4 + j;
        if (gr >= M) continue;
        float v = acc[m][n][j];
        if (bias) v += bias[gc];
        if (SELFC) {
          v += selfacc[(size_t)gr * 768 + z * 64 + gc] * scl[(size_t)gr * 12 + z]
             + simw[(size_t)gr * 12 + z] * bv2[z * 64 + gc];
        }
        const size_t idx = (size_t)gr * ldc + gc;
        if (OUT_BF16) {
          unsigned short* C = (unsigned short*)Cv + (size_t)zsC * z;
          C[idx] = f2bf(v);
        } else {
          float* C = (float*)Cv + (size_t)zsC * z;
          C[idx] = v;
        }
      }
    }
  }
}

// --------------------------- self attention ---------------------------------
// One block per (b,h); 4 waves, 64 query rows each.  QK^T and PV via MFMA.
// Softmax over the 256 SELF logits only; emits UNNORMALIZED out_self (f32)
// plus per-row stats (m_self, sum_self) for the joint renorm in fused_sim.

__global__ __launch_bounds__(256, 1)
void attn_self_kernel(const unsigned short* __restrict__ qkv,
                      float* __restrict__ selfacc,
                      float* __restrict__ mstat,
                      float* __restrict__ sstat)
{
  const int b = blockIdx.x / 12;
  const int h = blockIdx.x % 12;
  const int tid = threadIdx.x;
  const int lane = tid & 63;
  const int w = tid >> 6;
  const int lr = lane & 15, kg = lane >> 4;
  const size_t rowbase = (size_t)b * 256;

  __shared__ __align__(16) char smem[107520];
  unsigned short* Qs = (unsigned short*)smem;             // [256][72]
  unsigned short* Ks = (unsigned short*)(smem + 36864);   // [256][72]
  unsigned short* VT = (unsigned short*)(smem + 73728);   // [64][264]  VT[d][k]=V[k][d]
  unsigned short* aL = (unsigned short*)(smem + (size_t)w * 17408); // [64][136]/wave, aliases Qs/Ks

  for (int j = tid * 4; j < 256 * 64; j += 1024) {
    const int row = j >> 6, d = j & 63;
    const unsigned short* qp = qkv + (rowbase + row) * 2304 + h * 64 + d;
    u16x4 qv = *(const u16x4*)qp;
    u16x4 kv = *(const u16x4*)(qp + 768);
    *(u16x4*)&Qs[row * 72 + d] = qv;
    *(u16x4*)&Ks[row * 72 + d] = kv;
  }
  for (int i = 0; i < 64; ++i) {       // V transpose: lane=d, rows kk
    const int kk = w * 64 + i;
    VT[lane * 264 + kk] = qkv[(rowbase + kk) * 2304 + 1536 + h * 64 + lane];
  }
  __syncthreads();

  const int n0 = w * 64;
  f32x4 acc[4][16];
  #pragma unroll
  for (int m = 0; m < 4; m++)
    #pragma unroll
    for (int n = 0; n < 16; n++)
      #pragma unroll
      for (int q = 0; q < 4; q++) acc[m][n][q] = 0.f;

  #pragma unroll
  for (int ks = 0; ks < 64; ks += 32) {           // QK^T, K=64
    short8 af[4];
    #pragma unroll
    for (int m = 0; m < 4; m++) af[m] = *(const short8*)&Qs[(n0 + m * 16 + lr) * 72 + ks + kg * 8];
    #pragma unroll
    for (int n = 0; n < 16; n++) {
      short8 bfr = *(const short8*)&Ks[(n * 16 + lr) * 72 + ks + kg * 8];
      #pragma unroll
      for (int m = 0; m < 4; m++)
        acc[m][n] = __builtin_amdgcn_mfma_f32_16x16x32_bf16(af[m], bfr, acc[m][n], 0, 0, 0);
    }
  }

  #pragma unroll
  for (int m = 0; m < 4; m++) {
    #pragma unroll
    for (int j = 0; j < 4; j++) {
      float vmx = -1e30f;
      #pragma unroll
      for (int n = 0; n < 16; n++) { float s = acc[m][n][j] * 0.125f; acc[m][n][j] = s; vmx = fmaxf(vmx, s); }
      #pragma unroll
      for (int s = 1; s < 16; s <<= 1) vmx = fmaxf(vmx, __shfl_xor(vmx, s));
      float sum = 0.f;
      #pragma unroll
      for (int n = 0; n < 16; n++) { float e = __expf(acc[m][n][j] - vmx); acc[m][n][j] = e; sum += e; }
      #pragma unroll
      for (int s = 1; s < 16; s <<= 1) sum += __shfl_xor(sum, s);
      if (lr == 0) {
        const int row = n0 + m * 16 + kg * 4 + j;
        mstat[(rowbase + row) * 12 + h] = vmx;
        sstat[(rowbase + row) * 12 + h] = sum;
      }
    }
  }

  __syncthreads();   // all waves done reading Qs/Ks before aL overwrites them

  f32x4 acc2[4][4];
  #pragma unroll
  for (int m = 0; m < 4; m++)
    #pragma unroll
    for (int n = 0; n < 4; n++)
      #pragma unroll
      for (int q = 0; q < 4; q++) acc2[m][n][q] = 0.f;

  #pragma unroll
  for (int hl = 0; hl < 2; ++hl) {   // PV in two 128-col halves (LDS budget)
    #pragma unroll
    for (int m = 0; m < 4; m++)
      #pragma unroll
      for (int j = 0; j < 4; j++) {
        const int rw = m * 16 + kg * 4 + j;
        #pragma unroll
        for (int n2 = 0; n2 < 8; n2++)
          aL[rw * 136 + n2 * 16 + lr] = f2bf(acc[m][hl * 8 + n2][j]);   // unnormalized
      }
    #pragma unroll
    for (int ks2 = 0; ks2 < 4; ++ks2) {   // out^T = VT * a^T
      short8 vf[4], pf[4];
      #pragma unroll
      for (int mm = 0; mm < 4; mm++)
        vf[mm] = *(const short8*)&VT[(mm * 16 + lr) * 264 + hl * 128 + ks2 * 32 + kg * 8];
      #pragma unroll
      for (int nn = 0; nn < 4; nn++)
        pf[nn] = *(const short8*)&aL[(nn * 16 + lr) * 136 + ks2 * 32 + kg * 8];
      #pragma unroll
      for (int mm = 0; mm < 4; mm++)
        #pragma unroll
        for (int nn = 0; nn < 4; nn++)
          acc2[mm][nn] = __builtin_amdgcn_mfma_f32_16x16x32_bf16(vf[mm], pf[nn], acc2[mm][nn], 0, 0, 0);
    }
  }

  #pragma unroll
  for (int mm = 0; mm < 4; mm++)      // D rows = dh, D cols = query row
    #pragma unroll
    for (int nn = 0; nn < 4; nn++)
      #pragma unroll
      for (int j = 0; j < 4; j++) {
        const int dh = mm * 16 + kg * 4 + j;
        const int rn = n0 + nn * 16 + lr;
        selfacc[(rowbase + rn) * 768 + h * 64 + dh] = acc2[mm][nn][j];   // f32 unnorm
      }
}

// --------------------- fused sim logits + renorm + s_v (MFMA) --------------
// One block per (b,n) = r, 8 waves, 512 threads.
//  stage : COALESCED se read (wave w owns rows {2w,2w+1}, float4 at lane*4),
//          packed u32 m-pair writes into SE_T: row d = 9 dwords, dword column
//          col' = mp ^ ((d>>5)&7)  (swizzle -> near-conflict-free writes).
//  L-GEMM: L[16m][16h] = SE.T^T, K=96/wave (3 mfma); A-frags gathered from
//          SE_T (bf16, LDS), B-frags from global T (L3-resident).
//          Partials via Lp[w][lane] b128 (linear, conflict-free).
//  softmax+renorm: as before (redundant per wave), joint with (mstat,sstat).
//  s_v   : a^T A-frag from shuffles; B-frag = 4 u32 from swizzled SE_T;
//          6 d-tiles per wave.

__global__ __launch_bounds__(512, 4)
void fused_sim_kernel(const float* __restrict__ se, const unsigned short* __restrict__ T,
                      const unsigned short* __restrict__ qkv, const float* __restrict__ bk,
                      const float* __restrict__ mstat, const float* __restrict__ sstat,
                      unsigned short* __restrict__ s_v,
                      float* __restrict__ sclA, float* __restrict__ simwA)
{
  const int r = blockIdx.x;                    // b*256+n
  __shared__ __align__(16) unsigned int SE_T32[768 * 9];   // 27648 B, bf16 se^T
  __shared__ __align__(16) float Lp[8][64][4];             // 8192 B
  __shared__ float qb[16];
  const int tid = threadIdx.x;
  const int w = tid >> 6, lane = tid & 63;
  const int lr = lane & 15, kg = lane >> 4;
  const unsigned short* SE_T16 = (const unsigned short*)SE_T32;

  // ---- coalesced stage: wave w owns se rows m = {2w, 2w+1} ----
  const float* se_r = se + (size_t)r * 12288;
  float4 fa[3], fb[3];
  #pragma unroll
  for (int c = 0; c < 3; ++c) fa[c] = *(const float4*)&se_r[(2 * w) * 768 + c * 256 + lane * 4];
  #pragma unroll
  for (int c = 0; c < 3; ++c) fb[c] = *(const float4*)&se_r[(2 * w + 1) * 768 + c * 256 + lane * 4];
  #pragma unroll
  for (int c = 0; c < 3; ++c) {
    const float* pa = (const float*)&fa[c];
    const float* pb = (const float*)&fb[c];
    #pragma unroll
    for (int j = 0; j < 4; ++j) {
      const int d = c * 256 + lane * 4 + j;
      const unsigned int pk = (unsigned int)f2bf(pa[j]) | ((unsigned int)f2bf(pb[j]) << 16);
      SE_T32[d * 9 + (w ^ ((d >> 5) & 7))] = pk;
    }
  }
  // qb[h] = q_h . bk_h  (waves 0..5, 2 heads each)
  if (w < 6) {
    #pragma unroll
    for (int i = 0; i < 2; ++i) {
      const int hh = w * 2 + i;
      float p = bf2f(qkv[(size_t)r * 2304 + hh * 64 + lane]) * bk[hh * 64 + lane];
      #pragma unroll
      for (int sft = 32; sft; sft >>= 1) p += __shfl_xor(p, sft);
      if (lane == 0) qb[hh] = p;
    }
  }
  if (tid < 4) qb[12 + tid] = 0.f;

  // T B-frags for this wave's K-range (global, L3-resident; no LDS dep)
  short8 bfr[3];
  #pragma unroll
  for (int s = 0; s < 3; ++s)
    bfr[s] = *(const short8*)&T[(size_t)r * 9216 + lr * 768 + w * 96 + s * 32 + kg * 8];

  __syncthreads();

  // ---- L-GEMM partial: K in [w*96, w*96+96) ----
  f32x4 accL = {0.f, 0.f, 0.f, 0.f};
  #pragma unroll
  for (int s = 0; s < 3; ++s) {
    short8 af;
    const int kb = w * 96 + s * 32 + kg * 8;
    #pragma unroll
    for (int e = 0; e < 8; ++e) {
      const int k = kb + e;
      af[e] = (short)SE_T16[(k * 9 + ((lr >> 1) ^ ((k >> 5) & 7))) * 2 + (lr & 1)];
    }
    accL = __builtin_amdgcn_mfma_f32_16x16x32_bf16(af, bfr[s], accL, 0, 0, 0);
  }
  *(f32x4*)&Lp[w][lane][0] = accL;
  __syncthreads();

  // ---- softmax + joint renorm (redundant per wave; m=kg*4+j, h=lr) ----
  float vals[4] = {0.f, 0.f, 0.f, 0.f};
  #pragma unroll
  for (int ww = 0; ww < 8; ++ww) {
    f32x4 p = *(const f32x4*)&Lp[ww][lane][0];
    vals[0] += p[0]; vals[1] += p[1]; vals[2] += p[2]; vals[3] += p[3];
  }
  #pragma unroll
  for (int j = 0; j < 4; ++j) vals[j] = vals[j] * 0.125f + qb[lr];
  float mx = fmaxf(fmaxf(vals[0], vals[1]), fmaxf(vals[2], vals[3]));
  mx = fmaxf(mx, __shfl_xor(mx, 16));
  mx = fmaxf(mx, __shfl_xor(mx, 32));
  const int hidx = r * 12 + (lr < 12 ? lr : 11);
  const float msf = mstat[hidx];
  const float ssf = sstat[hidx];
  const float mj = fmaxf(mx, msf);
  float ea[4];
  #pragma unroll
  for (int j = 0; j < 4; ++j) ea[j] = __expf(vals[j] - mj);
  float ssum = ea[0] + ea[1] + ea[2] + ea[3];
  ssum += __shfl_xor(ssum, 16);
  ssum += __shfl_xor(ssum, 32);
  const float alpha = __expf(msf - mj);
  const float invZ = 1.0f / (ssf * alpha + ssum);
  float a[4];
  #pragma unroll
  for (int j = 0; j < 4; ++j) a[j] = ea[j] * invZ;
  if (w == 0 && kg == 0 && lr < 12) {
    sclA[(size_t)r * 12 + lr]  = alpha * invZ;
    simwA[(size_t)r * 12 + lr] = ssum * invZ;
  }

  // ---- a^T A-frag: lane (h=lr, kg) needs a[m=kg*8+e][h], zeros for kg>=2 ----
  short8 af8;
  #pragma unroll
  for (int e = 0; e < 8; ++e) {
    const int src = lr + ((kg & 1) * 2 + (e >> 2)) * 16;
    const float v = __shfl(a[e & 3], src);
    af8[e] = (kg < 2) ? (short)f2bf(v) : (short)0;
  }

  // ---- s_v GEMM: 6 d-tiles per wave, one mfma each ----
  #pragma unroll
  for (int i = 0; i < 6; ++i) {
    const int ntile = w + i * 8;
    const int row = ntile * 16 + lr;
    const int sw = (row >> 5) & 7;
    union { unsigned int u[4]; short8 s8; } bu;
    #pragma unroll
    for (int j = 0; j < 4; ++j)
      bu.u[j] = SE_T32[row * 9 + (((kg & 1) * 4 + j) ^ sw)];
    f32x4 cacc = {0.f, 0.f, 0.f, 0.f};
    cacc = __builtin_amdgcn_mfma_f32_16x16x32_bf16(af8, bu.s8, cacc, 0, 0, 0);
    if (kg < 3) {
      #pragma unroll
      for (int j = 0; j < 4; ++j) {
        const int h = kg * 4 + j;
        s_v[(size_t)r * 9216 + h * 768 + ntile * 16 + lr] = f2bf(cacc[j]);
      }
    }
  }
}

// ------------------------------- launcher ----------------------------------

extern "C" void kernel_launch(void* const* d_in, const int* in_sizes, int n_in,
                              void* d_out, int out_size, void* d_ws, size_t ws_size,
                              hipStream_t stream) {
  const float* x  = (const float*)d_in[0];
  const float* se = (const float*)d_in[1];
  const float* Wq = (const float*)d_in[2];
  const float* bq = (const float*)d_in[3];
  const float* Wk = (const float*)d_in[4];
  const float* bk = (const float*)d_in[5];
  const float* Wv = (const float*)d_in[6];
  const float* bv = (const float*)d_in[7];
  const float* Wp = (const float*)d_in[8];
  const float* bp = (const float*)d_in[9];
  float* out = (float*)d_out;
  char* ws = (char*)d_ws;

  // workspace layout (256B-aligned), total ~120.4 MB
  unsigned short* x_bf    = (unsigned short*)(ws);                 // 4096x768   bf16
  unsigned short* Wqkv_t  = (unsigned short*)(ws + 6291456);       // 2304x768   bf16  Wq^T|Wk^T|Wv^T rows
  unsigned short* Wp_t    = (unsigned short*)(ws + 9830400);       // 768x768    bf16
  unsigned short* Wk_bf   = (unsigned short*)(ws + 11010048);      // 768x768    bf16 (untransposed)
  float*          bqkv    = (float*)(ws + 12189696);               // 2304       f32
  unsigned short* qkv     = (unsigned short*)(ws + 12198912);      // 4096x2304  bf16  q|k|v
  unsigned short* Tbuf    = (unsigned short*)(ws + 31073280);      // 4096x12x768 bf16  T, then s_v
  float*          selfacc = (float*)(ws + 106570752);              // 4096x768   f32  unnorm out_self
  float*          mstat   = (float*)(ws + 119153664);              // 4096x12    f32
  float*          sstat   = (float*)(ws + 119350272);              // 4096x12    f32
  float*          sclA    = (float*)(ws + 119546880);              // 4096x12    f32
  float*          simwA   = (float*)(ws + 119743488);              // 4096x12    f32
  unsigned short* att     = (unsigned short*)(ws + 119940096);     // 4096x768   bf16

  cast_bf16<<<3072, 256, 0, stream>>>(x, x_bf, 3145728);
  transpose_cast<<<576, 256, 0, stream>>>(Wq, Wqkv_t);
  transpose_cast<<<576, 256, 0, stream>>>(Wk, Wqkv_t + 768 * 768);
  transpose_cast<<<576, 256, 0, stream>>>(Wv, Wqkv_t + 1536 * 768);
  transpose_cast<<<576, 256, 0, stream>>>(Wp, Wp_t);
  cast_bf16<<<576, 256, 0, stream>>>(Wk, Wk_bf, 589824);
  concat_bias<<<9, 256, 0, stream>>>(bq, bk, bv, bqkv);

  // qkv = x @ [Wq|Wk|Wv] + bias  (M=4096, N=2304, K=768)
  gemm_bt<true, false><<<dim3(32, 18, 1), 256, 0, stream>>>(
      x_bf, 768, 0, Wqkv_t, 768, 0, qkv, 2304, 0, 4096, 2304, 768,
      bqkv, nullptr, nullptr, nullptr, nullptr);
  // T[r,h,:] = q_h @ Wk_h^T  (per-head z=12, K=64)
  gemm_bt<true, false><<<dim3(32, 6, 12), 256, 0, stream>>>(
      qkv, 2304, 64, Wk_bf, 768, 64, Tbuf, 9216, 768, 4096, 768, 64,
      nullptr, nullptr, nullptr, nullptr, nullptr);

  attn_self_kernel<<<192, 256, 0, stream>>>(qkv, selfacc, mstat, sstat);
  fused_sim_kernel<<<4096, 512, 0, stream>>>(se, Tbuf, qkv, bk, mstat, sstat,
                                             Tbuf /* s_v overwrites T in-place per r */,
                                             sclA, simwA);

  // att = selfacc*scl + s_v_h @ Wv_h + simw*bv_h   (per-head z=12, N=64, K=768)
  gemm_bt<true, true><<<dim3(32, 1, 12), 256, 0, stream>>>(
      Tbuf, 9216, 768, Wqkv_t + 1536 * 768, 768, 64 * 768, att, 768, 64,
      4096, 64, 768, nullptr, selfacc, sclA, simwA, bv);
  // out = att @ Wp + bp  (f32 out)
  gemm_bt<false, false><<<dim3(32, 6, 1), 256, 0, stream>>>(
      att, 768, 0, Wp_t, 768, 0, out, 768, 0, 4096, 768, 768,
      bp, nullptr, nullptr, nullptr, nullptr);
}

// Round 6
// 256.544 us; speedup vs baseline: 2.8289x; 1.1104x over previous
//
#include <hip/hip_runtime.h>

// ---------------------------------------------------------------------------
// AsymAttention on MI355X (gfx950).
// B=16, N=256, M=16, D=768, H=12, Dh=64.  scale = 1/8.
//
// Algebraic refactors:
//  (1) avoid sim k/v projections (155 GF):
//      logits_sim[b,h,n,m] = (se[b,n,m,:].T_row + q_h.bk_h) * scale,
//          T[b,n,h,D] = sum_dh q[b,h,n,dh] * Wk[D, h*64+dh]       (K=64 GEMM)
//      out_sim = Wv_h^T s_v + (sum a_sim) bv,  s_v = sum_m a_sim[m] se[b,n,m,:]
//  (2) single COALESCED se pass: fused_sim stages se once (bf16, dual layout:
//      transposed for s_v B-frags, row-major for L-GEMM A-frags), L-GEMM +
//      joint-softmax renorm + s_v all consume LDS/L2 only.
//      Combine folded into the out_sim GEMM epilogue.
// ---------------------------------------------------------------------------

typedef __attribute__((ext_vector_type(8))) short short8;   // 8 x bf16 (MFMA frag)
typedef __attribute__((ext_vector_type(4))) float f32x4;    // MFMA acc
typedef __attribute__((ext_vector_type(4))) unsigned short u16x4;

__device__ __forceinline__ float bf2f(unsigned short u) {
  union { unsigned int i; float f; } c; c.i = ((unsigned int)u) << 16; return c.f;
}
__device__ __forceinline__ unsigned short f2bf(float f) {
  union { float f; unsigned int i; } c; c.f = f;
  unsigned int r = c.i + 0x7fffu + ((c.i >> 16) & 1u);   // RNE
  return (unsigned short)(r >> 16);
}

// --------------------------- merged prep kernels ---------------------------

// one launch: cast x -> bf16 (4/thread), cast Wk -> bf16, concat bias
__global__ void misc_prep(const float* __restrict__ x, unsigned short* __restrict__ x_bf,
                          const float* __restrict__ Wk, unsigned short* __restrict__ Wk_bf,
                          const float* __restrict__ bq, const float* __restrict__ bk,
                          const float* __restrict__ bv, float* __restrict__ bqkv) {
  int t = blockIdx.x * 256 + threadIdx.x;
  {
    int i = t * 4;
    float4 v = *(const float4*)&x[i];
    x_bf[i+0] = f2bf(v.x); x_bf[i+1] = f2bf(v.y); x_bf[i+2] = f2bf(v.z); x_bf[i+3] = f2bf(v.w);
  }
  if (t < 147456) {
    int i = t * 4;
    float4 v = *(const float4*)&Wk[i];
    Wk_bf[i+0] = f2bf(v.x); Wk_bf[i+1] = f2bf(v.y); Wk_bf[i+2] = f2bf(v.z); Wk_bf[i+3] = f2bf(v.w);
  }
  if (t < 2304) bqkv[t] = (t < 768) ? bq[t] : ((t < 1536) ? bk[t - 768] : bv[t - 1536]);
}

// Wt[n][k] = W[k][n], bf16 out; z selects one of 4 matrices.
__global__ void transpose_cast4(const float* __restrict__ Wq, const float* __restrict__ Wk,
                                const float* __restrict__ Wv, const float* __restrict__ Wp,
                                unsigned short* __restrict__ Wqkv_t, unsigned short* __restrict__ Wp_t) {
  const float* W = (blockIdx.z == 0) ? Wq : (blockIdx.z == 1) ? Wk : (blockIdx.z == 2) ? Wv : Wp;
  unsigned short* Wt = (blockIdx.z == 3) ? Wp_t : (Wqkv_t + (size_t)blockIdx.z * 589824);
  __shared__ float tile[32][33];
  int bx = blockIdx.x % 24, by = blockIdx.x / 24;
  int n0 = bx * 32, k0 = by * 32;
  int tid = threadIdx.x;
  for (int l = tid; l < 1024; l += 256) {
    int i = l >> 5, j = l & 31;
    tile[i][j] = W[(size_t)(k0 + i) * 768 + n0 + j];
  }
  __syncthreads();
  for (int l = tid; l < 1024; l += 256) {
    int i = l >> 5, j = l & 31;
    Wt[(size_t)(n0 + i) * 768 + k0 + j] = f2bf(tile[j][i]);
  }
}

// ------------------------------- GEMM (m97 pattern) ------------------------
// C[M x Nvalid] = A[M x K](bf16,row-major) * Bt[N x K]^T (+bias) ; 128x128 tile,
// BK=32, 4 waves (2x2), 4x4 frags/wave, global_load_lds width 16.
// SELFC epilogue: C = selfacc*scl + acc + simw*bv2  (joint-softmax combine).

template<bool OUT_BF16, bool SELFC>
__global__ __launch_bounds__(256)
void gemm_bt(const unsigned short* __restrict__ A, int lda, int zsA,
             const unsigned short* __restrict__ Bt, int ldb, int zsB,
             void* __restrict__ Cv, int ldc, int zsC,
             int M, int Nvalid, int K,
             const float* __restrict__ bias,
             const float* __restrict__ selfacc,
             const float* __restrict__ scl,
             const float* __restrict__ simw,
             const float* __restrict__ bv2)
{
  const int z = blockIdx.z;
  A  += (size_t)zsA * z;
  Bt += (size_t)zsB * z;
  const int row0 = blockIdx.x * 128;
  const int col0 = blockIdx.y * 128;
  __shared__ __align__(16) unsigned short lgA[128 * 32];
  __shared__ __align__(16) unsigned short lgB[128 * 32];
  const int tid = threadIdx.x;
  const int lane = tid & 63;
  const int w = tid >> 6;
  const int wr = w >> 1, wc = w & 1;
  const int lr = lane & 15, kg = lane >> 4;

  f32x4 acc[4][4];
  #pragma unroll
  for (int m = 0; m < 4; m++)
    #pragma unroll
    for (int n = 0; n < 4; n++)
      #pragma unroll
      for (int q = 0; q < 4; q++) acc[m][n][q] = 0.f;

  for (int k0 = 0; k0 < K; k0 += 32) {
    __syncthreads();
    #pragma unroll
    for (int it = 0; it < 2; ++it) {
      const int off  = it * 4096 + tid * 16;
      const int row  = off >> 6;
      const int colb = off & 63;
      const char* ga = (const char*)A + (size_t)(row0 + row) * (lda * 2) + k0 * 2 + colb;
      char* la = (char*)lgA + it * 4096 + w * 1024;
      __builtin_amdgcn_global_load_lds((const __attribute__((address_space(1))) unsigned int*)ga,
                                       (__attribute__((address_space(3))) unsigned int*)la, 16, 0, 0);
      const char* gb = (const char*)Bt + (size_t)(col0 + row) * (ldb * 2) + k0 * 2 + colb;
      char* lb = (char*)lgB + it * 4096 + w * 1024;
      __builtin_amdgcn_global_load_lds((const __attribute__((address_space(1))) unsigned int*)gb,
                                       (__attribute__((address_space(3))) unsigned int*)lb, 16, 0, 0);
    }
    __syncthreads();
    short8 af[4], bfr[4];
    #pragma unroll
    for (int m = 0; m < 4; m++) af[m]  = *(const short8*)&lgA[(wr * 64 + m * 16 + lr) * 32 + kg * 8];
    #pragma unroll
    for (int n = 0; n < 4; n++) bfr[n] = *(const short8*)&lgB[(wc * 64 + n * 16 + lr) * 32 + kg * 8];
    #pragma unroll
    for (int m = 0; m < 4; m++)
      #pragma unroll
      for (int n = 0; n < 4; n++)
        acc[m][n] = __builtin_amdgcn_mfma_f32_16x16x32_bf16(af[m], bfr[n], acc[m][n], 0, 0, 0);
  }

  // epilogue: C layout col=lane&15, row=(lane>>4)*4+reg
  #pragma unroll
  for (int m = 0; m < 4; m++) {
    #pragma unroll
    for (int n = 0; n < 4; n++) {
      const int gc = col0 + wc * 64 + n * 16 + lr;
      if (gc >= Nvalid) continue;
      #pragma unroll
      for (int j = 0; j < 4; j++) {
        const int gr = row0 + wr * 64 + m * 16 + kg * 4 + j;
        if (gr >= M) continue;
        float v = acc[m][n][j];
        if (bias) v += bias[gc];
        if (SELFC) {
          v += selfacc[(size_t)gr * 768 + z * 64 + gc] * scl[(size_t)gr * 12 + z]
             + simw[(size_t)gr * 12 + z] * bv2[z * 64 + gc];
        }
        const size_t idx = (size_t)gr * ldc + gc;
        if (OUT_BF16) {
          unsigned short* C = (unsigned short*)Cv + (size_t)zsC * z;
          C[idx] = f2bf(v);
        } else {
          float* C = (float*)Cv + (size_t)zsC * z;
          C[idx] = v;
        }
      }
    }
  }
}

// --------------------------- self attention ---------------------------------
// 4 blocks per (b,h) (grid 768), 64 q-rows per block, 4 waves x 16 rows.
// K staged in LDS [256][72]; V transposed in LDS [64][264]; Q read straight
// from global (16 rows x 16B frags).  aL (per-wave [16][136]) aliases Ks
// after QK^T.  Emits UNNORMALIZED out_self (f32) + (m_self,sum_self).

__global__ __launch_bounds__(256, 2)
void attn_self_kernel(const unsigned short* __restrict__ qkv,
                      float* __restrict__ selfacc,
                      float* __restrict__ mstat,
                      float* __restrict__ sstat)
{
  const int bh = blockIdx.x >> 2;
  const int qq = blockIdx.x & 3;
  const int b = bh / 12;
  const int h = bh % 12;
  const int tid = threadIdx.x;
  const int lane = tid & 63;
  const int w = tid >> 6;
  const int lr = lane & 15, kg = lane >> 4;
  const size_t rowbase = (size_t)b * 256;
  const int rows0 = qq * 64 + w * 16;            // this wave's 16 q-rows

  __shared__ __align__(16) char smem[70656];
  unsigned short* Ks = (unsigned short*)smem;             // [256][72]
  unsigned short* VT = (unsigned short*)(smem + 36864);   // [64][264]  VT[d][k]=V[k][d]
  unsigned short* aL = (unsigned short*)(smem + (size_t)w * 4352); // [16][136]/wave, aliases Ks

  // stage K: 256 rows x 64 cols, 16B per thread-iter
  for (int it = 0; it < 8; ++it) {
    const int idx = tid * 8 + it * 2048;
    const int row = idx >> 6, d = idx & 63;
    *(short8*)&Ks[row * 72 + d] =
        *(const short8*)&qkv[(rowbase + row) * 2304 + 768 + h * 64 + d];
  }
  for (int i = 0; i < 64; ++i) {       // V transpose: lane=d, rows kk
    const int kk = w * 64 + i;
    VT[lane * 264 + kk] = qkv[(rowbase + kk) * 2304 + 1536 + h * 64 + lane];
  }
  __syncthreads();

  f32x4 acc[16];
  #pragma unroll
  for (int n = 0; n < 16; n++)
    #pragma unroll
    for (int q = 0; q < 4; q++) acc[n][q] = 0.f;

  #pragma unroll
  for (int ks = 0; ks < 64; ks += 32) {           // QK^T, K=64; Q from global
    short8 af = *(const short8*)&qkv[(rowbase + rows0 + lr) * 2304 + h * 64 + ks + kg * 8];
    #pragma unroll
    for (int n = 0; n < 16; n++) {
      short8 bfr = *(const short8*)&Ks[(n * 16 + lr) * 72 + ks + kg * 8];
      acc[n] = __builtin_amdgcn_mfma_f32_16x16x32_bf16(af, bfr, acc[n], 0, 0, 0);
    }
  }

  #pragma unroll
  for (int j = 0; j < 4; j++) {
    float vmx = -1e30f;
    #pragma unroll
    for (int n = 0; n < 16; n++) { float s = acc[n][j] * 0.125f; acc[n][j] = s; vmx = fmaxf(vmx, s); }
    #pragma unroll
    for (int s = 1; s < 16; s <<= 1) vmx = fmaxf(vmx, __shfl_xor(vmx, s));
    float sum = 0.f;
    #pragma unroll
    for (int n = 0; n < 16; n++) { float e = __expf(acc[n][j] - vmx); acc[n][j] = e; sum += e; }
    #pragma unroll
    for (int s = 1; s < 16; s <<= 1) sum += __shfl_xor(sum, s);
    if (lr == 0) {
      const int row = rows0 + kg * 4 + j;
      mstat[(rowbase + row) * 12 + h] = vmx;
      sstat[(rowbase + row) * 12 + h] = sum;
    }
  }

  __syncthreads();   // all waves done reading Ks before aL overwrites it

  f32x4 acc2[4];
  #pragma unroll
  for (int m = 0; m < 4; m++)
    #pragma unroll
    for (int q = 0; q < 4; q++) acc2[m][q] = 0.f;

  #pragma unroll
  for (int hl = 0; hl < 2; ++hl) {   // PV in two 128-col halves
    #pragma unroll
    for (int j = 0; j < 4; j++) {
      const int rw = kg * 4 + j;
      #pragma unroll
      for (int n2 = 0; n2 < 8; n2++)
        aL[rw * 136 + n2 * 16 + lr] = f2bf(acc[hl * 8 + n2][j]);   // unnormalized
    }
    #pragma unroll
    for (int ks2 = 0; ks2 < 4; ++ks2) {   // out^T = VT * a^T
      short8 pf = *(const short8*)&aL[lr * 136 + ks2 * 32 + kg * 8];
      #pragma unroll
      for (int mm = 0; mm < 4; mm++) {
        short8 vf = *(const short8*)&VT[(mm * 16 + lr) * 264 + hl * 128 + ks2 * 32 + kg * 8];
        acc2[mm] = __builtin_amdgcn_mfma_f32_16x16x32_bf16(vf, pf, acc2[mm], 0, 0, 0);
      }
    }
  }

  #pragma unroll
  for (int mm = 0; mm < 4; mm++)      // D rows = dh, D cols = q-row (lr)
    #pragma unroll
    for (int j = 0; j < 4; j++) {
      const int dh = mm * 16 + kg * 4 + j;
      const int rn = rows0 + lr;
      selfacc[(rowbase + rn) * 768 + h * 64 + dh] = acc2[mm][j];   // f32 unnorm
    }
}

// --------------------- fused sim logits + renorm + s_v (MFMA) --------------
// One block per (b,n) = r, 8 waves, 512 threads.
//  stage : COALESCED se read (wave w owns rows {2w,2w+1}, float4 at lane*4);
//          writes TWO LDS layouts from the same registers:
//            SE_T32 [768 d][9 dwords]  m-pair packed + swizzle (s_v B-frags)
//            SErm   [16 m][388 dwords] row-major k-pairs      (L-GEMM A-frags)
//  L-GEMM: L[16m][16h] = SE.T^T, K=96/wave (3 mfma); A-frag = ds_read_b128
//          from SErm; B-frags from global T (L3-resident).
//          Partials via Lp[w][lane] b128 (linear, conflict-free).
//  softmax+renorm: redundant per wave, joint with (mstat,sstat).
//  s_v   : a^T A-frag from shuffles; B-frag = 4 u32 from swizzled SE_T;
//          6 d-tiles per wave.

__global__ __launch_bounds__(512, 4)
void fused_sim_kernel(const float* __restrict__ se, const unsigned short* __restrict__ T,
                      const unsigned short* __restrict__ qkv, const float* __restrict__ bk,
                      const float* __restrict__ mstat, const float* __restrict__ sstat,
                      unsigned short* __restrict__ s_v,
                      float* __restrict__ sclA, float* __restrict__ simwA)
{
  const int r = blockIdx.x;                    // b*256+n
  __shared__ __align__(16) unsigned int SE_T32[768 * 9];   // 27648 B
  __shared__ __align__(16) unsigned int SErm[16][388];     // 24832 B (776-elem rows)
  __shared__ __align__(16) float Lp[8][64][4];             // 8192 B
  __shared__ float qb[16];
  const int tid = threadIdx.x;
  const int w = tid >> 6, lane = tid & 63;
  const int lr = lane & 15, kg = lane >> 4;

  // ---- coalesced stage: wave w owns se rows m = {2w, 2w+1} ----
  const float* se_r = se + (size_t)r * 12288;
  unsigned short va[2][12];
  #pragma unroll
  for (int c = 0; c < 3; ++c) {
    float4 fa = *(const float4*)&se_r[(2 * w) * 768 + c * 256 + lane * 4];
    float4 fb = *(const float4*)&se_r[(2 * w + 1) * 768 + c * 256 + lane * 4];
    va[0][c*4+0] = f2bf(fa.x); va[0][c*4+1] = f2bf(fa.y); va[0][c*4+2] = f2bf(fa.z); va[0][c*4+3] = f2bf(fa.w);
    va[1][c*4+0] = f2bf(fb.x); va[1][c*4+1] = f2bf(fb.y); va[1][c*4+2] = f2bf(fb.z); va[1][c*4+3] = f2bf(fb.w);
  }
  #pragma unroll
  for (int c = 0; c < 3; ++c) {
    #pragma unroll
    for (int j = 0; j < 4; ++j) {        // SE_T: m-pair packed, swizzled dword col
      const int d = c * 256 + lane * 4 + j;
      SE_T32[d * 9 + (w ^ ((d >> 5) & 7))] =
          (unsigned int)va[0][c*4+j] | ((unsigned int)va[1][c*4+j] << 16);
    }
    #pragma unroll
    for (int rr = 0; rr < 2; ++rr) {     // SErm: row-major k-pairs, b64 writes
      uint2 pk;
      pk.x = (unsigned int)va[rr][c*4+0] | ((unsigned int)va[rr][c*4+1] << 16);
      pk.y = (unsigned int)va[rr][c*4+2] | ((unsigned int)va[rr][c*4+3] << 16);
      *(uint2*)&SErm[2 * w + rr][c * 128 + lane * 2] = pk;
    }
  }
  // qb[h] = q_h . bk_h  (waves 0..5, 2 heads each)
  if (w < 6) {
    #pragma unroll
    for (int i = 0; i < 2; ++i) {
      const int hh = w * 2 + i;
      float p = bf2f(qkv[(size_t)r * 2304 + hh * 64 + lane]) * bk[hh * 64 + lane];
      #pragma unroll
      for (int sft = 32; sft; sft >>= 1) p += __shfl_xor(p, sft);
      if (lane == 0) qb[hh] = p;
    }
  }
  if (tid < 4) qb[12 + tid] = 0.f;

  // T B-frags for this wave's K-range (global, L3-resident; no LDS dep)
  short8 bfr[3];
  #pragma unroll
  for (int s = 0; s < 3; ++s)
    bfr[s] = *(const short8*)&T[(size_t)r * 9216 + lr * 768 + w * 96 + s * 32 + kg * 8];

  __syncthreads();

  // ---- L-GEMM partial: K in [w*96, w*96+96) ----
  f32x4 accL = {0.f, 0.f, 0.f, 0.f};
  #pragma unroll
  for (int s = 0; s < 3; ++s) {
    const int kb = w * 96 + s * 32 + kg * 8;
    short8 af = *(const short8*)&SErm[lr][kb >> 1];
    accL = __builtin_amdgcn_mfma_f32_16x16x32_bf16(af, bfr[s], accL, 0, 0, 0);
  }
  *(f32x4*)&Lp[w][lane][0] = accL;
  __syncthreads();

  // ---- softmax + joint renorm (redundant per wave; m=kg*4+j, h=lr) ----
  float vals[4] = {0.f, 0.f, 0.f, 0.f};
  #pragma unroll
  for (int ww = 0; ww < 8; ++ww) {
    f32x4 p = *(const f32x4*)&Lp[ww][lane][0];
    vals[0] += p[0]; vals[1] += p[1]; vals[2] += p[2]; vals[3] += p[3];
  }
  #pragma unroll
  for (int j = 0; j < 4; ++j) vals[j] = vals[j] * 0.125f + qb[lr];
  float mx = fmaxf(fmaxf(vals[0], vals[1]), fmaxf(vals[2], vals[3]));
  mx = fmaxf(mx, __shfl_xor(mx, 16));
  mx = fmaxf(mx, __shfl_xor(mx, 32));
  const int hidx = r * 12 + (lr < 12 ? lr : 11);
  const float msf = mstat[hidx];
  const float ssf = sstat[hidx];
  const float mj = fmaxf(mx, msf);
  float ea[4];
  #pragma unroll
  for (int j = 0; j < 4; ++j) ea[j] = __expf(vals[j] - mj);
  float ssum = ea[0] + ea[1] + ea[2] + ea[3];
  ssum += __shfl_xor(ssum, 16);
  ssum += __shfl_xor(ssum, 32);
  const float alpha = __expf(msf - mj);
  const float invZ = 1.0f / (ssf * alpha + ssum);
  float a[4];
  #pragma unroll
  for (int j = 0; j < 4; ++j) a[j] = ea[j] * invZ;
  if (w == 0 && kg == 0 && lr < 12) {
    sclA[(size_t)r * 12 + lr]  = alpha * invZ;
    simwA[(size_t)r * 12 + lr] = ssum * invZ;
  }

  // ---- a^T A-frag: lane (h=lr, kg) needs a[m=kg*8+e][h], zeros for kg>=2 ----
  short8 af8;
  #pragma unroll
  for (int e = 0; e < 8; ++e) {
    const int src = lr + ((kg & 1) * 2 + (e >> 2)) * 16;
    const float v = __shfl(a[e & 3], src);
    af8[e] = (kg < 2) ? (short)f2bf(v) : (short)0;
  }

  // ---- s_v GEMM: 6 d-tiles per wave, one mfma each ----
  #pragma unroll
  for (int i = 0; i < 6; ++i) {
    const int ntile = w + i * 8;
    const int row = ntile * 16 + lr;
    const int sw = (row >> 5) & 7;
    union { unsigned int u[4]; short8 s8; } bu;
    #pragma unroll
    for (int j = 0; j < 4; ++j)
      bu.u[j] = SE_T32[row * 9 + (((kg & 1) * 4 + j) ^ sw)];
    f32x4 cacc = {0.f, 0.f, 0.f, 0.f};
    cacc = __builtin_amdgcn_mfma_f32_16x16x32_bf16(af8, bu.s8, cacc, 0, 0, 0);
    if (kg < 3) {
      #pragma unroll
      for (int j = 0; j < 4; ++j) {
        const int h = kg * 4 + j;
        s_v[(size_t)r * 9216 + h * 768 + ntile * 16 + lr] = f2bf(cacc[j]);
      }
    }
  }
}

// ------------------------------- launcher ----------------------------------

extern "C" void kernel_launch(void* const* d_in, const int* in_sizes, int n_in,
                              void* d_out, int out_size, void* d_ws, size_t ws_size,
                              hipStream_t stream) {
  const float* x  = (const float*)d_in[0];
  const float* se = (const float*)d_in[1];
  const float* Wq = (const float*)d_in[2];
  const float* bq = (const float*)d_in[3];
  const float* Wk = (const float*)d_in[4];
  const float* bk = (const float*)d_in[5];
  const float* Wv = (const float*)d_in[6];
  const float* bv = (const float*)d_in[7];
  const float* Wp = (const float*)d_in[8];
  const float* bp = (const float*)d_in[9];
  float* out = (float*)d_out;
  char* ws = (char*)d_ws;

  // workspace layout (256B-aligned), total ~120.4 MB
  unsigned short* x_bf    = (unsigned short*)(ws);                 // 4096x768   bf16
  unsigned short* Wqkv_t  = (unsigned short*)(ws + 6291456);       // 2304x768   bf16  Wq^T|Wk^T|Wv^T rows
  unsigned short* Wp_t    = (unsigned short*)(ws + 9830400);       // 768x768    bf16
  unsigned short* Wk_bf   = (unsigned short*)(ws + 11010048);      // 768x768    bf16 (untransposed)
  float*          bqkv    = (float*)(ws + 12189696);               // 2304       f32
  unsigned short* qkv     = (unsigned short*)(ws + 12198912);      // 4096x2304  bf16  q|k|v
  unsigned short* Tbuf    = (unsigned short*)(ws + 31073280);      // 4096x12x768 bf16  T, then s_v
  float*          selfacc = (float*)(ws + 106570752);              // 4096x768   f32  unnorm out_self
  float*          mstat   = (float*)(ws + 119153664);              // 4096x12    f32
  float*          sstat   = (float*)(ws + 119350272);              // 4096x12    f32
  float*          sclA    = (float*)(ws + 119546880);              // 4096x12    f32
  float*          simwA   = (float*)(ws + 119743488);              // 4096x12    f32
  unsigned short* att     = (unsigned short*)(ws + 119940096);     // 4096x768   bf16

  misc_prep<<<3072, 256, 0, stream>>>(x, x_bf, Wk, Wk_bf, bq, bk, bv, bqkv);
  transpose_cast4<<<dim3(576, 1, 4), 256, 0, stream>>>(Wq, Wk, Wv, Wp, Wqkv_t, Wp_t);

  // qkv = x @ [Wq|Wk|Wv] + bias  (M=4096, N=2304, K=768)
  gemm_bt<true, false><<<dim3(32, 18, 1), 256, 0, stream>>>(
      x_bf, 768, 0, Wqkv_t, 768, 0, qkv, 2304, 0, 4096, 2304, 768,
      bqkv, nullptr, nullptr, nullptr, nullptr);
  // T[r,h,:] = q_h @ Wk_h^T  (per-head z=12, K=64)
  gemm_bt<true, false><<<dim3(32, 6, 12), 256, 0, stream>>>(
      qkv, 2304, 64, Wk_bf, 768, 64, Tbuf, 9216, 768, 4096, 768, 64,
      nullptr, nullptr, nullptr, nullptr, nullptr);

  attn_self_kernel<<<768, 256, 0, stream>>>(qkv, selfacc, mstat, sstat);
  fused_sim_kernel<<<4096, 512, 0, stream>>>(se, Tbuf, qkv, bk, mstat, sstat,
                                             Tbuf /* s_v overwrites T in-place per r */,
                                             sclA, simwA);

  // att = selfacc*scl + s_v_h @ Wv_h + simw*bv_h   (per-head z=12, N=64, K=768)
  gemm_bt<true, true><<<dim3(32, 1, 12), 256, 0, stream>>>(
      Tbuf, 9216, 768, Wqkv_t + 1536 * 768, 768, 64 * 768, att, 768, 64,
      4096, 64, 768, nullptr, selfacc, sclA, simwA, bv);
  // out = att @ Wp + bp  (f32 out)
  gemm_bt<false, false><<<dim3(32, 6, 1), 256, 0, stream>>>(
      att, 768, 0, Wp_t, 768, 0, out, 768, 0, 4096, 768, 768,
      bp, nullptr, nullptr, nullptr, nullptr);
}

// Round 7
// 251.184 us; speedup vs baseline: 2.8893x; 1.0213x over previous
//
#include <hip/hip_runtime.h>

// ---------------------------------------------------------------------------
// AsymAttention on MI355X (gfx950).
// B=16, N=256, M=16, D=768, H=12, Dh=64.  scale = 1/8.
//
// Algebraic refactors:
//  (1) avoid sim k/v projections (155 GF):
//      logits_sim[b,h,n,m] = (se[b,n,m,:].T_row + q_h.bk_h) * scale,
//          T[b,n,h,D] = sum_dh q[b,h,n,dh] * Wk[D, h*64+dh]       (K=64 GEMM)
//      out_sim = Wv_h^T s_v + (sum a_sim) bv,  s_v = sum_m a_sim[m] se[b,n,m,:]
//  (2) single COALESCED se pass: fused_sim stages se once (bf16, dual layout),
//      L-GEMM + joint-softmax renorm + s_v all consume LDS/L2 only.
//      Combine folded into the out_sim GEMM epilogue.
//  (3) GEMM: TBK=64 staged as two 32-wide panels (keeps the verified 64B-row
//      ds_read_b128 pattern, halves barrier drains); outsim uses BN=64 tile.
// ---------------------------------------------------------------------------

typedef __attribute__((ext_vector_type(8))) short short8;   // 8 x bf16 (MFMA frag)
typedef __attribute__((ext_vector_type(4))) float f32x4;    // MFMA acc
typedef __attribute__((ext_vector_type(4))) unsigned short u16x4;

__device__ __forceinline__ float bf2f(unsigned short u) {
  union { unsigned int i; float f; } c; c.i = ((unsigned int)u) << 16; return c.f;
}
__device__ __forceinline__ unsigned short f2bf(float f) {
  union { float f; unsigned int i; } c; c.f = f;
  unsigned int r = c.i + 0x7fffu + ((c.i >> 16) & 1u);   // RNE
  return (unsigned short)(r >> 16);
}

// --------------------------- merged prep kernels ---------------------------

__global__ void misc_prep(const float* __restrict__ x, unsigned short* __restrict__ x_bf,
                          const float* __restrict__ Wk, unsigned short* __restrict__ Wk_bf,
                          const float* __restrict__ bq, const float* __restrict__ bk,
                          const float* __restrict__ bv, float* __restrict__ bqkv) {
  int t = blockIdx.x * 256 + threadIdx.x;
  {
    int i = t * 4;
    float4 v = *(const float4*)&x[i];
    x_bf[i+0] = f2bf(v.x); x_bf[i+1] = f2bf(v.y); x_bf[i+2] = f2bf(v.z); x_bf[i+3] = f2bf(v.w);
  }
  if (t < 147456) {
    int i = t * 4;
    float4 v = *(const float4*)&Wk[i];
    Wk_bf[i+0] = f2bf(v.x); Wk_bf[i+1] = f2bf(v.y); Wk_bf[i+2] = f2bf(v.z); Wk_bf[i+3] = f2bf(v.w);
  }
  if (t < 2304) bqkv[t] = (t < 768) ? bq[t] : ((t < 1536) ? bk[t - 768] : bv[t - 1536]);
}

// Wt[n][k] = W[k][n], bf16 out; z selects one of 4 matrices.
__global__ void transpose_cast4(const float* __restrict__ Wq, const float* __restrict__ Wk,
                                const float* __restrict__ Wv, const float* __restrict__ Wp,
                                unsigned short* __restrict__ Wqkv_t, unsigned short* __restrict__ Wp_t) {
  const float* W = (blockIdx.z == 0) ? Wq : (blockIdx.z == 1) ? Wk : (blockIdx.z == 2) ? Wv : Wp;
  unsigned short* Wt = (blockIdx.z == 3) ? Wp_t : (Wqkv_t + (size_t)blockIdx.z * 589824);
  __shared__ float tile[32][33];
  int bx = blockIdx.x % 24, by = blockIdx.x / 24;
  int n0 = bx * 32, k0 = by * 32;
  int tid = threadIdx.x;
  for (int l = tid; l < 1024; l += 256) {
    int i = l >> 5, j = l & 31;
    tile[i][j] = W[(size_t)(k0 + i) * 768 + n0 + j];
  }
  __syncthreads();
  for (int l = tid; l < 1024; l += 256) {
    int i = l >> 5, j = l & 31;
    Wt[(size_t)(n0 + i) * 768 + k0 + j] = f2bf(tile[j][i]);
  }
}

// ------------------------------- GEMM --------------------------------------
// C[128 x BN tile] = A[M x K](bf16 rm) * Bt[N x K]^T (+bias).  TBK=64 staged
// as two 32-wide panels (64B LDS row stride, m97 read pattern).  4 waves 2x2,
// 4 x NF frags/wave.  SELFC epilogue: C = selfacc*scl + acc + simw*bv2.

template<bool OUT_BF16, bool SELFC, int BN, int TBK>
__global__ __launch_bounds__(256)
void gemm_bt(const unsigned short* __restrict__ A, int lda, int zsA,
             const unsigned short* __restrict__ Bt, int ldb, int zsB,
             void* __restrict__ Cv, int ldc, int zsC,
             int M, int Nvalid, int K,
             const float* __restrict__ bias,
             const float* __restrict__ selfacc,
             const float* __restrict__ scl,
             const float* __restrict__ simw,
             const float* __restrict__ bv2)
{
  constexpr int NF  = BN / 32;                 // n-frags per wave
  constexpr int AIT = (128 * TBK * 2) / 4096;  // A staging iters
  constexpr int BIT = (BN  * TBK * 2) / 4096;  // B staging iters
  constexpr int PA  = 128 * 64;                // A panel bytes
  constexpr int PB  = BN * 64;                 // B panel bytes
  const int z = blockIdx.z;
  A  += (size_t)zsA * z;
  Bt += (size_t)zsB * z;
  const int row0 = blockIdx.x * 128;
  const int col0 = blockIdx.y * BN;
  __shared__ __align__(16) unsigned short lgA[128 * TBK];
  __shared__ __align__(16) unsigned short lgB[BN * TBK];
  const int tid = threadIdx.x;
  const int lane = tid & 63;
  const int w = tid >> 6;
  const int wr = w >> 1, wc = w & 1;
  const int lr = lane & 15, kg = lane >> 4;

  f32x4 acc[4][NF];
  #pragma unroll
  for (int m = 0; m < 4; m++)
    #pragma unroll
    for (int n = 0; n < NF; n++)
      #pragma unroll
      for (int q = 0; q < 4; q++) acc[m][n][q] = 0.f;

  for (int k0 = 0; k0 < K; k0 += TBK) {
    __syncthreads();
    #pragma unroll
    for (int it = 0; it < AIT; ++it) {
      const int off = it * 4096 + tid * 16;
      const int kp = off / PA, row = (off % PA) >> 6, colb = off & 63;
      const char* ga = (const char*)A + (size_t)(row0 + row) * (lda * 2) + (k0 + kp * 32) * 2 + colb;
      __builtin_amdgcn_global_load_lds((const __attribute__((address_space(1))) unsigned int*)ga,
                                       (__attribute__((address_space(3))) unsigned int*)((char*)lgA + off), 16, 0, 0);
    }
    #pragma unroll
    for (int it = 0; it < BIT; ++it) {
      const int off = it * 4096 + tid * 16;
      const int kp = off / PB, row = (off % PB) >> 6, colb = off & 63;
      const char* gb = (const char*)Bt + (size_t)(col0 + row) * (ldb * 2) + (k0 + kp * 32) * 2 + colb;
      __builtin_amdgcn_global_load_lds((const __attribute__((address_space(1))) unsigned int*)gb,
                                       (__attribute__((address_space(3))) unsigned int*)((char*)lgB + off), 16, 0, 0);
    }
    __syncthreads();
    #pragma unroll
    for (int kk = 0; kk < TBK; kk += 32) {
      short8 af[4], bfr[NF];
      #pragma unroll
      for (int m = 0; m < 4; m++)
        af[m] = *(const short8*)&lgA[(kk >> 5) * (128 * 32) + (wr * 64 + m * 16 + lr) * 32 + kg * 8];
      #pragma unroll
      for (int n = 0; n < NF; n++)
        bfr[n] = *(const short8*)&lgB[(kk >> 5) * (BN * 32) + (wc * (BN / 2) + n * 16 + lr) * 32 + kg * 8];
      #pragma unroll
      for (int m = 0; m < 4; m++)
        #pragma unroll
        for (int n = 0; n < NF; n++)
          acc[m][n] = __builtin_amdgcn_mfma_f32_16x16x32_bf16(af[m], bfr[n], acc[m][n], 0, 0, 0);
    }
  }

  // epilogue: C layout col=lane&15, row=(lane>>4)*4+reg
  #pragma unroll
  for (int m = 0; m < 4; m++) {
    #pragma unroll
    for (int n = 0; n < NF; n++) {
      const int gc = col0 + wc * (BN / 2) + n * 16 + lr;
      if (gc >= Nvalid) continue;
      #pragma unroll
      for (int j = 0; j < 4; j++) {
        const int gr = row0 + wr * 64 + m * 16 + kg * 4 + j;
        if (gr >= M) continue;
        float v = acc[m][n][j];
        if (bias) v += bias[gc];
        if (SELFC) {
          v += selfacc[(size_t)gr * 768 + z * 64 + gc] * scl[(size_t)gr * 12 + z]
             + simw[(size_t)gr * 12 + z] * bv2[z * 64 + gc];
        }
        const size_t idx = (size_t)gr * ldc + gc;
        if (OUT_BF16) {
          unsigned short* C = (unsigned short*)Cv + (size_t)zsC * z;
          C[idx] = f2bf(v);
        } else {
          float* C = (float*)Cv + (size_t)zsC * z;
          C[idx] = v;
        }
      }
    }
  }
}

// --------------------------- self attention ---------------------------------
// 4 blocks per (b,h) (grid 768), 64 q-rows per block, 4 waves x 16 rows.
// K staged in LDS [256][72]; V transposed in LDS [64][264]; Q from global.
// aL (per-wave [16][136]) aliases Ks after QK^T.  Emits UNNORMALIZED out_self
// (f32) + (m_self, sum_self).

__global__ __launch_bounds__(256, 2)
void attn_self_kernel(const unsigned short* __restrict__ qkv,
                      float* __restrict__ selfacc,
                      float* __restrict__ mstat,
                      float* __restrict__ sstat)
{
  const int bh = blockIdx.x >> 2;
  const int qq = blockIdx.x & 3;
  const int b = bh / 12;
  const int h = bh % 12;
  const int tid = threadIdx.x;
  const int lane = tid & 63;
  const int w = tid >> 6;
  const int lr = lane & 15, kg = lane >> 4;
  const size_t rowbase = (size_t)b * 256;
  const int rows0 = qq * 64 + w * 16;            // this wave's 16 q-rows

  __shared__ __align__(16) char smem[70656];
  unsigned short* Ks = (unsigned short*)smem;             // [256][72]
  unsigned short* VT = (unsigned short*)(smem + 36864);   // [64][264]  VT[d][k]=V[k][d]
  unsigned short* aL = (unsigned short*)(smem + (size_t)w * 4352); // [16][136]/wave, aliases Ks

  // stage K: 256 rows x 64 cols, 16B per thread-iter
  for (int it = 0; it < 8; ++it) {
    const int idx = tid * 8 + it * 2048;
    const int row = idx >> 6, d = idx & 63;
    *(short8*)&Ks[row * 72 + d] =
        *(const short8*)&qkv[(rowbase + row) * 2304 + 768 + h * 64 + d];
  }
  // V transpose: 16 iters, u16x4 loads (4 rows x 64 d per wave-iter)
  #pragma unroll
  for (int it = 0; it < 16; ++it) {
    const int kk = w * 64 + it * 4 + kg;
    const int d0 = lr * 4;
    u16x4 v4 = *(const u16x4*)&qkv[(rowbase + kk) * 2304 + 1536 + h * 64 + d0];
    VT[(d0+0) * 264 + kk] = v4.x;
    VT[(d0+1) * 264 + kk] = v4.y;
    VT[(d0+2) * 264 + kk] = v4.z;
    VT[(d0+3) * 264 + kk] = v4.w;
  }
  __syncthreads();

  f32x4 acc[16];
  #pragma unroll
  for (int n = 0; n < 16; n++)
    #pragma unroll
    for (int q = 0; q < 4; q++) acc[n][q] = 0.f;

  #pragma unroll
  for (int ks = 0; ks < 64; ks += 32) {           // QK^T, K=64; Q from global
    short8 af = *(const short8*)&qkv[(rowbase + rows0 + lr) * 2304 + h * 64 + ks + kg * 8];
    #pragma unroll
    for (int n = 0; n < 16; n++) {
      short8 bfr = *(const short8*)&Ks[(n * 16 + lr) * 72 + ks + kg * 8];
      acc[n] = __builtin_amdgcn_mfma_f32_16x16x32_bf16(af, bfr, acc[n], 0, 0, 0);
    }
  }

  #pragma unroll
  for (int j = 0; j < 4; j++) {
    float vmx = -1e30f;
    #pragma unroll
    for (int n = 0; n < 16; n++) { float s = acc[n][j] * 0.125f; acc[n][j] = s; vmx = fmaxf(vmx, s); }
    #pragma unroll
    for (int s = 1; s < 16; s <<= 1) vmx = fmaxf(vmx, __shfl_xor(vmx, s));
    float sum = 0.f;
    #pragma unroll
    for (int n = 0; n < 16; n++) { float e = __expf(acc[n][j] - vmx); acc[n][j] = e; sum += e; }
    #pragma unroll
    for (int s = 1; s < 16; s <<= 1) sum += __shfl_xor(sum, s);
    if (lr == 0) {
      const int row = rows0 + kg * 4 + j;
      mstat[(rowbase + row) * 12 + h] = vmx;
      sstat[(rowbase + row) * 12 + h] = sum;
    }
  }

  __syncthreads();   // all waves done reading Ks before aL overwrites it

  f32x4 acc2[4];
  #pragma unroll
  for (int m = 0; m < 4; m++)
    #pragma unroll
    for (int q = 0; q < 4; q++) acc2[m][q] = 0.f;

  #pragma unroll
  for (int hl = 0; hl < 2; ++hl) {   // PV in two 128-col halves
    #pragma unroll
    for (int j = 0; j < 4; j++) {
      const int rw = kg * 4 + j;
      #pragma unroll
      for (int n2 = 0; n2 < 8; n2++)
        aL[rw * 136 + n2 * 16 + lr] = f2bf(acc[hl * 8 + n2][j]);   // unnormalized
    }
    #pragma unroll
    for (int ks2 = 0; ks2 < 4; ++ks2) {   // out^T = VT * a^T
      short8 pf = *(const short8*)&aL[lr * 136 + ks2 * 32 + kg * 8];
      #pragma unroll
      for (int mm = 0; mm < 4; mm++) {
        short8 vf = *(const short8*)&VT[(mm * 16 + lr) * 264 + hl * 128 + ks2 * 32 + kg * 8];
        acc2[mm] = __builtin_amdgcn_mfma_f32_16x16x32_bf16(vf, pf, acc2[mm], 0, 0, 0);
      }
    }
  }

  #pragma unroll
  for (int mm = 0; mm < 4; mm++)      // D rows = dh, D cols = q-row (lr)
    #pragma unroll
    for (int j = 0; j < 4; j++) {
      const int dh = mm * 16 + kg * 4 + j;
      const int rn = rows0 + lr;
      selfacc[(rowbase + rn) * 768 + h * 64 + dh] = acc2[mm][j];   // f32 unnorm
    }
}

// --------------------- fused sim logits + renorm + s_v (MFMA) --------------
// One block per (b,n) = r, 8 waves, 512 threads.  (See R6 notes.)

__global__ __launch_bounds__(512, 4)
void fused_sim_kernel(const float* __restrict__ se, const unsigned short* __restrict__ T,
                      const unsigned short* __restrict__ qkv, const float* __restrict__ bk,
                      const float* __restrict__ mstat, const float* __restrict__ sstat,
                      unsigned short* __restrict__ s_v,
                      float* __restrict__ sclA, float* __restrict__ simwA)
{
  const int r = blockIdx.x;                    // b*256+n
  __shared__ __align__(16) unsigned int SE_T32[768 * 9];   // 27648 B
  __shared__ __align__(16) unsigned int SErm[16][388];     // 24832 B (776-elem rows)
  __shared__ __align__(16) float Lp[8][64][4];             // 8192 B
  __shared__ float qb[16];
  const int tid = threadIdx.x;
  const int w = tid >> 6, lane = tid & 63;
  const int lr = lane & 15, kg = lane >> 4;

  // ---- coalesced stage: wave w owns se rows m = {2w, 2w+1} ----
  const float* se_r = se + (size_t)r * 12288;
  unsigned short va[2][12];
  #pragma unroll
  for (int c = 0; c < 3; ++c) {
    float4 fa = *(const float4*)&se_r[(2 * w) * 768 + c * 256 + lane * 4];
    float4 fb = *(const float4*)&se_r[(2 * w + 1) * 768 + c * 256 + lane * 4];
    va[0][c*4+0] = f2bf(fa.x); va[0][c*4+1] = f2bf(fa.y); va[0][c*4+2] = f2bf(fa.z); va[0][c*4+3] = f2bf(fa.w);
    va[1][c*4+0] = f2bf(fb.x); va[1][c*4+1] = f2bf(fb.y); va[1][c*4+2] = f2bf(fb.z); va[1][c*4+3] = f2bf(fb.w);
  }
  #pragma unroll
  for (int c = 0; c < 3; ++c) {
    #pragma unroll
    for (int j = 0; j < 4; ++j) {        // SE_T: m-pair packed, swizzled dword col
      const int d = c * 256 + lane * 4 + j;
      SE_T32[d * 9 + (w ^ ((d >> 5) & 7))] =
          (unsigned int)va[0][c*4+j] | ((unsigned int)va[1][c*4+j] << 16);
    }
    #pragma unroll
    for (int rr = 0; rr < 2; ++rr) {     // SErm: row-major k-pairs, b64 writes
      uint2 pk;
      pk.x = (unsigned int)va[rr][c*4+0] | ((unsigned int)va[rr][c*4+1] << 16);
      pk.y = (unsigned int)va[rr][c*4+2] | ((unsigned int)va[rr][c*4+3] << 16);
      *(uint2*)&SErm[2 * w + rr][c * 128 + lane * 2] = pk;
    }
  }
  // qb[h] = q_h . bk_h  (waves 0..5, 2 heads each)
  if (w < 6) {
    #pragma unroll
    for (int i = 0; i < 2; ++i) {
      const int hh = w * 2 + i;
      float p = bf2f(qkv[(size_t)r * 2304 + hh * 64 + lane]) * bk[hh * 64 + lane];
      #pragma unroll
      for (int sft = 32; sft; sft >>= 1) p += __shfl_xor(p, sft);
      if (lane == 0) qb[hh] = p;
    }
  }
  if (tid < 4) qb[12 + tid] = 0.f;

  // T B-frags for this wave's K-range (global, L3-resident; no LDS dep)
  short8 bfr[3];
  #pragma unroll
  for (int s = 0; s < 3; ++s)
    bfr[s] = *(const short8*)&T[(size_t)r * 9216 + lr * 768 + w * 96 + s * 32 + kg * 8];

  __syncthreads();

  // ---- L-GEMM partial: K in [w*96, w*96+96) ----
  f32x4 accL = {0.f, 0.f, 0.f, 0.f};
  #pragma unroll
  for (int s = 0; s < 3; ++s) {
    const int kb = w * 96 + s * 32 + kg * 8;
    short8 af = *(const short8*)&SErm[lr][kb >> 1];
    accL = __builtin_amdgcn_mfma_f32_16x16x32_bf16(af, bfr[s], accL, 0, 0, 0);
  }
  *(f32x4*)&Lp[w][lane][0] = accL;
  __syncthreads();

  // ---- softmax + joint renorm (redundant per wave; m=kg*4+j, h=lr) ----
  float vals[4] = {0.f, 0.f, 0.f, 0.f};
  #pragma unroll
  for (int ww = 0; ww < 8; ++ww) {
    f32x4 p = *(const f32x4*)&Lp[ww][lane][0];
    vals[0] += p[0]; vals[1] += p[1]; vals[2] += p[2]; vals[3] += p[3];
  }
  #pragma unroll
  for (int j = 0; j < 4; ++j) vals[j] = vals[j] * 0.125f + qb[lr];
  float mx = fmaxf(fmaxf(vals[0], vals[1]), fmaxf(vals[2], vals[3]));
  mx = fmaxf(mx, __shfl_xor(mx, 16));
  mx = fmaxf(mx, __shfl_xor(mx, 32));
  const int hidx = r * 12 + (lr < 12 ? lr : 11);
  const float msf = mstat[hidx];
  const float ssf = sstat[hidx];
  const float mj = fmaxf(mx, msf);
  float ea[4];
  #pragma unroll
  for (int j = 0; j < 4; ++j) ea[j] = __expf(vals[j] - mj);
  float ssum = ea[0] + ea[1] + ea[2] + ea[3];
  ssum += __shfl_xor(ssum, 16);
  ssum += __shfl_xor(ssum, 32);
  const float alpha = __expf(msf - mj);
  const float invZ = 1.0f / (ssf * alpha + ssum);
  float a[4];
  #pragma unroll
  for (int j = 0; j < 4; ++j) a[j] = ea[j] * invZ;
  if (w == 0 && kg == 0 && lr < 12) {
    sclA[(size_t)r * 12 + lr]  = alpha * invZ;
    simwA[(size_t)r * 12 + lr] = ssum * invZ;
  }

  // ---- a^T A-frag: lane (h=lr, kg) needs a[m=kg*8+e][h], zeros for kg>=2 ----
  short8 af8;
  #pragma unroll
  for (int e = 0; e < 8; ++e) {
    const int src = lr + ((kg & 1) * 2 + (e >> 2)) * 16;
    const float v = __shfl(a[e & 3], src);
    af8[e] = (kg < 2) ? (short)f2bf(v) : (short)0;
  }

  // ---- s_v GEMM: 6 d-tiles per wave, one mfma each ----
  #pragma unroll
  for (int i = 0; i < 6; ++i) {
    const int ntile = w + i * 8;
    const int row = ntile * 16 + lr;
    const int sw = (row >> 5) & 7;
    union { unsigned int u[4]; short8 s8; } bu;
    #pragma unroll
    for (int j = 0; j < 4; ++j)
      bu.u[j] = SE_T32[row * 9 + (((kg & 1) * 4 + j) ^ sw)];
    f32x4 cacc = {0.f, 0.f, 0.f, 0.f};
    cacc = __builtin_amdgcn_mfma_f32_16x16x32_bf16(af8, bu.s8, cacc, 0, 0, 0);
    if (kg < 3) {
      #pragma unroll
      for (int j = 0; j < 4; ++j) {
        const int h = kg * 4 + j;
        s_v[(size_t)r * 9216 + h * 768 + ntile * 16 + lr] = f2bf(cacc[j]);
      }
    }
  }
}

// ------------------------------- launcher ----------------------------------

extern "C" void kernel_launch(void* const* d_in, const int* in_sizes, int n_in,
                              void* d_out, int out_size, void* d_ws, size_t ws_size,
                              hipStream_t stream) {
  const float* x  = (const float*)d_in[0];
  const float* se = (const float*)d_in[1];
  const float* Wq = (const float*)d_in[2];
  const float* bq = (const float*)d_in[3];
  const float* Wk = (const float*)d_in[4];
  const float* bk = (const float*)d_in[5];
  const float* Wv = (const float*)d_in[6];
  const float* bv = (const float*)d_in[7];
  const float* Wp = (const float*)d_in[8];
  const float* bp = (const float*)d_in[9];
  float* out = (float*)d_out;
  char* ws = (char*)d_ws;

  // workspace layout (256B-aligned), total ~120.4 MB
  unsigned short* x_bf    = (unsigned short*)(ws);                 // 4096x768   bf16
  unsigned short* Wqkv_t  = (unsigned short*)(ws + 6291456);       // 2304x768   bf16  Wq^T|Wk^T|Wv^T rows
  unsigned short* Wp_t    = (unsigned short*)(ws + 9830400);       // 768x768    bf16
  unsigned short* Wk_bf   = (unsigned short*)(ws + 11010048);      // 768x768    bf16 (untransposed)
  float*          bqkv    = (float*)(ws + 12189696);               // 2304       f32
  unsigned short* qkv     = (unsigned short*)(ws + 12198912);      // 4096x2304  bf16  q|k|v
  unsigned short* Tbuf    = (unsigned short*)(ws + 31073280);      // 4096x12x768 bf16  T, then s_v
  float*          selfacc = (float*)(ws + 106570752);              // 4096x768   f32  unnorm out_self
  float*          mstat   = (float*)(ws + 119153664);              // 4096x12    f32
  float*          sstat   = (float*)(ws + 119350272);              // 4096x12    f32
  float*          sclA    = (float*)(ws + 119546880);              // 4096x12    f32
  float*          simwA   = (float*)(ws + 119743488);              // 4096x12    f32
  unsigned short* att     = (unsigned short*)(ws + 119940096);     // 4096x768   bf16

  misc_prep<<<3072, 256, 0, stream>>>(x, x_bf, Wk, Wk_bf, bq, bk, bv, bqkv);
  transpose_cast4<<<dim3(576, 1, 4), 256, 0, stream>>>(Wq, Wk, Wv, Wp, Wqkv_t, Wp_t);

  // qkv = x @ [Wq|Wk|Wv] + bias  (M=4096, N=2304, K=768)
  gemm_bt<true, false, 128, 64><<<dim3(32, 18, 1), 256, 0, stream>>>(
      x_bf, 768, 0, Wqkv_t, 768, 0, qkv, 2304, 0, 4096, 2304, 768,
      bqkv, nullptr, nullptr, nullptr, nullptr);
  // T[r,h,:] = q_h @ Wk_h^T  (per-head z=12, K=64 -> single K-step)
  gemm_bt<true, false, 128, 64><<<dim3(32, 6, 12), 256, 0, stream>>>(
      qkv, 2304, 64, Wk_bf, 768, 64, Tbuf, 9216, 768, 4096, 768, 64,
      nullptr, nullptr, nullptr, nullptr, nullptr);

  attn_self_kernel<<<768, 256, 0, stream>>>(qkv, selfacc, mstat, sstat);
  fused_sim_kernel<<<4096, 512, 0, stream>>>(se, Tbuf, qkv, bk, mstat, sstat,
                                             Tbuf /* s_v overwrites T in-place per r */,
                                             sclA, simwA);

  // att = selfacc*scl + s_v_h @ Wv_h + simw*bv_h   (per-head z=12, N=64, K=768)
  gemm_bt<true, true, 64, 64><<<dim3(32, 1, 12), 256, 0, stream>>>(
      Tbuf, 9216, 768, Wqkv_t + 1536 * 768, 768, 64 * 768, att, 768, 64,
      4096, 64, 768, nullptr, selfacc, sclA, simwA, bv);
  // out = att @ Wp + bp  (f32 out)
  gemm_bt<false, false, 128, 64><<<dim3(32, 6, 1), 256, 0, stream>>>(
      att, 768, 0, Wp_t, 768, 0, out, 768, 0, 4096, 768, 768,
      bp, nullptr, nullptr, nullptr, nullptr);
}

// Round 9
// 233.873 us; speedup vs baseline: 3.1032x; 1.0740x over previous
//
#include <hip/hip_runtime.h>

// ---------------------------------------------------------------------------
// AsymAttention on MI355X (gfx950).
// B=16, N=256, M=16, D=768, H=12, Dh=64.  scale = 1/8.
//
// Algebraic refactors:
//  (1) avoid sim k/v projections (155 GF):
//      logits_sim[b,h,n,m] = (se[b,n,m,:].T_row + q_h.bk_h) * scale,
//          T[b,n,h,D] = sum_dh q[b,h,n,dh] * Wk[D, h*64+dh]       (K=64 GEMM)
//      out_sim = Wv_h^T s_v + (sum a_sim) bv,  s_v = sum_m a_sim[m] se[b,n,m,:]
//  (2) single COALESCED se pass in fused_sim (dual-layout bf16 LDS staging).
//  (3) launch-graph compression: 6 kernels (prep_all; qkv; T-GEMM+attn_self
//      merged; fused_sim; outsim; final) — boundaries cost ~10us each.
// ---------------------------------------------------------------------------

typedef __attribute__((ext_vector_type(8))) short short8;   // 8 x bf16 (MFMA frag)
typedef __attribute__((ext_vector_type(4))) float f32x4;    // MFMA acc
typedef __attribute__((ext_vector_type(4))) unsigned short u16x4;

__device__ __forceinline__ float bf2f(unsigned short u) {
  union { unsigned int i; float f; } c; c.i = ((unsigned int)u) << 16; return c.f;
}
__device__ __forceinline__ unsigned short f2bf(float f) {
  union { float f; unsigned int i; } c; c.f = f;
  unsigned int r = c.i + 0x7fffu + ((c.i >> 16) & 1u);   // RNE
  return (unsigned short)(r >> 16);
}

// ------------------------------ prep (1 launch) ----------------------------
// bid < 3072 : cast x -> bf16 (4/thread) + cast Wk + concat bias
// bid >= 3072: W transpose-cast, t = bid-3072, z = t/576 selects Wq/Wk/Wv/Wp

__global__ void prep_all(const float* __restrict__ x, unsigned short* __restrict__ x_bf,
                         const float* __restrict__ Wq, const float* __restrict__ Wk,
                         const float* __restrict__ Wv, const float* __restrict__ Wp,
                         unsigned short* __restrict__ Wqkv_t, unsigned short* __restrict__ Wp_t,
                         unsigned short* __restrict__ Wk_bf,
                         const float* __restrict__ bq, const float* __restrict__ bk,
                         const float* __restrict__ bv, float* __restrict__ bqkv) {
  const int bid = blockIdx.x;
  const int tid = threadIdx.x;
  if (bid < 3072) {
    int t = bid * 256 + tid;
    {
      int i = t * 4;
      float4 v = *(const float4*)&x[i];
      x_bf[i+0] = f2bf(v.x); x_bf[i+1] = f2bf(v.y); x_bf[i+2] = f2bf(v.z); x_bf[i+3] = f2bf(v.w);
    }
    if (t < 147456) {
      int i = t * 4;
      float4 v = *(const float4*)&Wk[i];
      Wk_bf[i+0] = f2bf(v.x); Wk_bf[i+1] = f2bf(v.y); Wk_bf[i+2] = f2bf(v.z); Wk_bf[i+3] = f2bf(v.w);
    }
    if (t < 2304) bqkv[t] = (t < 768) ? bq[t] : ((t < 1536) ? bk[t - 768] : bv[t - 1536]);
  } else {
    const int t = bid - 3072;
    const int z = t / 576, xx = t % 576;
    const float* W = (z == 0) ? Wq : (z == 1) ? Wk : (z == 2) ? Wv : Wp;
    unsigned short* Wt = (z == 3) ? Wp_t : (Wqkv_t + (size_t)z * 589824);
    __shared__ float tile[32][33];
    int bx = xx % 24, by = xx / 24;
    int n0 = bx * 32, k0 = by * 32;
    for (int l = tid; l < 1024; l += 256) {
      int i = l >> 5, j = l & 31;
      tile[i][j] = W[(size_t)(k0 + i) * 768 + n0 + j];
    }
    __syncthreads();
    for (int l = tid; l < 1024; l += 256) {
      int i = l >> 5, j = l & 31;
      Wt[(size_t)(n0 + i) * 768 + k0 + j] = f2bf(tile[j][i]);
    }
  }
}

// ------------------------------- GEMM --------------------------------------
// C[128 x BN tile] = A[M x K](bf16 rm) * Bt[N x K]^T (+bias).  TBK=64 staged
// as two 32-wide panels (64B LDS row stride, m97 read pattern).  4 waves 2x2.
// 1D grid with bijective XCD swizzle (NXB blocks in x per s-row).
// SELFC epilogue: C = selfacc*scl + acc + simw*bv2.

template<bool OUT_BF16, bool SELFC, int BN, int NXB, bool SWZ>
__global__ __launch_bounds__(256)
void gemm_bt(const unsigned short* __restrict__ A, int lda, int zsA,
             const unsigned short* __restrict__ Bt, int ldb, int zsB,
             void* __restrict__ Cv, int ldc, int zsC,
             int M, int Nvalid, int K, int nblk,
             const float* __restrict__ bias,
             const float* __restrict__ selfacc,
             const float* __restrict__ scl,
             const float* __restrict__ simw,
             const float* __restrict__ bv2)
{
  constexpr int TBK = 64;
  constexpr int NF  = BN / 32;                 // n-frags per wave
  constexpr int AIT = (128 * TBK * 2) / 4096;  // A staging iters
  constexpr int BIT = (BN  * TBK * 2) / 4096;  // B staging iters
  constexpr int PA  = 128 * 64;                // A panel bytes
  constexpr int PB  = BN * 64;                 // B panel bytes
  int s = blockIdx.x;
  if (SWZ) { const int cpx = nblk >> 3; s = (s & 7) * cpx + (s >> 3); }
  const int xb = s % NXB;
  const int yb = (s / NXB);
  const int z = blockIdx.z;
  A  += (size_t)zsA * z;
  Bt += (size_t)zsB * z;
  const int row0 = xb * 128;
  const int col0 = yb * BN;
  __shared__ __align__(16) unsigned short lgA[128 * TBK];
  __shared__ __align__(16) unsigned short lgB[BN * TBK];
  const int tid = threadIdx.x;
  const int lane = tid & 63;
  const int w = tid >> 6;
  const int wr = w >> 1, wc = w & 1;
  const int lr = lane & 15, kg = lane >> 4;

  f32x4 acc[4][NF];
  #pragma unroll
  for (int m = 0; m < 4; m++)
    #pragma unroll
    for (int n = 0; n < NF; n++)
      #pragma unroll
      for (int q = 0; q < 4; q++) acc[m][n][q] = 0.f;

  for (int k0 = 0; k0 < K; k0 += TBK) {
    __syncthreads();
    #pragma unroll
    for (int it = 0; it < AIT; ++it) {
      const int off = it * 4096 + tid * 16;
      const int kp = off / PA, row = (off % PA) >> 6, colb = off & 63;
      const char* ga = (const char*)A + (size_t)(row0 + row) * (lda * 2) + (k0 + kp * 32) * 2 + colb;
      __builtin_amdgcn_global_load_lds((const __attribute__((address_space(1))) unsigned int*)ga,
                                       (__attribute__((address_space(3))) unsigned int*)((char*)lgA + off), 16, 0, 0);
    }
    #pragma unroll
    for (int it = 0; it < BIT; ++it) {
      const int off = it * 4096 + tid * 16;
      const int kp = off / PB, row = (off % PB) >> 6, colb = off & 63;
      const char* gb = (const char*)Bt + (size_t)(col0 + row) * (ldb * 2) + (k0 + kp * 32) * 2 + colb;
      __builtin_amdgcn_global_load_lds((const __attribute__((address_space(1))) unsigned int*)gb,
                                       (__attribute__((address_space(3))) unsigned int*)((char*)lgB + off), 16, 0, 0);
    }
    __syncthreads();
    #pragma unroll
    for (int kk = 0; kk < TBK; kk += 32) {
      short8 af[4], bfr[NF];
      #pragma unroll
      for (int m = 0; m < 4; m++)
        af[m] = *(const short8*)&lgA[(kk >> 5) * (128 * 32) + (wr * 64 + m * 16 + lr) * 32 + kg * 8];
      #pragma unroll
      for (int n = 0; n < NF; n++)
        bfr[n] = *(const short8*)&lgB[(kk >> 5) * (BN * 32) + (wc * (BN / 2) + n * 16 + lr) * 32 + kg * 8];
      #pragma unroll
      for (int m = 0; m < 4; m++)
        #pragma unroll
        for (int n = 0; n < NF; n++)
          acc[m][n] = __builtin_amdgcn_mfma_f32_16x16x32_bf16(af[m], bfr[n], acc[m][n], 0, 0, 0);
    }
  }

  // epilogue: C layout col=lane&15, row=(lane>>4)*4+reg
  #pragma unroll
  for (int m = 0; m < 4; m++) {
    #pragma unroll
    for (int n = 0; n < NF; n++) {
      const int gc = col0 + wc * (BN / 2) + n * 16 + lr;
      if (gc >= Nvalid) continue;
      #pragma unroll
      for (int j = 0; j < 4; j++) {
        const int gr = row0 + wr * 64 + m * 16 + kg * 4 + j;
        if (gr >= M) continue;
        float v = acc[m][n][j];
        if (bias) v += bias[gc];
        if (SELFC) {
          v += selfacc[(size_t)gr * 768 + z * 64 + gc] * scl[(size_t)gr * 12 + z]
             + simw[(size_t)gr * 12 + z] * bv2[z * 64 + gc];
        }
        const size_t idx = (size_t)gr * ldc + gc;
        if (OUT_BF16) {
          unsigned short* C = (unsigned short*)Cv + (size_t)zsC * z;
          C[idx] = f2bf(v);
        } else {
          float* C = (float*)Cv + (size_t)zsC * z;
          C[idx] = v;
        }
      }
    }
  }
}

// ----------------- merged: attn_self (768 blks) + T-GEMM (2304) ------------
// attn part: 4 blocks per (b,h), 64 q-rows per block, 4 waves x 16 rows.
// T part:    T[r, h*768+d] = q_h @ Wk_h^T per head; 128x128 tile, single
//            K-step (K=64).  Shared 70.6KB LDS union -> 2 blocks/CU.

__global__ __launch_bounds__(256, 2)
void tattn_kernel(const unsigned short* __restrict__ qkv,
                  const unsigned short* __restrict__ Wk_bf,
                  unsigned short* __restrict__ Tbuf,
                  float* __restrict__ selfacc,
                  float* __restrict__ mstat,
                  float* __restrict__ sstat)
{
  __shared__ __align__(16) char smem[70656];
  const int tid = threadIdx.x;
  const int lane = tid & 63;
  const int w = tid >> 6;
  const int lr = lane & 15, kg = lane >> 4;

  if (blockIdx.x >= 768) {
    // ---------------- T-GEMM body ----------------
    const int bid = blockIdx.x - 768;
    const int xb = bid % 32, yb = (bid / 32) % 6, z = bid / 192;
    const int row0 = xb * 128, col0 = yb * 128;
    const int wr = w >> 1, wc = w & 1;
    const unsigned short* A  = qkv + 64 * z;          // lda 2304
    const unsigned short* Bt = Wk_bf + 64 * z;        // ldb 768
    unsigned short* lgA = (unsigned short*)smem;               // 128x64
    unsigned short* lgB = (unsigned short*)(smem + 16384);     // 128x64

    f32x4 acc[4][4];
    #pragma unroll
    for (int m = 0; m < 4; m++)
      #pragma unroll
      for (int n = 0; n < 4; n++)
        #pragma unroll
        for (int q = 0; q < 4; q++) acc[m][n][q] = 0.f;

    #pragma unroll
    for (int it = 0; it < 4; ++it) {
      const int off = it * 4096 + tid * 16;
      const int kp = off / 8192, row = (off % 8192) >> 6, colb = off & 63;
      const char* ga = (const char*)A + (size_t)(row0 + row) * 4608 + (kp * 32) * 2 + colb;
      __builtin_amdgcn_global_load_lds((const __attribute__((address_space(1))) unsigned int*)ga,
                                       (__attribute__((address_space(3))) unsigned int*)((char*)lgA + off), 16, 0, 0);
      const char* gb = (const char*)Bt + (size_t)(col0 + row) * 1536 + (kp * 32) * 2 + colb;
      __builtin_amdgcn_global_load_lds((const __attribute__((address_space(1))) unsigned int*)gb,
                                       (__attribute__((address_space(3))) unsigned int*)((char*)lgB + off), 16, 0, 0);
    }
    __syncthreads();
    #pragma unroll
    for (int kk = 0; kk < 64; kk += 32) {
      short8 af[4], bfr[4];
      #pragma unroll
      for (int m = 0; m < 4; m++)
        af[m] = *(const short8*)&lgA[(kk >> 5) * 4096 + (wr * 64 + m * 16 + lr) * 32 + kg * 8];
      #pragma unroll
      for (int n = 0; n < 4; n++)
        bfr[n] = *(const short8*)&lgB[(kk >> 5) * 4096 + (wc * 64 + n * 16 + lr) * 32 + kg * 8];
      #pragma unroll
      for (int m = 0; m < 4; m++)
        #pragma unroll
        for (int n = 0; n < 4; n++)
          acc[m][n] = __builtin_amdgcn_mfma_f32_16x16x32_bf16(af[m], bfr[n], acc[m][n], 0, 0, 0);
    }
    #pragma unroll
    for (int m = 0; m < 4; m++)
      #pragma unroll
      for (int n = 0; n < 4; n++) {
        const int gc = col0 + wc * 64 + n * 16 + lr;
        #pragma unroll
        for (int j = 0; j < 4; j++) {
          const int gr = row0 + wr * 64 + m * 16 + kg * 4 + j;
          Tbuf[(size_t)gr * 9216 + z * 768 + gc] = f2bf(acc[m][n][j]);
        }
      }
    return;
  }

  // ---------------- attn_self body ----------------
  const int bh = blockIdx.x >> 2;
  const int qq = blockIdx.x & 3;
  const int b = bh / 12;
  const int h = bh % 12;
  const size_t rowbase = (size_t)b * 256;
  const int rows0 = qq * 64 + w * 16;            // this wave's 16 q-rows

  unsigned short* Ks = (unsigned short*)smem;             // [256][72]
  unsigned short* VT = (unsigned short*)(smem + 36864);   // [64][264]  VT[d][k]=V[k][d]
  unsigned short* aL = (unsigned short*)(smem + (size_t)w * 4352); // [16][136]/wave, aliases Ks

  for (int it = 0; it < 8; ++it) {
    const int idx = tid * 8 + it * 2048;
    const int row = idx >> 6, d = idx & 63;
    *(short8*)&Ks[row * 72 + d] =
        *(const short8*)&qkv[(rowbase + row) * 2304 + 768 + h * 64 + d];
  }
  #pragma unroll
  for (int it = 0; it < 16; ++it) {
    const int kk = w * 64 + it * 4 + kg;
    const int d0 = lr * 4;
    u16x4 v4 = *(const u16x4*)&qkv[(rowbase + kk) * 2304 + 1536 + h * 64 + d0];
    VT[(d0+0) * 264 + kk] = v4.x;
    VT[(d0+1) * 264 + kk] = v4.y;
    VT[(d0+2) * 264 + kk] = v4.z;
    VT[(d0+3) * 264 + kk] = v4.w;
  }
  __syncthreads();

  f32x4 acc[16];
  #pragma unroll
  for (int n = 0; n < 16; n++)
    #pragma unroll
    for (int q = 0; q < 4; q++) acc[n][q] = 0.f;

  #pragma unroll
  for (int ks = 0; ks < 64; ks += 32) {           // QK^T, K=64; Q from global
    short8 af = *(const short8*)&qkv[(rowbase + rows0 + lr) * 2304 + h * 64 + ks + kg * 8];
    #pragma unroll
    for (int n = 0; n < 16; n++) {
      short8 bfr = *(const short8*)&Ks[(n * 16 + lr) * 72 + ks + kg * 8];
      acc[n] = __builtin_amdgcn_mfma_f32_16x16x32_bf16(af, bfr, acc[n], 0, 0, 0);
    }
  }

  #pragma unroll
  for (int j = 0; j < 4; j++) {
    float vmx = -1e30f;
    #pragma unroll
    for (int n = 0; n < 16; n++) { float s = acc[n][j] * 0.125f; acc[n][j] = s; vmx = fmaxf(vmx, s); }
    #pragma unroll
    for (int s = 1; s < 16; s <<= 1) vmx = fmaxf(vmx, __shfl_xor(vmx, s));
    float sum = 0.f;
    #pragma unroll
    for (int n = 0; n < 16; n++) { float e = __expf(acc[n][j] - vmx); acc[n][j] = e; sum += e; }
    #pragma unroll
    for (int s = 1; s < 16; s <<= 1) sum += __shfl_xor(sum, s);
    if (lr == 0) {
      const int row = rows0 + kg * 4 + j;
      mstat[(rowbase + row) * 12 + h] = vmx;
      sstat[(rowbase + row) * 12 + h] = sum;
    }
  }

  __syncthreads();   // all waves done reading Ks before aL overwrites it

  f32x4 acc2[4];
  #pragma unroll
  for (int m = 0; m < 4; m++)
    #pragma unroll
    for (int q = 0; q < 4; q++) acc2[m][q] = 0.f;

  #pragma unroll
  for (int hl = 0; hl < 2; ++hl) {   // PV in two 128-col halves
    #pragma unroll
    for (int j = 0; j < 4; j++) {
      const int rw = kg * 4 + j;
      #pragma unroll
      for (int n2 = 0; n2 < 8; n2++)
        aL[rw * 136 + n2 * 16 + lr] = f2bf(acc[hl * 8 + n2][j]);   // unnormalized
    }
    #pragma unroll
    for (int ks2 = 0; ks2 < 4; ++ks2) {   // out^T = VT * a^T
      short8 pf = *(const short8*)&aL[lr * 136 + ks2 * 32 + kg * 8];
      #pragma unroll
      for (int mm = 0; mm < 4; mm++) {
        short8 vf = *(const short8*)&VT[(mm * 16 + lr) * 264 + hl * 128 + ks2 * 32 + kg * 8];
        acc2[mm] = __builtin_amdgcn_mfma_f32_16x16x32_bf16(vf, pf, acc2[mm], 0, 0, 0);
      }
    }
  }

  #pragma unroll
  for (int mm = 0; mm < 4; mm++)      // D rows = dh, D cols = q-row (lr)
    #pragma unroll
    for (int j = 0; j < 4; j++) {
      const int dh = mm * 16 + kg * 4 + j;
      const int rn = rows0 + lr;
      selfacc[(rowbase + rn) * 768 + h * 64 + dh] = acc2[mm][j];   // f32 unnorm
    }
}

// --------------------- fused sim logits + renorm + s_v (MFMA) --------------
// One block per (b,n) = r, 8 waves, 512 threads.  (See R6 notes.)

__global__ __launch_bounds__(512, 4)
void fused_sim_kernel(const float* __restrict__ se, const unsigned short* __restrict__ T,
                      const unsigned short* __restrict__ qkv, const float* __restrict__ bk,
                      const float* __restrict__ mstat, const float* __restrict__ sstat,
                      unsigned short* __restrict__ s_v,
                      float* __restrict__ sclA, float* __restrict__ simwA)
{
  const int r = blockIdx.x;                    // b*256+n
  __shared__ __align__(16) unsigned int SE_T32[768 * 9];   // 27648 B
  __shared__ __align__(16) unsigned int SErm[16][388];     // 24832 B (776-elem rows)
  __shared__ __align__(16) float Lp[8][64][4];             // 8192 B
  __shared__ float qb[16];
  const int tid = threadIdx.x;
  const int w = tid >> 6, lane = tid & 63;
  const int lr = lane & 15, kg = lane >> 4;

  // ---- coalesced stage: wave w owns se rows m = {2w, 2w+1} ----
  const float* se_r = se + (size_t)r * 12288;
  unsigned short va[2][12];
  #pragma unroll
  for (int c = 0; c < 3; ++c) {
    float4 fa = *(const float4*)&se_r[(2 * w) * 768 + c * 256 + lane * 4];
    float4 fb = *(const float4*)&se_r[(2 * w + 1) * 768 + c * 256 + lane * 4];
    va[0][c*4+0] = f2bf(fa.x); va[0][c*4+1] = f2bf(fa.y); va[0][c*4+2] = f2bf(fa.z); va[0][c*4+3] = f2bf(fa.w);
    va[1][c*4+0] = f2bf(fb.x); va[1][c*4+1] = f2bf(fb.y); va[1][c*4+2] = f2bf(fb.z); va[1][c*4+3] = f2bf(fb.w);
  }
  #pragma unroll
  for (int c = 0; c < 3; ++c) {
    #pragma unroll
    for (int j = 0; j < 4; ++j) {        // SE_T: m-pair packed, swizzled dword col
      const int d = c * 256 + lane * 4 + j;
      SE_T32[d * 9 + (w ^ ((d >> 5) & 7))] =
          (unsigned int)va[0][c*4+j] | ((unsigned int)va[1][c*4+j] << 16);
    }
    #pragma unroll
    for (int rr = 0; rr < 2; ++rr) {     // SErm: row-major k-pairs, b64 writes
      uint2 pk;
      pk.x = (unsigned int)va[rr][c*4+0] | ((unsigned int)va[rr][c*4+1] << 16);
      pk.y = (unsigned int)va[rr][c*4+2] | ((unsigned int)va[rr][c*4+3] << 16);
      *(uint2*)&SErm[2 * w + rr][c * 128 + lane * 2] = pk;
    }
  }
  // qb[h] = q_h . bk_h  (waves 0..5, 2 heads each)
  if (w < 6) {
    #pragma unroll
    for (int i = 0; i < 2; ++i) {
      const int hh = w * 2 + i;
      float p = bf2f(qkv[(size_t)r * 2304 + hh * 64 + lane]) * bk[hh * 64 + lane];
      #pragma unroll
      for (int sft = 32; sft; sft >>= 1) p += __shfl_xor(p, sft);
      if (lane == 0) qb[hh] = p;
    }
  }
  if (tid < 4) qb[12 + tid] = 0.f;

  // T B-frags for this wave's K-range (global, L3-resident; no LDS dep)
  short8 bfr[3];
  #pragma unroll
  for (int s = 0; s < 3; ++s)
    bfr[s] = *(const short8*)&T[(size_t)r * 9216 + lr * 768 + w * 96 + s * 32 + kg * 8];

  __syncthreads();

  // ---- L-GEMM partial: K in [w*96, w*96+96) ----
  f32x4 accL = {0.f, 0.f, 0.f, 0.f};
  #pragma unroll
  for (int s = 0; s < 3; ++s) {
    const int kb = w * 96 + s * 32 + kg * 8;
    short8 af = *(const short8*)&SErm[lr][kb >> 1];
    accL = __builtin_amdgcn_mfma_f32_16x16x32_bf16(af, bfr[s], accL, 0, 0, 0);
  }
  *(f32x4*)&Lp[w][lane][0] = accL;
  __syncthreads();

  // ---- softmax + joint renorm (redundant per wave; m=kg*4+j, h=lr) ----
  float vals[4] = {0.f, 0.f, 0.f, 0.f};
  #pragma unroll
  for (int ww = 0; ww < 8; ++ww) {
    f32x4 p = *(const f32x4*)&Lp[ww][lane][0];
    vals[0] += p[0]; vals[1] += p[1]; vals[2] += p[2]; vals[3] += p[3];
  }
  #pragma unroll
  for (int j = 0; j < 4; ++j) vals[j] = vals[j] * 0.125f + qb[lr];
  float mx = fmaxf(fmaxf(vals[0], vals[1]), fmaxf(vals[2], vals[3]));
  mx = fmaxf(mx, __shfl_xor(mx, 16));
  mx = fmaxf(mx, __shfl_xor(mx, 32));
  const int hidx = r * 12 + (lr < 12 ? lr : 11);
  const float msf = mstat[hidx];
  const float ssf = sstat[hidx];
  const float mj = fmaxf(mx, msf);
  float ea[4];
  #pragma unroll
  for (int j = 0; j < 4; ++j) ea[j] = __expf(vals[j] - mj);
  float ssum = ea[0] + ea[1] + ea[2] + ea[3];
  ssum += __shfl_xor(ssum, 16);
  ssum += __shfl_xor(ssum, 32);
  const float alpha = __expf(msf - mj);
  const float invZ = 1.0f / (ssf * alpha + ssum);
  float a[4];
  #pragma unroll
  for (int j = 0; j < 4; ++j) a[j] = ea[j] * invZ;
  if (w == 0 && kg == 0 && lr < 12) {
    sclA[(size_t)r * 12 + lr]  = alpha * invZ;
    simwA[(size_t)r * 12 + lr] = ssum * invZ;
  }

  // ---- a^T A-frag: lane (h=lr, kg) needs a[m=kg*8+e][h], zeros for kg>=2 ----
  short8 af8;
  #pragma unroll
  for (int e = 0; e < 8; ++e) {
    const int src = lr + ((kg & 1) * 2 + (e >> 2)) * 16;
    const float v = __shfl(a[e & 3], src);
    af8[e] = (kg < 2) ? (short)f2bf(v) : (short)0;
  }

  // ---- s_v GEMM: 6 d-tiles per wave, one mfma each ----
  #pragma unroll
  for (int i = 0; i < 6; ++i) {
    const int ntile = w + i * 8;
    const int row = ntile * 16 + lr;
    const int sw = (row >> 5) & 7;
    union { unsigned int u[4]; short8 s8; } bu;
    #pragma unroll
    for (int j = 0; j < 4; ++j)
      bu.u[j] = SE_T32[row * 9 + (((kg & 1) * 4 + j) ^ sw)];
    f32x4 cacc = {0.f, 0.f, 0.f, 0.f};
    cacc = __builtin_amdgcn_mfma_f32_16x16x32_bf16(af8, bu.s8, cacc, 0, 0, 0);
    if (kg < 3) {
      #pragma unroll
      for (int j = 0; j < 4; ++j) {
        const int h = kg * 4 + j;
        s_v[(size_t)r * 9216 + h * 768 + ntile * 16 + lr] = f2bf(cacc[j]);
      }
    }
  }
}

// ------------------------------- launcher ----------------------------------

extern "C" void kernel_launch(void* const* d_in, const int* in_sizes, int n_in,
                              void* d_out, int out_size, void* d_ws, size_t ws_size,
                              hipStream_t stream) {
  const float* x  = (const float*)d_in[0];
  const float* se = (const float*)d_in[1];
  const float* Wq = (const float*)d_in[2];
  const float* bq = (const float*)d_in[3];
  const float* Wk = (const float*)d_in[4];
  const float* bk = (const float*)d_in[5];
  const float* Wv = (const float*)d_in[6];
  const float* bv = (const float*)d_in[7];
  const float* Wp = (const float*)d_in[8];
  const float* bp = (const float*)d_in[9];
  float* out = (float*)d_out;
  char* ws = (char*)d_ws;

  // workspace layout (256B-aligned), total ~120.4 MB
  unsigned short* x_bf    = (unsigned short*)(ws);                 // 4096x768   bf16
  unsigned short* Wqkv_t  = (unsigned short*)(ws + 6291456);       // 2304x768   bf16  Wq^T|Wk^T|Wv^T rows
  unsigned short* Wp_t    = (unsigned short*)(ws + 9830400);       // 768x768    bf16
  unsigned short* Wk_bf   = (unsigned short*)(ws + 11010048);      // 768x768    bf16 (untransposed)
  float*          bqkv    = (float*)(ws + 12189696);               // 2304       f32
  unsigned short* qkv     = (unsigned short*)(ws + 12198912);      // 4096x2304  bf16  q|k|v
  unsigned short* Tbuf    = (unsigned short*)(ws + 31073280);      // 4096x12x768 bf16  T, then s_v
  float*          selfacc = (float*)(ws + 106570752);              // 4096x768   f32  unnorm out_self
  float*          mstat   = (float*)(ws + 119153664);              // 4096x12    f32
  float*          sstat   = (float*)(ws + 119350272);              // 4096x12    f32
  float*          sclA    = (float*)(ws + 119546880);              // 4096x12    f32
  float*          simwA   = (float*)(ws + 119743488);              // 4096x12    f32
  unsigned short* att     = (unsigned short*)(ws + 119940096);     // 4096x768   bf16

  prep_all<<<5376, 256, 0, stream>>>(x, x_bf, Wq, Wk, Wv, Wp, Wqkv_t, Wp_t,
                                     Wk_bf, bq, bk, bv, bqkv);

  // qkv = x @ [Wq|Wk|Wv] + bias  (M=4096, N=2304, K=768), XCD-swizzled 1D grid
  gemm_bt<true, false, 128, 32, true><<<576, 256, 0, stream>>>(
      x_bf, 768, 0, Wqkv_t, 768, 0, qkv, 2304, 0, 4096, 2304, 768, 576,
      bqkv, nullptr, nullptr, nullptr, nullptr);

  // merged: attn_self (768 blocks) + T-GEMM (2304 blocks)
  tattn_kernel<<<3072, 256, 0, stream>>>(qkv, Wk_bf, Tbuf, selfacc, mstat, sstat);

  fused_sim_kernel<<<4096, 512, 0, stream>>>(se, Tbuf, qkv, bk, mstat, sstat,
                                             Tbuf /* s_v overwrites T in-place per r */,
                                             sclA, simwA);

  // att = selfacc*scl + s_v_h @ Wv_h + simw*bv_h   (per-head z=12, N=64, K=768)
  gemm_bt<true, true, 64, 32, false><<<dim3(32, 1, 12), 256, 0, stream>>>(
      Tbuf, 9216, 768, Wqkv_t + 1536 * 768, 768, 64 * 768, att, 768, 64,
      4096, 64, 768, 32, nullptr, selfacc, sclA, simwA, bv);
  // out = att @ Wp + bp  (f32 out), XCD-swizzled 1D grid
  gemm_bt<false, false, 128, 32, true><<<192, 256, 0, stream>>>(
      att, 768, 0, Wp_t, 768, 0, out, 768, 0, 4096, 768, 768, 192,
      bp, nullptr, nullptr, nullptr, nullptr);
}

// Round 11
// 196.156 us; speedup vs baseline: 3.6999x; 1.1923x over previous
//
#include <hip/hip_runtime.h>

// ---------------------------------------------------------------------------
// AsymAttention on MI355X (gfx950).
// B=16, N=256, M=16, D=768, H=12, Dh=64.  scale = 1/8.
//
// Algebraic refactors:
//  (1) avoid sim k/v projections (155 GF):
//      logits_sim[b,h,n,m] = (se[b,n,m,:].T_row + q_h.bk_h) * scale,
//          T[b,n,h,D] = sum_dh q[b,h,n,dh] * Wk[D, h*64+dh]       (K=64 GEMM)
//      out_sim = Wv_h^T s_v + (sum a_sim) bv,  s_v = sum_m a_sim[m] se[b,n,m,:]
//  (2) single COALESCED se pass in fused_sim (dual-layout bf16 LDS staging).
//  (3) launch-graph compression: 6 kernels; qkv uses a 512-thread 256x128
//      tile (288 blocks); outsim ZY-grid (z=s/32); final yb-grid (yb=s/32).
// ---------------------------------------------------------------------------

typedef __attribute__((ext_vector_type(8))) short short8;   // 8 x bf16 (MFMA frag)
typedef __attribute__((ext_vector_type(4))) float f32x4;    // MFMA acc
typedef __attribute__((ext_vector_type(4))) unsigned short u16x4;

__device__ __forceinline__ float bf2f(unsigned short u) {
  union { unsigned int i; float f; } c; c.i = ((unsigned int)u) << 16; return c.f;
}
__device__ __forceinline__ unsigned short f2bf(float f) {
  union { float f; unsigned int i; } c; c.f = f;
  unsigned int r = c.i + 0x7fffu + ((c.i >> 16) & 1u);   // RNE
  return (unsigned short)(r >> 16);
}

// ------------------------------ prep (1 launch) ----------------------------

__global__ void prep_all(const float* __restrict__ x, unsigned short* __restrict__ x_bf,
                         const float* __restrict__ Wq, const float* __restrict__ Wk,
                         const float* __restrict__ Wv, const float* __restrict__ Wp,
                         unsigned short* __restrict__ Wqkv_t, unsigned short* __restrict__ Wp_t,
                         unsigned short* __restrict__ Wk_bf,
                         const float* __restrict__ bq, const float* __restrict__ bk,
                         const float* __restrict__ bv, float* __restrict__ bqkv) {
  const int bid = blockIdx.x;
  const int tid = threadIdx.x;
  if (bid < 3072) {
    int t = bid * 256 + tid;
    {
      int i = t * 4;
      float4 v = *(const float4*)&x[i];
      x_bf[i+0] = f2bf(v.x); x_bf[i+1] = f2bf(v.y); x_bf[i+2] = f2bf(v.z); x_bf[i+3] = f2bf(v.w);
    }
    if (t < 147456) {
      int i = t * 4;
      float4 v = *(const float4*)&Wk[i];
      Wk_bf[i+0] = f2bf(v.x); Wk_bf[i+1] = f2bf(v.y); Wk_bf[i+2] = f2bf(v.z); Wk_bf[i+3] = f2bf(v.w);
    }
    if (t < 2304) bqkv[t] = (t < 768) ? bq[t] : ((t < 1536) ? bk[t - 768] : bv[t - 1536]);
  } else {
    const int t = bid - 3072;
    const int z = t / 576, xx = t % 576;
    const float* W = (z == 0) ? Wq : (z == 1) ? Wk : (z == 2) ? Wv : Wp;
    unsigned short* Wt = (z == 3) ? Wp_t : (Wqkv_t + (size_t)z * 589824);
    __shared__ float tile[32][33];
    int bx = xx % 24, by = xx / 24;
    int n0 = bx * 32, k0 = by * 32;
    for (int l = tid; l < 1024; l += 256) {
      int i = l >> 5, j = l & 31;
      tile[i][j] = W[(size_t)(k0 + i) * 768 + n0 + j];
    }
    __syncthreads();
    for (int l = tid; l < 1024; l += 256) {
      int i = l >> 5, j = l & 31;
      Wt[(size_t)(n0 + i) * 768 + k0 + j] = f2bf(tile[j][i]);
    }
  }
}

// --------------------- qkv GEMM: 512 threads, 256x128 tile -----------------
// C[256 x 128] = A[4096 x 768] * Bt[2304 x 768]^T + bias.  TBK=64 as two
// 32-wide panels.  8 waves (4 row x 2 col), 64x64 per wave.  288 blocks,
// bijective XCD swizzle.

__global__ __launch_bounds__(512)
void gemm_qkv(const unsigned short* __restrict__ A,
              const unsigned short* __restrict__ Bt,
              unsigned short* __restrict__ C,
              const float* __restrict__ bias)
{
  int s = blockIdx.x;
  s = (s & 7) * 36 + (s >> 3);              // 288 = 8 * 36, bijective
  const int xb = s % 16, yb = s / 16;       // 16 x 18
  const int row0 = xb * 256;
  const int col0 = yb * 128;
  __shared__ __align__(16) unsigned short lgA[256 * 64];   // 32 KB
  __shared__ __align__(16) unsigned short lgB[128 * 64];   // 16 KB
  const int tid = threadIdx.x;
  const int lane = tid & 63;
  const int w = tid >> 6;                   // 0..7
  const int wr = w >> 1, wc = w & 1;        // 4 x 2
  const int lr = lane & 15, kg = lane >> 4;

  f32x4 acc[4][4];
  #pragma unroll
  for (int m = 0; m < 4; m++)
    #pragma unroll
    for (int n = 0; n < 4; n++)
      #pragma unroll
      for (int q = 0; q < 4; q++) acc[m][n][q] = 0.f;

  for (int k0 = 0; k0 < 768; k0 += 64) {
    __syncthreads();
    #pragma unroll
    for (int it = 0; it < 4; ++it) {        // A: 32 KB, panel 16 KB (256x32)
      const int off = it * 8192 + tid * 16;
      const int kp = off >> 14, row = (off & 16383) >> 6, colb = off & 63;
      const char* ga = (const char*)A + (size_t)(row0 + row) * 1536 + (k0 + kp * 32) * 2 + colb;
      __builtin_amdgcn_global_load_lds((const __attribute__((address_space(1))) unsigned int*)ga,
                                       (__attribute__((address_space(3))) unsigned int*)((char*)lgA + off), 16, 0, 0);
    }
    #pragma unroll
    for (int it = 0; it < 2; ++it) {        // B: 16 KB, panel 8 KB (128x32)
      const int off = it * 8192 + tid * 16;
      const int kp = off >> 13, row = (off & 8191) >> 6, colb = off & 63;
      const char* gb = (const char*)Bt + (size_t)(col0 + row) * 1536 + (k0 + kp * 32) * 2 + colb;
      __builtin_amdgcn_global_load_lds((const __attribute__((address_space(1))) unsigned int*)gb,
                                       (__attribute__((address_space(3))) unsigned int*)((char*)lgB + off), 16, 0, 0);
    }
    __syncthreads();
    #pragma unroll
    for (int kk = 0; kk < 64; kk += 32) {
      short8 af[4], bfr[4];
      #pragma unroll
      for (int m = 0; m < 4; m++)
        af[m] = *(const short8*)&lgA[(kk >> 5) * (256 * 32) + (wr * 64 + m * 16 + lr) * 32 + kg * 8];
      #pragma unroll
      for (int n = 0; n < 4; n++)
        bfr[n] = *(const short8*)&lgB[(kk >> 5) * (128 * 32) + (wc * 64 + n * 16 + lr) * 32 + kg * 8];
      #pragma unroll
      for (int m = 0; m < 4; m++)
        #pragma unroll
        for (int n = 0; n < 4; n++)
          acc[m][n] = __builtin_amdgcn_mfma_f32_16x16x32_bf16(af[m], bfr[n], acc[m][n], 0, 0, 0);
    }
  }

  #pragma unroll
  for (int m = 0; m < 4; m++)
    #pragma unroll
    for (int n = 0; n < 4; n++) {
      const int gc = col0 + wc * 64 + n * 16 + lr;
      #pragma unroll
      for (int j = 0; j < 4; j++) {
        const int gr = row0 + wr * 64 + m * 16 + kg * 4 + j;
        C[(size_t)gr * 2304 + gc] = f2bf(acc[m][n][j] + bias[gc]);
      }
    }
}

// ------------------------------- GEMM (generic) ----------------------------
// C[128 x BN tile] = A * Bt^T (+bias).  TBK=64 two-panel staging.  4 waves.
// 1D grid, optional bijective XCD swizzle.
// ZY=true : z  = s/NXB (yb=0)   — per-head GEMMs (outsim)
// ZY=false: yb = s/NXB, z=bIdx.z — plain column tiling (final)
// SELFC epilogue: C = selfacc*scl + acc + simw*bv2.

template<bool OUT_BF16, bool SELFC, int BN, int NXB, bool SWZ, bool ZY>
__global__ __launch_bounds__(256)
void gemm_bt(const unsigned short* __restrict__ A, int lda, int zsA,
             const unsigned short* __restrict__ Bt, int ldb, int zsB,
             void* __restrict__ Cv, int ldc, int zsC,
             int M, int Nvalid, int K, int nblk,
             const float* __restrict__ bias,
             const float* __restrict__ selfacc,
             const float* __restrict__ scl,
             const float* __restrict__ simw,
             const float* __restrict__ bv2)
{
  constexpr int TBK = 64;
  constexpr int NF  = BN / 32;
  constexpr int AIT = (128 * TBK * 2) / 4096;
  constexpr int BIT = (BN  * TBK * 2) / 4096;
  constexpr int PA  = 128 * 64;
  constexpr int PB  = BN * 64;
  int s = blockIdx.x;
  if (SWZ) { const int cpx = nblk >> 3; s = (s & 7) * cpx + (s >> 3); }
  const int xb = s % NXB;
  const int sq = s / NXB;
  const int yb = ZY ? 0 : sq;
  const int z  = ZY ? sq : blockIdx.z;
  A  += (size_t)zsA * z;
  Bt += (size_t)zsB * z;
  const int row0 = xb * 128;
  const int col0 = yb * BN;
  __shared__ __align__(16) unsigned short lgA[128 * TBK];
  __shared__ __align__(16) unsigned short lgB[BN * TBK];
  const int tid = threadIdx.x;
  const int lane = tid & 63;
  const int w = tid >> 6;
  const int wr = w >> 1, wc = w & 1;
  const int lr = lane & 15, kg = lane >> 4;

  f32x4 acc[4][NF];
  #pragma unroll
  for (int m = 0; m < 4; m++)
    #pragma unroll
    for (int n = 0; n < NF; n++)
      #pragma unroll
      for (int q = 0; q < 4; q++) acc[m][n][q] = 0.f;

  for (int k0 = 0; k0 < K; k0 += TBK) {
    __syncthreads();
    #pragma unroll
    for (int it = 0; it < AIT; ++it) {
      const int off = it * 4096 + tid * 16;
      const int kp = off / PA, row = (off % PA) >> 6, colb = off & 63;
      const char* ga = (const char*)A + (size_t)(row0 + row) * (lda * 2) + (k0 + kp * 32) * 2 + colb;
      __builtin_amdgcn_global_load_lds((const __attribute__((address_space(1))) unsigned int*)ga,
                                       (__attribute__((address_space(3))) unsigned int*)((char*)lgA + off), 16, 0, 0);
    }
    #pragma unroll
    for (int it = 0; it < BIT; ++it) {
      const int off = it * 4096 + tid * 16;
      const int kp = off / PB, row = (off % PB) >> 6, colb = off & 63;
      const char* gb = (const char*)Bt + (size_t)(col0 + row) * (ldb * 2) + (k0 + kp * 32) * 2 + colb;
      __builtin_amdgcn_global_load_lds((const __attribute__((address_space(1))) unsigned int*)gb,
                                       (__attribute__((address_space(3))) unsigned int*)((char*)lgB + off), 16, 0, 0);
    }
    __syncthreads();
    #pragma unroll
    for (int kk = 0; kk < TBK; kk += 32) {
      short8 af[4], bfr[NF];
      #pragma unroll
      for (int m = 0; m < 4; m++)
        af[m] = *(const short8*)&lgA[(kk >> 5) * (128 * 32) + (wr * 64 + m * 16 + lr) * 32 + kg * 8];
      #pragma unroll
      for (int n = 0; n < NF; n++)
        bfr[n] = *(const short8*)&lgB[(kk >> 5) * (BN * 32) + (wc * (BN / 2) + n * 16 + lr) * 32 + kg * 8];
      #pragma unroll
      for (int m = 0; m < 4; m++)
        #pragma unroll
        for (int n = 0; n < NF; n++)
          acc[m][n] = __builtin_amdgcn_mfma_f32_16x16x32_bf16(af[m], bfr[n], acc[m][n], 0, 0, 0);
    }
  }

  #pragma unroll
  for (int m = 0; m < 4; m++) {
    #pragma unroll
    for (int n = 0; n < NF; n++) {
      const int gc = col0 + wc * (BN / 2) + n * 16 + lr;
      if (gc >= Nvalid) continue;
      #pragma unroll
      for (int j = 0; j < 4; j++) {
        const int gr = row0 + wr * 64 + m * 16 + kg * 4 + j;
        if (gr >= M) continue;
        float v = acc[m][n][j];
        if (bias) v += bias[gc];
        if (SELFC) {
          v += selfacc[(size_t)gr * 768 + z * 64 + gc] * scl[(size_t)gr * 12 + z]
             + simw[(size_t)gr * 12 + z] * bv2[z * 64 + gc];
        }
        const size_t idx = (size_t)gr * ldc + gc;
        if (OUT_BF16) {
          unsigned short* C = (unsigned short*)Cv + (size_t)zsC * z;
          C[idx] = f2bf(v);
        } else {
          float* C = (float*)Cv + (size_t)zsC * z;
          C[idx] = v;
        }
      }
    }
  }
}

// ----------------- merged: attn_self (768 blks) + T-GEMM (2304) ------------

__global__ __launch_bounds__(256, 2)
void tattn_kernel(const unsigned short* __restrict__ qkv,
                  const unsigned short* __restrict__ Wk_bf,
                  unsigned short* __restrict__ Tbuf,
                  float* __restrict__ selfacc,
                  float* __restrict__ mstat,
                  float* __restrict__ sstat)
{
  __shared__ __align__(16) char smem[70656];
  const int tid = threadIdx.x;
  const int lane = tid & 63;
  const int w = tid >> 6;
  const int lr = lane & 15, kg = lane >> 4;

  if (blockIdx.x >= 768) {
    // ---------------- T-GEMM body ----------------
    const int bid = blockIdx.x - 768;
    const int xb = bid % 32, yb = (bid / 32) % 6, z = bid / 192;
    const int row0 = xb * 128, col0 = yb * 128;
    const int wr = w >> 1, wc = w & 1;
    const unsigned short* A  = qkv + 64 * z;          // lda 2304
    const unsigned short* Bt = Wk_bf + 64 * z;        // ldb 768
    unsigned short* lgA = (unsigned short*)smem;               // 128x64
    unsigned short* lgB = (unsigned short*)(smem + 16384);     // 128x64

    f32x4 acc[4][4];
    #pragma unroll
    for (int m = 0; m < 4; m++)
      #pragma unroll
      for (int n = 0; n < 4; n++)
        #pragma unroll
        for (int q = 0; q < 4; q++) acc[m][n][q] = 0.f;

    #pragma unroll
    for (int it = 0; it < 4; ++it) {
      const int off = it * 4096 + tid * 16;
      const int kp = off / 8192, row = (off % 8192) >> 6, colb = off & 63;
      const char* ga = (const char*)A + (size_t)(row0 + row) * 4608 + (kp * 32) * 2 + colb;
      __builtin_amdgcn_global_load_lds((const __attribute__((address_space(1))) unsigned int*)ga,
                                       (__attribute__((address_space(3))) unsigned int*)((char*)lgA + off), 16, 0, 0);
      const char* gb = (const char*)Bt + (size_t)(col0 + row) * 1536 + (kp * 32) * 2 + colb;
      __builtin_amdgcn_global_load_lds((const __attribute__((address_space(1))) unsigned int*)gb,
                                       (__attribute__((address_space(3))) unsigned int*)((char*)lgB + off), 16, 0, 0);
    }
    __syncthreads();
    #pragma unroll
    for (int kk = 0; kk < 64; kk += 32) {
      short8 af[4], bfr[4];
      #pragma unroll
      for (int m = 0; m < 4; m++)
        af[m] = *(const short8*)&lgA[(kk >> 5) * 4096 + (wr * 64 + m * 16 + lr) * 32 + kg * 8];
      #pragma unroll
      for (int n = 0; n < 4; n++)
        bfr[n] = *(const short8*)&lgB[(kk >> 5) * 4096 + (wc * 64 + n * 16 + lr) * 32 + kg * 8];
      #pragma unroll
      for (int m = 0; m < 4; m++)
        #pragma unroll
        for (int n = 0; n < 4; n++)
          acc[m][n] = __builtin_amdgcn_mfma_f32_16x16x32_bf16(af[m], bfr[n], acc[m][n], 0, 0, 0);
    }
    #pragma unroll
    for (int m = 0; m < 4; m++)
      #pragma unroll
      for (int n = 0; n < 4; n++) {
        const int gc = col0 + wc * 64 + n * 16 + lr;
        #pragma unroll
        for (int j = 0; j < 4; j++) {
          const int gr = row0 + wr * 64 + m * 16 + kg * 4 + j;
          Tbuf[(size_t)gr * 9216 + z * 768 + gc] = f2bf(acc[m][n][j]);
        }
      }
    return;
  }

  // ---------------- attn_self body ----------------
  const int bh = blockIdx.x >> 2;
  const int qq = blockIdx.x & 3;
  const int b = bh / 12;
  const int h = bh % 12;
  const size_t rowbase = (size_t)b * 256;
  const int rows0 = qq * 64 + w * 16;            // this wave's 16 q-rows

  unsigned short* Ks = (unsigned short*)smem;             // [256][72]
  unsigned short* VT = (unsigned short*)(smem + 36864);   // [64][264]  VT[d][k]=V[k][d]
  unsigned short* aL = (unsigned short*)(smem + (size_t)w * 4352); // [16][136]/wave, aliases Ks

  for (int it = 0; it < 8; ++it) {
    const int idx = tid * 8 + it * 2048;
    const int row = idx >> 6, d = idx & 63;
    *(short8*)&Ks[row * 72 + d] =
        *(const short8*)&qkv[(rowbase + row) * 2304 + 768 + h * 64 + d];
  }
  #pragma unroll
  for (int it = 0; it < 16; ++it) {
    const int kk = w * 64 + it * 4 + kg;
    const int d0 = lr * 4;
    u16x4 v4 = *(const u16x4*)&qkv[(rowbase + kk) * 2304 + 1536 + h * 64 + d0];
    VT[(d0+0) * 264 + kk] = v4.x;
    VT[(d0+1) * 264 + kk] = v4.y;
    VT[(d0+2) * 264 + kk] = v4.z;
    VT[(d0+3) * 264 + kk] = v4.w;
  }
  __syncthreads();

  f32x4 acc[16];
  #pragma unroll
  for (int n = 0; n < 16; n++)
    #pragma unroll
    for (int q = 0; q < 4; q++) acc[n][q] = 0.f;

  #pragma unroll
  for (int ks = 0; ks < 64; ks += 32) {           // QK^T, K=64; Q from global
    short8 af = *(const short8*)&qkv[(rowbase + rows0 + lr) * 2304 + h * 64 + ks + kg * 8];
    #pragma unroll
    for (int n = 0; n < 16; n++) {
      short8 bfr = *(const short8*)&Ks[(n * 16 + lr) * 72 + ks + kg * 8];
      acc[n] = __builtin_amdgcn_mfma_f32_16x16x32_bf16(af, bfr, acc[n], 0, 0, 0);
    }
  }

  #pragma unroll
  for (int j = 0; j < 4; j++) {
    float vmx = -1e30f;
    #pragma unroll
    for (int n = 0; n < 16; n++) { float s = acc[n][j] * 0.125f; acc[n][j] = s; vmx = fmaxf(vmx, s); }
    #pragma unroll
    for (int s = 1; s < 16; s <<= 1) vmx = fmaxf(vmx, __shfl_xor(vmx, s));
    float sum = 0.f;
    #pragma unroll
    for (int n = 0; n < 16; n++) { float e = __expf(acc[n][j] - vmx); acc[n][j] = e; sum += e; }
    #pragma unroll
    for (int s = 1; s < 16; s <<= 1) sum += __shfl_xor(sum, s);
    if (lr == 0) {
      const int row = rows0 + kg * 4 + j;
      mstat[(rowbase + row) * 12 + h] = vmx;
      sstat[(rowbase + row) * 12 + h] = sum;
    }
  }

  __syncthreads();   // all waves done reading Ks before aL overwrites it

  f32x4 acc2[4];
  #pragma unroll
  for (int m = 0; m < 4; m++)
    #pragma unroll
    for (int q = 0; q < 4; q++) acc2[m][q] = 0.f;

  #pragma unroll
  for (int hl = 0; hl < 2; ++hl) {   // PV in two 128-col halves
    #pragma unroll
    for (int j = 0; j < 4; j++) {
      const int rw = kg * 4 + j;
      #pragma unroll
      for (int n2 = 0; n2 < 8; n2++)
        aL[rw * 136 + n2 * 16 + lr] = f2bf(acc[hl * 8 + n2][j]);   // unnormalized
    }
    #pragma unroll
    for (int ks2 = 0; ks2 < 4; ++ks2) {   // out^T = VT * a^T
      short8 pf = *(const short8*)&aL[lr * 136 + ks2 * 32 + kg * 8];
      #pragma unroll
      for (int mm = 0; mm < 4; mm++) {
        short8 vf = *(const short8*)&VT[(mm * 16 + lr) * 264 + hl * 128 + ks2 * 32 + kg * 8];
        acc2[mm] = __builtin_amdgcn_mfma_f32_16x16x32_bf16(vf, pf, acc2[mm], 0, 0, 0);
      }
    }
  }

  #pragma unroll
  for (int mm = 0; mm < 4; mm++)      // D rows = dh, D cols = q-row (lr)
    #pragma unroll
    for (int j = 0; j < 4; j++) {
      const int dh = mm * 16 + kg * 4 + j;
      const int rn = rows0 + lr;
      selfacc[(rowbase + rn) * 768 + h * 64 + dh] = acc2[mm][j];   // f32 unnorm
    }
}

// --------------------- fused sim logits + renorm + s_v (MFMA) --------------
// One block per (b,n) = r, 8 waves, 512 threads.  (See R6 notes.)

__global__ __launch_bounds__(512, 4)
void fused_sim_kernel(const float* __restrict__ se, const unsigned short* __restrict__ T,
                      const unsigned short* __restrict__ qkv, const float* __restrict__ bk,
                      const float* __restrict__ mstat, const float* __restrict__ sstat,
                      unsigned short* __restrict__ s_v,
                      float* __restrict__ sclA, float* __restrict__ simwA)
{
  const int r = blockIdx.x;                    // b*256+n
  __shared__ __align__(16) unsigned int SE_T32[768 * 9];   // 27648 B
  __shared__ __align__(16) unsigned int SErm[16][388];     // 24832 B (776-elem rows)
  __shared__ __align__(16) float Lp[8][64][4];             // 8192 B
  __shared__ float qb[16];
  const int tid = threadIdx.x;
  const int w = tid >> 6, lane = tid & 63;
  const int lr = lane & 15, kg = lane >> 4;

  // ---- coalesced stage: wave w owns se rows m = {2w, 2w+1} ----
  const float* se_r = se + (size_t)r * 12288;
  unsigned short va[2][12];
  #pragma unroll
  for (int c = 0; c < 3; ++c) {
    float4 fa = *(const float4*)&se_r[(2 * w) * 768 + c * 256 + lane * 4];
    float4 fb = *(const float4*)&se_r[(2 * w + 1) * 768 + c * 256 + lane * 4];
    va[0][c*4+0] = f2bf(fa.x); va[0][c*4+1] = f2bf(fa.y); va[0][c*4+2] = f2bf(fa.z); va[0][c*4+3] = f2bf(fa.w);
    va[1][c*4+0] = f2bf(fb.x); va[1][c*4+1] = f2bf(fb.y); va[1][c*4+2] = f2bf(fb.z); va[1][c*4+3] = f2bf(fb.w);
  }
  #pragma unroll
  for (int c = 0; c < 3; ++c) {
    #pragma unroll
    for (int j = 0; j < 4; ++j) {        // SE_T: m-pair packed, swizzled dword col
      const int d = c * 256 + lane * 4 + j;
      SE_T32[d * 9 + (w ^ ((d >> 5) & 7))] =
          (unsigned int)va[0][c*4+j] | ((unsigned int)va[1][c*4+j] << 16);
    }
    #pragma unroll
    for (int rr = 0; rr < 2; ++rr) {     // SErm: row-major k-pairs, b64 writes
      uint2 pk;
      pk.x = (unsigned int)va[rr][c*4+0] | ((unsigned int)va[rr][c*4+1] << 16);
      pk.y = (unsigned int)va[rr][c*4+2] | ((unsigned int)va[rr][c*4+3] << 16);
      *(uint2*)&SErm[2 * w + rr][c * 128 + lane * 2] = pk;
    }
  }
  // qb[h] = q_h . bk_h  (waves 0..5, 2 heads each)
  if (w < 6) {
    #pragma unroll
    for (int i = 0; i < 2; ++i) {
      const int hh = w * 2 + i;
      float p = bf2f(qkv[(size_t)r * 2304 + hh * 64 + lane]) * bk[hh * 64 + lane];
      #pragma unroll
      for (int sft = 32; sft; sft >>= 1) p += __shfl_xor(p, sft);
      if (lane == 0) qb[hh] = p;
    }
  }
  if (tid < 4) qb[12 + tid] = 0.f;

  // T B-frags for this wave's K-range (global, L3-resident; no LDS dep)
  short8 bfr[3];
  #pragma unroll
  for (int s = 0; s < 3; ++s)
    bfr[s] = *(const short8*)&T[(size_t)r * 9216 + lr * 768 + w * 96 + s * 32 + kg * 8];

  __syncthreads();

  // ---- L-GEMM partial: K in [w*96, w*96+96) ----
  f32x4 accL = {0.f, 0.f, 0.f, 0.f};
  #pragma unroll
  for (int s = 0; s < 3; ++s) {
    const int kb = w * 96 + s * 32 + kg * 8;
    short8 af = *(const short8*)&SErm[lr][kb >> 1];
    accL = __builtin_amdgcn_mfma_f32_16x16x32_bf16(af, bfr[s], accL, 0, 0, 0);
  }
  *(f32x4*)&Lp[w][lane][0] = accL;
  __syncthreads();

  // ---- softmax + joint renorm (redundant per wave; m=kg*4+j, h=lr) ----
  float vals[4] = {0.f, 0.f, 0.f, 0.f};
  #pragma unroll
  for (int ww = 0; ww < 8; ++ww) {
    f32x4 p = *(const f32x4*)&Lp[ww][lane][0];
    vals[0] += p[0]; vals[1] += p[1]; vals[2] += p[2]; vals[3] += p[3];
  }
  #pragma unroll
  for (int j = 0; j < 4; ++j) vals[j] = vals[j] * 0.125f + qb[lr];
  float mx = fmaxf(fmaxf(vals[0], vals[1]), fmaxf(vals[2], vals[3]));
  mx = fmaxf(mx, __shfl_xor(mx, 16));
  mx = fmaxf(mx, __shfl_xor(mx, 32));
  const int hidx = r * 12 + (lr < 12 ? lr : 11);
  const float msf = mstat[hidx];
  const float ssf = sstat[hidx];
  const float mj = fmaxf(mx, msf);
  float ea[4];
  #pragma unroll
  for (int j = 0; j < 4; ++j) ea[j] = __expf(vals[j] - mj);
  float ssum = ea[0] + ea[1] + ea[2] + ea[3];
  ssum += __shfl_xor(ssum, 16);
  ssum += __shfl_xor(ssum, 32);
  const float alpha = __expf(msf - mj);
  const float invZ = 1.0f / (ssf * alpha + ssum);
  float a[4];
  #pragma unroll
  for (int j = 0; j < 4; ++j) a[j] = ea[j] * invZ;
  if (w == 0 && kg == 0 && lr < 12) {
    sclA[(size_t)r * 12 + lr]  = alpha * invZ;
    simwA[(size_t)r * 12 + lr] = ssum * invZ;
  }

  // ---- a^T A-frag: lane (h=lr, kg) needs a[m=kg*8+e][h], zeros for kg>=2 ----
  short8 af8;
  #pragma unroll
  for (int e = 0; e < 8; ++e) {
    const int src = lr + ((kg & 1) * 2 + (e >> 2)) * 16;
    const float v = __shfl(a[e & 3], src);
    af8[e] = (kg < 2) ? (short)f2bf(v) : (short)0;
  }

  // ---- s_v GEMM: 6 d-tiles per wave, one mfma each ----
  #pragma unroll
  for (int i = 0; i < 6; ++i) {
    const int ntile = w + i * 8;
    const int row = ntile * 16 + lr;
    const int sw = (row >> 5) & 7;
    union { unsigned int u[4]; short8 s8; } bu;
    #pragma unroll
    for (int j = 0; j < 4; ++j)
      bu.u[j] = SE_T32[row * 9 + (((kg & 1) * 4 + j) ^ sw)];
    f32x4 cacc = {0.f, 0.f, 0.f, 0.f};
    cacc = __builtin_amdgcn_mfma_f32_16x16x32_bf16(af8, bu.s8, cacc, 0, 0, 0);
    if (kg < 3) {
      #pragma unroll
      for (int j = 0; j < 4; ++j) {
        const int h = kg * 4 + j;
        s_v[(size_t)r * 9216 + h * 768 + ntile * 16 + lr] = f2bf(cacc[j]);
      }
    }
  }
}

// ------------------------------- launcher ----------------------------------

extern "C" void kernel_launch(void* const* d_in, const int* in_sizes, int n_in,
                              void* d_out, int out_size, void* d_ws, size_t ws_size,
                              hipStream_t stream) {
  const float* x  = (const float*)d_in[0];
  const float* se = (const float*)d_in[1];
  const float* Wq = (const float*)d_in[2];
  const float* bq = (const float*)d_in[3];
  const float* Wk = (const float*)d_in[4];
  const float* bk = (const float*)d_in[5];
  const float* Wv = (const float*)d_in[6];
  const float* bv = (const float*)d_in[7];
  const float* Wp = (const float*)d_in[8];
  const float* bp = (const float*)d_in[9];
  float* out = (float*)d_out;
  char* ws = (char*)d_ws;

  // workspace layout (256B-aligned), total ~120.4 MB
  unsigned short* x_bf    = (unsigned short*)(ws);                 // 4096x768   bf16
  unsigned short* Wqkv_t  = (unsigned short*)(ws + 6291456);       // 2304x768   bf16  Wq^T|Wk^T|Wv^T rows
  unsigned short* Wp_t    = (unsigned short*)(ws + 9830400);       // 768x768    bf16
  unsigned short* Wk_bf   = (unsigned short*)(ws + 11010048);      // 768x768    bf16 (untransposed)
  float*          bqkv    = (float*)(ws + 12189696);               // 2304       f32
  unsigned short* qkv     = (unsigned short*)(ws + 12198912);      // 4096x2304  bf16  q|k|v
  unsigned short* Tbuf    = (unsigned short*)(ws + 31073280);      // 4096x12x768 bf16  T, then s_v
  float*          selfacc = (float*)(ws + 106570752);              // 4096x768   f32  unnorm out_self
  float*          mstat   = (float*)(ws + 119153664);              // 4096x12    f32
  float*          sstat   = (float*)(ws + 119350272);              // 4096x12    f32
  float*          sclA    = (float*)(ws + 119546880);              // 4096x12    f32
  float*          simwA   = (float*)(ws + 119743488);              // 4096x12    f32
  unsigned short* att     = (unsigned short*)(ws + 119940096);     // 4096x768   bf16

  prep_all<<<5376, 256, 0, stream>>>(x, x_bf, Wq, Wk, Wv, Wp, Wqkv_t, Wp_t,
                                     Wk_bf, bq, bk, bv, bqkv);

  // qkv = x @ [Wq|Wk|Wv] + bias: 256x128 tile, 512 threads, 288 blocks
  gemm_qkv<<<288, 512, 0, stream>>>(x_bf, Wqkv_t, qkv, bqkv);

  // merged: attn_self (768 blocks) + T-GEMM (2304 blocks)
  tattn_kernel<<<3072, 256, 0, stream>>>(qkv, Wk_bf, Tbuf, selfacc, mstat, sstat);

  fused_sim_kernel<<<4096, 512, 0, stream>>>(se, Tbuf, qkv, bk, mstat, sstat,
                                             Tbuf /* s_v overwrites T in-place per r */,
                                             sclA, simwA);

  // att = selfacc*scl + s_v_h @ Wv_h + simw*bv_h   (ZY: z = s/32, 384 blocks)
  gemm_bt<true, true, 64, 32, true, true><<<384, 256, 0, stream>>>(
      Tbuf, 9216, 768, Wqkv_t + 1536 * 768, 768, 64 * 768, att, 768, 64,
      4096, 64, 768, 384, nullptr, selfacc, sclA, simwA, bv);
  // out = att @ Wp + bp  (f32 out), yb = s/32 (ZY=false), 384 blocks, swizzled
  gemm_bt<false, false, 64, 32, true, false><<<384, 256, 0, stream>>>(
      att, 768, 0, Wp_t, 768, 0, out, 768, 0, 4096, 768, 768, 384,
      bp, nullptr, nullptr, nullptr, nullptr);
}